// Round 7
// baseline (729.314 us; speedup 1.0000x reference)
//
#include <hip/hip_runtime.h>
#include <stdint.h>

typedef unsigned char u8;
typedef unsigned short u16;
typedef unsigned int u32;
typedef unsigned long long u64;

// ---- problem constants ----
// B=128 S=128 WL=16 V=50000 C=100 T=17 WE=300 CE=50 CF=50 K=3 H=256 D=350
#define NPOS 16384          // B*S
#define KPAD 384            // D padded to multiple of 64

typedef __attribute__((ext_vector_type(8))) short bf16x8;
typedef __attribute__((ext_vector_type(4))) float f32x4;

__device__ __forceinline__ float bf2f(u16 u) { return __uint_as_float(((u32)u) << 16); }
__device__ __forceinline__ u16 f2bf(float f) {
    u32 u = __float_as_uint(f);
    u += 0x7fffu + ((u >> 16) & 1u);   // RNE
    return (u16)(u >> 16);
}
__device__ __forceinline__ float frcp(float x) {
#if __has_builtin(__builtin_amdgcn_rcpf)
    return __builtin_amdgcn_rcpf(x);       // v_rcp_f32, 1ulp — fine vs fp8 weights
#else
    return 1.0f / x;
#endif
}
__device__ __forceinline__ float sigm(float x) { return frcp(1.0f + __expf(-x)); }
__device__ __forceinline__ float tanh_(float x) { return fmaf(2.0f, frcp(1.0f + __expf(-2.0f * x)), -1.0f); }

// f32 -> fp8 e4m3fn (OCP), RNE, clamp to +-448. Prep-path (manual, no builtin risk).
__device__ u8 f2fp8_manual(float f) {
    u32 u = __float_as_uint(f);
    u32 s = (u >> 31) << 7;
    u32 ae = (u >> 23) & 255u;
    u32 m = u & 0x7fffffu;
    int e = (int)ae - 127;
    if (ae == 0) return (u8)s;                 // f32 subnormal -> 0
    if (e >= 9) return (u8)(s | 0x7e);         // >= 512 -> clamp 448
    if (e >= -6) {                             // e4m3 normal
        u32 mant = m >> 20;
        u32 rem = m & 0xfffffu;
        if (rem > 0x80000u || (rem == 0x80000u && (mant & 1u))) mant++;
        u32 ef = (u32)(e + 7);
        if (mant == 8u) { mant = 0u; ef++; }
        if (ef >= 16u || (ef == 15u && mant == 7u)) return (u8)(s | 0x7e);
        return (u8)(s | (ef << 3) | mant);
    }
    if (e < -10) return (u8)s;                 // underflow to 0
    int sb = 14 - e;                           // shift for units of 2^-9
    u32 X = 0x800000u | m;
    u32 mant = X >> sb;
    u32 rem = X & ((1u << sb) - 1u);
    u32 half = 1u << (sb - 1);
    if (rem > half || (rem == half && (mant & 1u))) mant++;
    if (mant >= 8u) return (u8)(s | (1u << 3)); // rounds to first normal 2^-6
    return (u8)(s | mant);
}

__device__ __forceinline__ u8 f2fp8(float f) {
#if __has_builtin(__builtin_amdgcn_cvt_pk_fp8_f32)
    return (u8)(__builtin_amdgcn_cvt_pk_fp8_f32(f, f, 0, false) & 0xff);
#else
    return f2fp8_manual(f);
#endif
}

// ---- workspace layout (bytes) ----
static constexpr size_t OFF_INP  = 0;                       // u16 [16384][384]   = 12582912
static constexpr size_t OFF_WIH  = 12582912;                // u16 [2048][384]    = 1572864
static constexpr size_t OFF_WHH  = 14155776;                // fp8 packed 512KB
static constexpr size_t OFF_XG   = 15204352;                // u16 xg2 repacked   = 67108864
static constexpr size_t OFF_HS   = 82313216;                // u16 [16384][512]   = 16777216
static constexpr size_t OFF_EMIS = 99090432;                // f32 [16384][17]    = 1114112
static constexpr size_t OFF_NLL  = 100204544;               // f32 [128]

// ============================================================
// Prep: pack [w_ih_f; w_ih_b] into bf16 [2048][384] (K padded w/ zeros)
// ============================================================
__global__ __launch_bounds__(128) void k_prep_wih(const float* __restrict__ wf,
                                                  const float* __restrict__ wb,
                                                  u16* __restrict__ wih) {
    int n = blockIdx.x, tid = threadIdx.x;
    const float* src = (n < 1024) ? (wf + (size_t)n * 350) : (wb + (size_t)(n - 1024) * 350);
    u16* dst = wih + (size_t)n * KPAD;
    for (int k = tid; k < KPAD; k += 128) dst[k] = (k < 350) ? f2bf(src[k]) : (u16)0;
}

// ============================================================
// Prep: w_hh (both dirs) -> fp8, packed for 16x16x32 B-frags:
// whh8[((d*8+w)*4+g)*8192 + (nb*8+kc)*512 + (q*16+c16)*8 + e]
// where hid = w*32+nb*16+c16, k = kc*32 + q*8 + e
// ============================================================
__global__ __launch_bounds__(128) void k_prep_whh8(const float* __restrict__ wf,
                                                   const float* __restrict__ wb,
                                                   u8* __restrict__ whh8) {
    int bx = blockIdx.x, tid = threadIdx.x;
    int d = bx >> 10, row = bx & 1023;                 // row = gate*256 + hid
    const float* src = (d ? wb : wf) + (size_t)row * 256;
    int g = row >> 8, hid = row & 255;
    int w = hid >> 5, nb = (hid >> 4) & 1, c16 = hid & 15;
    u8* base = whh8 + ((size_t)((d * 8 + w) * 4 + g)) * 8192;
    for (int k = tid; k < 256; k += 128) {
        int kc = k >> 5, q = (k >> 3) & 3, e = k & 7;
        base[(nb * 8 + kc) * 512 + (q * 16 + c16) * 8 + e] = f2fp8_manual(src[k]);
    }
}

// ============================================================
// Embedding + char conv + concat -> inp bf16 [16384][384]
// ============================================================
__global__ __launch_bounds__(128) void k_embed_conv(const int* __restrict__ words,
                                                    const int* __restrict__ chars,
                                                    const float* __restrict__ word_emb,
                                                    const float* __restrict__ char_emb,
                                                    const float* __restrict__ conv_w,
                                                    const float* __restrict__ conv_b,
                                                    u16* __restrict__ inp) {
    int pos = blockIdx.x, tid = threadIdx.x;
    __shared__ float ce[18 * 50];                      // rows 0 and 17 are zero pad
    const int* ch = chars + (size_t)pos * 16;
    for (int i = tid; i < 18 * 50; i += 128) {
        int row = i / 50, c = i - row * 50;
        float v = 0.f;
        if (row >= 1 && row <= 16) v = char_emb[(size_t)ch[row - 1] * 50 + c];
        ce[i] = v;
    }
    __syncthreads();
    {   // word embedding copy + zero pad
        const float* we = word_emb + (size_t)words[pos] * 300;
        u16* op = inp + (size_t)pos * KPAD;
        for (int c = tid; c < 300; c += 128) op[c] = f2bf(we[c]);
        for (int c = 350 + tid; c < KPAD; c += 128) op[c] = 0;
    }
    if (tid < 100) {
        int oc = tid >> 1, half = tid & 1, t0 = half * 8;
        float acc[8];
#pragma unroll
        for (int tt = 0; tt < 8; ++tt) acc[tt] = 0.f;
        const float* wrow = conv_w + (size_t)oc * 150;
        for (int ic = 0; ic < 50; ++ic) {
#pragma unroll
            for (int k = 0; k < 3; ++k) {
                float wv = wrow[ic * 3 + k];
#pragma unroll
                for (int tt = 0; tt < 8; ++tt)
                    acc[tt] = fmaf(ce[(t0 + tt + k) * 50 + ic], wv, acc[tt]);
            }
        }
        float cb = conv_b[oc];
        float m = 0.f;                                  // relu floor
#pragma unroll
        for (int tt = 0; tt < 8; ++tt) m = fmaxf(m, acc[tt] + cb);
        m = fmaxf(m, __shfl_xor(m, 1));
        if (half == 0) inp[(size_t)pos * KPAD + 300 + oc] = f2bf(m);
    }
}

// ============================================================
// GEMM: inp[16384][384] @ wih[2048][384]^T (bf16 MFMA). Epilogue adds the
// LSTM bias (position-independent) and writes xg2 packed for k_lstm:
// slot = ((d*8+grp)*128 + tt)*16384 + (w*64 + q*16 + c16)*32 + (nb*4+reg)*4 + gate
// with bwd time axis pre-reversed (tt).
// ============================================================
__global__ __launch_bounds__(256, 2) void k_gemm(const u16* __restrict__ A,
                                                 const u16* __restrict__ Bm,
                                                 u16* __restrict__ C,
                                                 const int* __restrict__ lengths,
                                                 const float* __restrict__ bias_f,
                                                 const float* __restrict__ bias_b) {
    __shared__ u16 sa[128 * 64];
    __shared__ u16 sb[128 * 64];
    int tid = threadIdx.x;
    int n0 = blockIdx.x * 128, m0 = blockIdx.y * 128;
    int lane = tid & 63, wid = tid >> 6;
    int wr = wid >> 1, wc = wid & 1;
    f32x4 acc[4][4];
#pragma unroll
    for (int mt = 0; mt < 4; ++mt)
#pragma unroll
        for (int nt = 0; nt < 4; ++nt) acc[mt][nt] = (f32x4){0.f, 0.f, 0.f, 0.f};

    for (int kt = 0; kt < 6; ++kt) {
#pragma unroll
        for (int c = 0; c < 4; ++c) {
            int idx = (c * 256 + tid) * 16;            // byte within 16KB tile
            int row = idx >> 7, colb = idx & 127;
            int dst = idx ^ ((row & 7) << 4);
            uint4 va = *(const uint4*)((const char*)A + (size_t)(m0 + row) * 768 + kt * 128 + colb);
            *(uint4*)((char*)sa + dst) = va;
            uint4 vb = *(const uint4*)((const char*)Bm + (size_t)(n0 + row) * 768 + kt * 128 + colb);
            *(uint4*)((char*)sb + dst) = vb;
        }
        __syncthreads();
#pragma unroll
        for (int kc = 0; kc < 2; ++kc) {
            bf16x8 af[4], bf[4];
#pragma unroll
            for (int mt = 0; mt < 4; ++mt) {
                int row = wr * 64 + mt * 16 + (lane & 15);
                int off = (row * 128 + kc * 64 + (lane >> 4) * 16) ^ ((row & 7) << 4);
                af[mt] = *(const bf16x8*)((const char*)sa + off);
            }
#pragma unroll
            for (int nt = 0; nt < 4; ++nt) {
                int row = wc * 64 + nt * 16 + (lane & 15);
                int off = (row * 128 + kc * 64 + (lane >> 4) * 16) ^ ((row & 7) << 4);
                bf[nt] = *(const bf16x8*)((const char*)sb + off);
            }
#pragma unroll
            for (int mt = 0; mt < 4; ++mt)
#pragma unroll
                for (int nt = 0; nt < 4; ++nt)
                    acc[mt][nt] = __builtin_amdgcn_mfma_f32_16x16x32_bf16(af[mt], bf[nt], acc[mt][nt], 0, 0, 0);
        }
        __syncthreads();
    }
    // epilogue: tile spans exactly batch element b = blockIdx.y (t = 0..127)
    int b = blockIdx.y;
    int len = lengths[b];
    int grp = b >> 4, row16 = b & 15;
    int qq = row16 >> 2, rg = row16 & 3;
    float bv[4];
    int dds[4], loffs[4];
#pragma unroll
    for (int nt = 0; nt < 4; ++nt) {
        int col = n0 + wc * 64 + nt * 16 + (lane & 15);
        int dd = col >> 10, rem = col & 1023;
        bv[nt] = (dd ? bias_b : bias_f)[rem];
        int gate = rem >> 8, hid = rem & 255;
        int w2 = hid >> 5, nb = (hid >> 4) & 1, cc = hid & 15;
        dds[nt] = dd;
        loffs[nt] = (w2 * 64 + qq * 16 + cc) * 32 + (nb * 4 + rg) * 4 + gate;
    }
#pragma unroll
    for (int mt = 0; mt < 4; ++mt)
#pragma unroll
        for (int nt = 0; nt < 4; ++nt) {
#pragma unroll
            for (int r = 0; r < 4; ++r) {
                int t = wr * 64 + mt * 16 + (lane >> 4) * 4 + r;
                int tt = dds[nt] ? ((t < len) ? (len - 1 - t) : t) : t;
                size_t slot = ((size_t)(dds[nt] * 8 + grp) * 128 + tt) * 16384 + loffs[nt];
                C[slot] = f2bf(acc[mt][nt][r] + bv[nt]);
            }
        }
}

// ============================================================
// BiLSTM recurrence. 16 WGs = dir(2) x group(8, 16 rows). 512 thr = 8 waves.
// All 4 gates register-resident fp8 (u64 br[4][16]). h fp8 double-buffered LDS,
// row stride 264 (balanced banks, no swizzle). Zero-VALU LDS addressing
// (base VGPR + folded offset immediates). Inline-asm barrier: only lgkmcnt(0)
// drained — global hs stores / xg prefetch stay in flight across steps.
// MFMA: v_mfma_f32_16x16x32_fp8_fp8, setprio(1) around the cluster.
// ============================================================
#define LSTM_STEP(T, XC, XN, BUF)                                                 \
    {                                                                             \
        *(uint4*)(&XN[0])  = *(const uint4*)(xp);                                 \
        *(uint4*)(&XN[4])  = *(const uint4*)(xp + 8);                             \
        *(uint4*)(&XN[8])  = *(const uint4*)(xp + 16);                            \
        *(uint4*)(&XN[12]) = *(const uint4*)(xp + 24);                            \
        xp += 16384;                                                              \
        f32x4 acc[8];                                                             \
        _Pragma("unroll") for (int u = 0; u < 8; ++u)                             \
            acc[u] = (f32x4){0.f, 0.f, 0.f, 0.f};                                 \
        __builtin_amdgcn_s_setprio(1);                                            \
        _Pragma("unroll") for (int kc = 0; kc < 8; ++kc) {                        \
            long long a = *(const long long*)(ha + (BUF) * 4224 + kc * 32);       \
            _Pragma("unroll") for (int g = 0; g < 4; ++g)                         \
                acc[g] = __builtin_amdgcn_mfma_f32_16x16x32_fp8_fp8(              \
                    a, (long long)br[g][kc], acc[g], 0, 0, 0);                    \
            _Pragma("unroll") for (int g = 0; g < 4; ++g)                         \
                acc[4 + g] = __builtin_amdgcn_mfma_f32_16x16x32_fp8_fp8(          \
                    a, (long long)br[g][8 + kc], acc[4 + g], 0, 0, 0);            \
        }                                                                         \
        __builtin_amdgcn_s_setprio(0);                                            \
        _Pragma("unroll") for (int nb = 0; nb < 2; ++nb)                          \
            _Pragma("unroll") for (int rg = 0; rg < 4; ++rg) {                    \
                int u = nb * 4 + rg;                                              \
                u32 w0 = XC[u * 2], w1 = XC[u * 2 + 1];                           \
                float pi = acc[nb * 4 + 0][rg] + __uint_as_float(w0 << 16);       \
                float pf = acc[nb * 4 + 1][rg] + __uint_as_float(w0 & 0xffff0000u); \
                float pg = acc[nb * 4 + 2][rg] + __uint_as_float(w1 << 16);       \
                float po = acc[nb * 4 + 3][rg] + __uint_as_float(w1 & 0xffff0000u); \
                float gi = sigm(pi), gf = sigm(pf), gg = tanh_(pg), go = sigm(po); \
                float cn = gf * cst[u] + gi * gg;                                 \
                float hn = go * tanh_(cn);                                        \
                u8 nq = f2fp8(hn);                                                \
                if ((T) < lenr[rg]) {                                             \
                    cst[u] = cn;                                                  \
                    hq[u] = nq;                                                   \
                    *(u16*)(hsp + voff[u]) = (u16)(__float_as_uint(hn) >> 16);    \
                }                                                                 \
                voff[u] += (u32)dstepB;                                           \
                hw[(1 - (BUF)) * 4224 + hwoff[u]] = hq[u];                        \
            }                                                                     \
        asm volatile("s_waitcnt lgkmcnt(0)\n\ts_barrier" ::: "memory");           \
    }

__global__ __launch_bounds__(512, 2) void k_lstm(const u16* __restrict__ xg2,
                                                 const u8* __restrict__ whh8,
                                                 const int* __restrict__ lengths,
                                                 u16* __restrict__ hs) {
    __shared__ u8 h8[2][4224];                         // [buf][16 rows][stride 264]
    int tid = threadIdx.x, lane = tid & 63, w = tid >> 6;
    int bx = blockIdx.x;
    int d = bx >> 3, grp = bx & 7;
    int c16 = lane & 15, q = lane >> 4;

    u8* hw = &h8[0][0];
    for (int i = tid * 8; i < 8448; i += 4096) *(u64*)(hw + i) = 0;

    int lenr[4];
#pragma unroll
    for (int rg = 0; rg < 4; ++rg) lenr[rg] = lengths[grp * 16 + q * 4 + rg];

    // register-resident fp8 weights: 4 gates x 16 (nb*8+kc) u64 frags = 128 regs
    const u8* wbse = whh8 + ((size_t)((d * 8 + w) * 4)) * 8192;
    u64 br[4][16];
#pragma unroll
    for (int g = 0; g < 4; ++g)
#pragma unroll
        for (int j = 0; j < 16; ++j)
            br[g][j] = *(const u64*)(wbse + (size_t)g * 8192 + j * 512 + lane * 8);

    float cst[8];
    u8 hq[8];                                          // current h as fp8 (carried for masked rows)
#pragma unroll
    for (int u = 0; u < 8; ++u) { cst[u] = 0.f; hq[u] = 0; }

    // hoisted per-unit addresses
    u32 hwoff[8];                                      // LDS write offsets (within one buffer)
    u32 voff[8];                                       // hs byte offsets (running)
    int dstepB = d ? -1024 : 1024;
    u8* hsp = (u8*)hs;
#pragma unroll
    for (int nb = 0; nb < 2; ++nb)
#pragma unroll
        for (int rg = 0; rg < 4; ++rg) {
            int u = nb * 4 + rg;
            int row = q * 4 + rg;
            int hid = w * 32 + nb * 16 + c16;
            hwoff[u] = row * 264 + hid;
            int p0 = d ? (lenr[rg] - 1) : 0;
            voff[u] = (u32)((((grp * 16 + row) * 128 + p0) * 512 + d * 256 + hid) * 2);
        }

    // xg: bias pre-folded; 64B/lane/step; xp points at the NEXT slab
    const u16* xslab = xg2 + ((size_t)(d * 8 + grp) * 128) * 16384 + (w * 64 + lane) * 32;
    u32 xqa[16], xqb[16];
    *(uint4*)(&xqa[0])  = *(const uint4*)(xslab);
    *(uint4*)(&xqa[4])  = *(const uint4*)(xslab + 8);
    *(uint4*)(&xqa[8])  = *(const uint4*)(xslab + 16);
    *(uint4*)(&xqa[12]) = *(const uint4*)(xslab + 24);
    const u16* xp = xslab + 16384;

    // A-frag LDS base (row r = c16, k = kc*32 + q*8 + e), stride 264, no swizzle
    const u8* ha = &h8[0][0] + (c16 * 264 + q * 8);

    __syncthreads();

    for (int t2 = 0; t2 < 128; t2 += 2) {
        LSTM_STEP(t2,     xqa, xqb, 0)
        LSTM_STEP(t2 + 1, xqb, xqa, 1)
    }
}

// ============================================================
// Emissions: emis[pos][17] = hs[pos][512] . proj_w[17][512] + proj_b
// ============================================================
__global__ __launch_bounds__(256) void k_emis(const u16* __restrict__ hs,
                                              const float* __restrict__ proj_w,
                                              const float* __restrict__ proj_b,
                                              float* __restrict__ emis) {
    __shared__ float pw[17 * 512];
    int tid = threadIdx.x;
    for (int i = tid; i < 17 * 512; i += 256) pw[i] = proj_w[i];
    __syncthreads();
    int lane = tid & 63, wv = tid >> 6;
    int pos = blockIdx.x * 4 + wv;
    float hv[8];
    const u16* hp = hs + (size_t)pos * 512 + lane * 8;
#pragma unroll
    for (int j = 0; j < 8; ++j) hv[j] = bf2f(hp[j]);
    for (int tg = 0; tg < 17; ++tg) {
        const float* wp = pw + tg * 512 + lane * 8;
        float s = 0.f;
#pragma unroll
        for (int j = 0; j < 8; ++j) s = fmaf(hv[j], wp[j], s);
#pragma unroll
        for (int off = 32; off; off >>= 1) s += __shfl_down(s, off);
        if (lane == 0) emis[(size_t)pos * 17 + tg] = s + proj_b[tg];
    }
}

// ============================================================
// CRF per-sample NLL. One 64-thread block per batch element.
// ============================================================
__global__ __launch_bounds__(64) void k_crf(const float* __restrict__ emis,
                                            const int* __restrict__ tags,
                                            const int* __restrict__ lengths,
                                            const float* __restrict__ trans,
                                            const float* __restrict__ start_trans,
                                            const float* __restrict__ end_trans,
                                            float* __restrict__ nll) {
    int b = blockIdx.x, lane = threadIdx.x;
    __shared__ float tr[289];
    __shared__ float al[17];
    __shared__ float scs;
    for (int i = lane; i < 289; i += 64) tr[i] = trans[i];
    int len = lengths[b];
    const int* tg = tags + (size_t)b * 128;
    const float* em = emis + (size_t)b * 128 * 17;
    __syncthreads();

    float sc = 0.f;
    for (int t = lane; t < len; t += 64) {
        sc += em[t * 17 + tg[t]];
        if (t >= 1) sc += tr[tg[t - 1] * 17 + tg[t]];
    }
#pragma unroll
    for (int off = 32; off; off >>= 1) sc += __shfl_down(sc, off);
    if (lane == 0) scs = sc + start_trans[tg[0]] + end_trans[tg[len - 1]];

    if (lane < 17) al[lane] = start_trans[lane] + em[lane];
    __syncthreads();
    for (int t = 1; t < len; ++t) {
        float anew = 0.f;
        if (lane < 17) {
            float m = -1e30f;
            for (int i = 0; i < 17; ++i) m = fmaxf(m, al[i] + tr[i * 17 + lane]);
            float s = 0.f;
            for (int i = 0; i < 17; ++i) s += __expf(al[i] + tr[i * 17 + lane] - m);
            anew = m + __logf(s) + em[t * 17 + lane];
        }
        __syncthreads();
        if (lane < 17) al[lane] = anew;
        __syncthreads();
    }
    float v = (lane < 17) ? al[lane] + end_trans[lane] : -1e30f;
    float m = v;
#pragma unroll
    for (int off = 32; off; off >>= 1) m = fmaxf(m, __shfl_xor(m, off));
    float s = (lane < 17) ? __expf(v - m) : 0.f;
#pragma unroll
    for (int off = 32; off; off >>= 1) s += __shfl_xor(s, off);
    if (lane == 0) nll[b] = (m + __logf(s)) - scs;
}

__global__ __launch_bounds__(128) void k_reduce(const float* __restrict__ nll, float* __restrict__ out) {
    int tid = threadIdx.x;
    float v = nll[tid];
#pragma unroll
    for (int off = 32; off; off >>= 1) v += __shfl_down(v, off);
    __shared__ float partial[2];
    if ((tid & 63) == 0) partial[tid >> 6] = v;
    __syncthreads();
    if (tid == 0) out[0] = partial[0] + partial[1];
}

// ============================================================
extern "C" void kernel_launch(void* const* d_in, const int* in_sizes, int n_in,
                              void* d_out, int out_size, void* d_ws, size_t ws_size,
                              hipStream_t stream) {
    (void)in_sizes; (void)n_in; (void)out_size; (void)ws_size;
    const int*   words       = (const int*)d_in[0];
    const int*   chars       = (const int*)d_in[1];
    const int*   tags        = (const int*)d_in[2];
    const int*   lengths     = (const int*)d_in[3];
    const float* word_emb    = (const float*)d_in[4];
    const float* char_emb    = (const float*)d_in[5];
    const float* conv_w      = (const float*)d_in[6];
    const float* conv_b      = (const float*)d_in[7];
    const float* w_ih_f      = (const float*)d_in[8];
    const float* w_hh_f      = (const float*)d_in[9];
    const float* b_f         = (const float*)d_in[10];
    const float* w_ih_b      = (const float*)d_in[11];
    const float* w_hh_b      = (const float*)d_in[12];
    const float* b_b         = (const float*)d_in[13];
    const float* proj_w      = (const float*)d_in[14];
    const float* proj_b      = (const float*)d_in[15];
    const float* trans       = (const float*)d_in[16];
    const float* start_trans = (const float*)d_in[17];
    const float* end_trans   = (const float*)d_in[18];

    char* ws = (char*)d_ws;
    u16* inp   = (u16*)(ws + OFF_INP);
    u16* wih   = (u16*)(ws + OFF_WIH);
    u8*  whh8  = (u8*)(ws + OFF_WHH);
    u16* xgb   = (u16*)(ws + OFF_XG);
    u16* hsb   = (u16*)(ws + OFF_HS);
    float* em  = (float*)(ws + OFF_EMIS);
    float* nll = (float*)(ws + OFF_NLL);

    k_prep_wih<<<2048, 128, 0, stream>>>(w_ih_f, w_ih_b, wih);
    k_prep_whh8<<<2048, 128, 0, stream>>>(w_hh_f, w_hh_b, whh8);
    k_embed_conv<<<NPOS, 128, 0, stream>>>(words, chars, word_emb, char_emb, conv_w, conv_b, inp);
    k_gemm<<<dim3(16, 128), 256, 0, stream>>>(inp, wih, xgb, lengths, b_f, b_b);
    k_lstm<<<16, 512, 0, stream>>>(xgb, whh8, lengths, hsb);
    k_emis<<<4096, 256, 0, stream>>>(hsb, proj_w, proj_b, em);
    k_crf<<<128, 64, 0, stream>>>(em, tags, lengths, trans, start_trans, end_trans, nll);
    k_reduce<<<1, 128, 0, stream>>>(nll, (float*)d_out);
}

// Round 8
// 606.438 us; speedup vs baseline: 1.2026x; 1.2026x over previous
//
#include <hip/hip_runtime.h>
#include <stdint.h>

typedef unsigned char u8;
typedef unsigned short u16;
typedef unsigned int u32;
typedef unsigned long long u64;

// ---- problem constants ----
// B=128 S=128 WL=16 V=50000 C=100 T=17 WE=300 CE=50 CF=50 K=3 H=256 D=350
#define NPOS 16384          // B*S
#define KPAD 384            // D padded to multiple of 64

typedef __attribute__((ext_vector_type(8))) short bf16x8;
typedef __attribute__((ext_vector_type(4))) float f32x4;
typedef __attribute__((ext_vector_type(8))) int i32x8;

__device__ __forceinline__ float bf2f(u16 u) { return __uint_as_float(((u32)u) << 16); }
__device__ __forceinline__ u16 f2bf(float f) {
    u32 u = __float_as_uint(f);
    u += 0x7fffu + ((u >> 16) & 1u);   // RNE
    return (u16)(u >> 16);
}
__device__ __forceinline__ float frcp(float x) {
#if __has_builtin(__builtin_amdgcn_rcpf)
    return __builtin_amdgcn_rcpf(x);       // v_rcp_f32, 1ulp — fine vs fp8 weights
#else
    return 1.0f / x;
#endif
}
__device__ __forceinline__ float sigm(float x) { return frcp(1.0f + __expf(-x)); }
__device__ __forceinline__ float tanh_(float x) { return fmaf(2.0f, frcp(1.0f + __expf(-2.0f * x)), -1.0f); }

// f32 -> fp8 e4m3fn (OCP), RNE, clamp to +-448. Prep-path (manual, no builtin risk).
__device__ u8 f2fp8_manual(float f) {
    u32 u = __float_as_uint(f);
    u32 s = (u >> 31) << 7;
    u32 ae = (u >> 23) & 255u;
    u32 m = u & 0x7fffffu;
    int e = (int)ae - 127;
    if (ae == 0) return (u8)s;                 // f32 subnormal -> 0
    if (e >= 9) return (u8)(s | 0x7e);         // >= 512 -> clamp 448
    if (e >= -6) {                             // e4m3 normal
        u32 mant = m >> 20;
        u32 rem = m & 0xfffffu;
        if (rem > 0x80000u || (rem == 0x80000u && (mant & 1u))) mant++;
        u32 ef = (u32)(e + 7);
        if (mant == 8u) { mant = 0u; ef++; }
        if (ef >= 16u || (ef == 15u && mant == 7u)) return (u8)(s | 0x7e);
        return (u8)(s | (ef << 3) | mant);
    }
    if (e < -10) return (u8)s;                 // underflow to 0
    int sb = 14 - e;                           // shift for units of 2^-9
    u32 X = 0x800000u | m;
    u32 mant = X >> sb;
    u32 rem = X & ((1u << sb) - 1u);
    u32 half = 1u << (sb - 1);
    if (rem > half || (rem == half && (mant & 1u))) mant++;
    if (mant >= 8u) return (u8)(s | (1u << 3)); // rounds to first normal 2^-6
    return (u8)(s | mant);
}

__device__ __forceinline__ u8 f2fp8(float f) {
#if __has_builtin(__builtin_amdgcn_cvt_pk_fp8_f32)
    return (u8)(__builtin_amdgcn_cvt_pk_fp8_f32(f, f, 0, false) & 0xff);
#else
    return f2fp8_manual(f);
#endif
}

// ---- workspace layout (bytes) ----
static constexpr size_t OFF_INP  = 0;                       // u16 [16384][384]   = 12582912
static constexpr size_t OFF_WIH  = 12582912;                // u16 [2048][384]    = 1572864
static constexpr size_t OFF_WHH  = 14155776;                // fp8 packed 512KB
static constexpr size_t OFF_XG   = 15204352;                // u16 xg2 repacked   = 67108864
static constexpr size_t OFF_HS   = 82313216;                // u16 [16384][512]   = 16777216
static constexpr size_t OFF_EMIS = 99090432;                // f32 [16384][17]    = 1114112
static constexpr size_t OFF_NLL  = 100204544;               // f32 [128]

// ============================================================
// Prep: pack [w_ih_f; w_ih_b] into bf16 [2048][384] (K padded w/ zeros)
// ============================================================
__global__ __launch_bounds__(128) void k_prep_wih(const float* __restrict__ wf,
                                                  const float* __restrict__ wb,
                                                  u16* __restrict__ wih) {
    int n = blockIdx.x, tid = threadIdx.x;
    const float* src = (n < 1024) ? (wf + (size_t)n * 350) : (wb + (size_t)(n - 1024) * 350);
    u16* dst = wih + (size_t)n * KPAD;
    for (int k = tid; k < KPAD; k += 128) dst[k] = (k < 350) ? f2bf(src[k]) : (u16)0;
}

// ============================================================
// Prep: w_hh (both dirs) -> fp8, packed for the MX-scaled 16x16x128 B-frag:
// whh8[((d*8+w)*4+g)*8192 + ((nb*2+kk)*64 + lane)*32 + j]
// where hid = w*32+nb*16+c16, lane = q*16+c16, k = kk*128 + q*32 + j
// ============================================================
__global__ __launch_bounds__(128) void k_prep_whh8(const float* __restrict__ wf,
                                                   const float* __restrict__ wb,
                                                   u8* __restrict__ whh8) {
    int bx = blockIdx.x, tid = threadIdx.x;
    int d = bx >> 10, row = bx & 1023;                 // row = gate*256 + hid
    const float* src = (d ? wb : wf) + (size_t)row * 256;
    int g = row >> 8, hid = row & 255;
    int w = hid >> 5, nb = (hid >> 4) & 1, c16 = hid & 15;
    u8* base = whh8 + ((size_t)((d * 8 + w) * 4 + g)) * 8192;
    for (int k = tid; k < 256; k += 128) {
        int kk = k >> 7, q = (k >> 5) & 3, j = k & 31;
        base[((nb * 2 + kk) * 64 + (q * 16 + c16)) * 32 + j] = f2fp8_manual(src[k]);
    }
}

// ============================================================
// Embedding + char conv + concat -> inp bf16 [16384][384]
// ============================================================
__global__ __launch_bounds__(128) void k_embed_conv(const int* __restrict__ words,
                                                    const int* __restrict__ chars,
                                                    const float* __restrict__ word_emb,
                                                    const float* __restrict__ char_emb,
                                                    const float* __restrict__ conv_w,
                                                    const float* __restrict__ conv_b,
                                                    u16* __restrict__ inp) {
    int pos = blockIdx.x, tid = threadIdx.x;
    __shared__ float ce[18 * 50];                      // rows 0 and 17 are zero pad
    const int* ch = chars + (size_t)pos * 16;
    for (int i = tid; i < 18 * 50; i += 128) {
        int row = i / 50, c = i - row * 50;
        float v = 0.f;
        if (row >= 1 && row <= 16) v = char_emb[(size_t)ch[row - 1] * 50 + c];
        ce[i] = v;
    }
    __syncthreads();
    {   // word embedding copy + zero pad
        const float* we = word_emb + (size_t)words[pos] * 300;
        u16* op = inp + (size_t)pos * KPAD;
        for (int c = tid; c < 300; c += 128) op[c] = f2bf(we[c]);
        for (int c = 350 + tid; c < KPAD; c += 128) op[c] = 0;
    }
    if (tid < 100) {
        int oc = tid >> 1, half = tid & 1, t0 = half * 8;
        float acc[8];
#pragma unroll
        for (int tt = 0; tt < 8; ++tt) acc[tt] = 0.f;
        const float* wrow = conv_w + (size_t)oc * 150;
        for (int ic = 0; ic < 50; ++ic) {
#pragma unroll
            for (int k = 0; k < 3; ++k) {
                float wv = wrow[ic * 3 + k];
#pragma unroll
                for (int tt = 0; tt < 8; ++tt)
                    acc[tt] = fmaf(ce[(t0 + tt + k) * 50 + ic], wv, acc[tt]);
            }
        }
        float cb = conv_b[oc];
        float m = 0.f;                                  // relu floor
#pragma unroll
        for (int tt = 0; tt < 8; ++tt) m = fmaxf(m, acc[tt] + cb);
        m = fmaxf(m, __shfl_xor(m, 1));
        if (half == 0) inp[(size_t)pos * KPAD + 300 + oc] = f2bf(m);
    }
}

// ============================================================
// GEMM: inp[16384][384] @ wih[2048][384]^T (bf16 MFMA). Epilogue adds the
// LSTM bias (position-independent) and writes xg2 packed for k_lstm:
// slot = ((d*8+grp)*128 + tt)*16384 + (w*64 + q*16 + c16)*32 + (nb*4+reg)*4 + gate
// with bwd time axis pre-reversed (tt).
// ============================================================
__global__ __launch_bounds__(256, 2) void k_gemm(const u16* __restrict__ A,
                                                 const u16* __restrict__ Bm,
                                                 u16* __restrict__ C,
                                                 const int* __restrict__ lengths,
                                                 const float* __restrict__ bias_f,
                                                 const float* __restrict__ bias_b) {
    __shared__ u16 sa[128 * 64];
    __shared__ u16 sb[128 * 64];
    int tid = threadIdx.x;
    int n0 = blockIdx.x * 128, m0 = blockIdx.y * 128;
    int lane = tid & 63, wid = tid >> 6;
    int wr = wid >> 1, wc = wid & 1;
    f32x4 acc[4][4];
#pragma unroll
    for (int mt = 0; mt < 4; ++mt)
#pragma unroll
        for (int nt = 0; nt < 4; ++nt) acc[mt][nt] = (f32x4){0.f, 0.f, 0.f, 0.f};

    for (int kt = 0; kt < 6; ++kt) {
#pragma unroll
        for (int c = 0; c < 4; ++c) {
            int idx = (c * 256 + tid) * 16;            // byte within 16KB tile
            int row = idx >> 7, colb = idx & 127;
            int dst = idx ^ ((row & 7) << 4);
            uint4 va = *(const uint4*)((const char*)A + (size_t)(m0 + row) * 768 + kt * 128 + colb);
            *(uint4*)((char*)sa + dst) = va;
            uint4 vb = *(const uint4*)((const char*)Bm + (size_t)(n0 + row) * 768 + kt * 128 + colb);
            *(uint4*)((char*)sb + dst) = vb;
        }
        __syncthreads();
#pragma unroll
        for (int kc = 0; kc < 2; ++kc) {
            bf16x8 af[4], bf[4];
#pragma unroll
            for (int mt = 0; mt < 4; ++mt) {
                int row = wr * 64 + mt * 16 + (lane & 15);
                int off = (row * 128 + kc * 64 + (lane >> 4) * 16) ^ ((row & 7) << 4);
                af[mt] = *(const bf16x8*)((const char*)sa + off);
            }
#pragma unroll
            for (int nt = 0; nt < 4; ++nt) {
                int row = wc * 64 + nt * 16 + (lane & 15);
                int off = (row * 128 + kc * 64 + (lane >> 4) * 16) ^ ((row & 7) << 4);
                bf[nt] = *(const bf16x8*)((const char*)sb + off);
            }
#pragma unroll
            for (int mt = 0; mt < 4; ++mt)
#pragma unroll
                for (int nt = 0; nt < 4; ++nt)
                    acc[mt][nt] = __builtin_amdgcn_mfma_f32_16x16x32_bf16(af[mt], bf[nt], acc[mt][nt], 0, 0, 0);
        }
        __syncthreads();
    }
    // epilogue: tile spans exactly batch element b = blockIdx.y (t = 0..127)
    int b = blockIdx.y;
    int len = lengths[b];
    int grp = b >> 4, row16 = b & 15;
    int qq = row16 >> 2, rg = row16 & 3;
    float bv[4];
    int dds[4], loffs[4];
#pragma unroll
    for (int nt = 0; nt < 4; ++nt) {
        int col = n0 + wc * 64 + nt * 16 + (lane & 15);
        int dd = col >> 10, rem = col & 1023;
        bv[nt] = (dd ? bias_b : bias_f)[rem];
        int gate = rem >> 8, hid = rem & 255;
        int w2 = hid >> 5, nb = (hid >> 4) & 1, cc = hid & 15;
        dds[nt] = dd;
        loffs[nt] = (w2 * 64 + qq * 16 + cc) * 32 + (nb * 4 + rg) * 4 + gate;
    }
#pragma unroll
    for (int mt = 0; mt < 4; ++mt)
#pragma unroll
        for (int nt = 0; nt < 4; ++nt) {
#pragma unroll
            for (int r = 0; r < 4; ++r) {
                int t = wr * 64 + mt * 16 + (lane >> 4) * 4 + r;
                int tt = dds[nt] ? ((t < len) ? (len - 1 - t) : t) : t;
                size_t slot = ((size_t)(dds[nt] * 8 + grp) * 128 + tt) * 16384 + loffs[nt];
                C[slot] = f2bf(acc[mt][nt][r] + bv[nt]);
            }
        }
}

// ============================================================
// BiLSTM recurrence. 16 WGs = dir(2) x group(8, 16 rows). 512 thr = 8 waves.
// All 4 gates register-resident fp8 (i32x8 br[16] = 128 regs). h fp8
// double-buffered LDS, row stride 272. MX-scaled MFMA 16x16x128 (fp8/fp8,
// unit scales): 16 MFMAs/wave/step at 2x rate. nb0-MFMA / nb1-MFMA /
// epilogue-nb0 / epilogue-nb1 ordering lets the scheduler hide epilogue
// VALU under nb1's dependent MFMA chains. Single-base + immediate-offset
// LDS addressing; barrier drains lgkmcnt only.
// ============================================================
#define LSTM_STEP(T, XC, XN, BUF)                                                 \
    {                                                                             \
        *(uint4*)(&XN[0])  = *(const uint4*)(xp);                                 \
        *(uint4*)(&XN[4])  = *(const uint4*)(xp + 8);                             \
        *(uint4*)(&XN[8])  = *(const uint4*)(xp + 16);                            \
        *(uint4*)(&XN[12]) = *(const uint4*)(xp + 24);                            \
        xp += 16384;                                                              \
        i32x8 a0, a1;                                                             \
        {                                                                         \
            uint4 lo = *(const uint4*)(ha + (BUF) * 4352);                        \
            uint4 hi = *(const uint4*)(ha + (BUF) * 4352 + 16);                   \
            a0[0] = lo.x; a0[1] = lo.y; a0[2] = lo.z; a0[3] = lo.w;               \
            a0[4] = hi.x; a0[5] = hi.y; a0[6] = hi.z; a0[7] = hi.w;               \
            lo = *(const uint4*)(ha + (BUF) * 4352 + 128);                        \
            hi = *(const uint4*)(ha + (BUF) * 4352 + 144);                        \
            a1[0] = lo.x; a1[1] = lo.y; a1[2] = lo.z; a1[3] = lo.w;               \
            a1[4] = hi.x; a1[5] = hi.y; a1[6] = hi.z; a1[7] = hi.w;               \
        }                                                                         \
        f32x4 acc[8];                                                             \
        _Pragma("unroll") for (int u = 0; u < 8; ++u)                             \
            acc[u] = (f32x4){0.f, 0.f, 0.f, 0.f};                                 \
        __builtin_amdgcn_s_setprio(1);                                            \
        _Pragma("unroll") for (int g = 0; g < 4; ++g)                             \
            acc[g] = __builtin_amdgcn_mfma_scale_f32_16x16x128_f8f6f4(            \
                a0, br[g * 4 + 0], acc[g], 0, 0, 0, 127, 0, 127);                 \
        _Pragma("unroll") for (int g = 0; g < 4; ++g)                             \
            acc[g] = __builtin_amdgcn_mfma_scale_f32_16x16x128_f8f6f4(            \
                a1, br[g * 4 + 1], acc[g], 0, 0, 0, 127, 0, 127);                 \
        _Pragma("unroll") for (int g = 0; g < 4; ++g)                             \
            acc[4 + g] = __builtin_amdgcn_mfma_scale_f32_16x16x128_f8f6f4(        \
                a0, br[g * 4 + 2], acc[4 + g], 0, 0, 0, 127, 0, 127);             \
        _Pragma("unroll") for (int g = 0; g < 4; ++g)                             \
            acc[4 + g] = __builtin_amdgcn_mfma_scale_f32_16x16x128_f8f6f4(        \
                a1, br[g * 4 + 3], acc[4 + g], 0, 0, 0, 127, 0, 127);             \
        __builtin_amdgcn_s_setprio(0);                                            \
        _Pragma("unroll") for (int nb = 0; nb < 2; ++nb)                          \
            _Pragma("unroll") for (int rg = 0; rg < 4; ++rg) {                    \
                int u = nb * 4 + rg;                                              \
                u32 w0 = XC[u * 2], w1 = XC[u * 2 + 1];                           \
                float pi = acc[nb * 4 + 0][rg] + __uint_as_float(w0 << 16);       \
                float pf = acc[nb * 4 + 1][rg] + __uint_as_float(w0 & 0xffff0000u); \
                float pg = acc[nb * 4 + 2][rg] + __uint_as_float(w1 << 16);       \
                float po = acc[nb * 4 + 3][rg] + __uint_as_float(w1 & 0xffff0000u); \
                float gi = sigm(pi), gf = sigm(pf), gg = tanh_(pg), go = sigm(po); \
                float cn = gf * cst[u] + gi * gg;                                 \
                float hn = go * tanh_(cn);                                        \
                u8 nq = f2fp8(hn);                                                \
                if ((T) < lenr[rg]) {                                             \
                    cst[u] = cn;                                                  \
                    hq[u] = nq;                                                   \
                    *(u16*)(hsp + voff[u]) = (u16)(__float_as_uint(hn) >> 16);    \
                }                                                                 \
                voff[u] += (u32)dstepB;                                           \
                hwp[(1 - (BUF)) * 4352 + rg * 272 + nb * 16] = hq[u];             \
            }                                                                     \
        asm volatile("s_waitcnt lgkmcnt(0)\n\ts_barrier" ::: "memory");           \
    }

__global__ __launch_bounds__(512, 2) void k_lstm(const u16* __restrict__ xg2,
                                                 const u8* __restrict__ whh8,
                                                 const int* __restrict__ lengths,
                                                 u16* __restrict__ hs) {
    __shared__ u8 h8[2][4352];                         // [buf][16 rows][stride 272]
    int tid = threadIdx.x, lane = tid & 63, w = tid >> 6;
    int bx = blockIdx.x;
    int d = bx >> 3, grp = bx & 7;
    int c16 = lane & 15, q = lane >> 4;

    u8* hflat = &h8[0][0];
    for (int i = tid * 8; i < 8704; i += 4096) *(u64*)(hflat + i) = 0;

    int lenr[4];
#pragma unroll
    for (int rg = 0; rg < 4; ++rg) lenr[rg] = lengths[grp * 16 + q * 4 + rg];

    // register-resident fp8 weights: [g][nb][kk] i32x8 = 128 regs
    const u8* wbse = whh8 + ((size_t)((d * 8 + w) * 4)) * 8192;
    i32x8 br[16];
#pragma unroll
    for (int g = 0; g < 4; ++g)
#pragma unroll
        for (int nb = 0; nb < 2; ++nb)
#pragma unroll
            for (int kk = 0; kk < 2; ++kk) {
                const u8* p = wbse + (size_t)g * 8192 + ((nb * 2 + kk) * 64 + lane) * 32;
                uint4 lo = *(const uint4*)p, hi = *(const uint4*)(p + 16);
                i32x8 v;
                v[0] = lo.x; v[1] = lo.y; v[2] = lo.z; v[3] = lo.w;
                v[4] = hi.x; v[5] = hi.y; v[6] = hi.z; v[7] = hi.w;
                br[g * 4 + nb * 2 + kk] = v;
            }

    float cst[8];
    u8 hq[8];                                          // current h as fp8 (carried for masked rows)
#pragma unroll
    for (int u = 0; u < 8; ++u) { cst[u] = 0.f; hq[u] = 0; }

    // hs byte offsets (running)
    u32 voff[8];
    int dstepB = d ? -1024 : 1024;
    u8* hsp = (u8*)hs;
#pragma unroll
    for (int nb = 0; nb < 2; ++nb)
#pragma unroll
        for (int rg = 0; rg < 4; ++rg) {
            int u = nb * 4 + rg;
            int row = q * 4 + rg;
            int hid = w * 32 + nb * 16 + c16;
            int p0 = d ? (lenr[rg] - 1) : 0;
            voff[u] = (u32)((((grp * 16 + row) * 128 + p0) * 512 + d * 256 + hid) * 2);
        }

    // xg: bias pre-folded; 64B/lane/step; xp points at the NEXT slab
    const u16* xslab = xg2 + ((size_t)(d * 8 + grp) * 128) * 16384 + (w * 64 + lane) * 32;
    u32 xqa[16], xqb[16];
    *(uint4*)(&xqa[0])  = *(const uint4*)(xslab);
    *(uint4*)(&xqa[4])  = *(const uint4*)(xslab + 8);
    *(uint4*)(&xqa[8])  = *(const uint4*)(xslab + 16);
    *(uint4*)(&xqa[12]) = *(const uint4*)(xslab + 24);
    const u16* xp = xslab + 16384;

    // A-frag LDS base: row c16, k = q*32 + j (+ kk*128 via imm), stride 272
    const u8* ha = hflat + (c16 * 272 + q * 32);
    // h write base: row = q*4+rg (imm rg*272), hid = w*32 + nb*16 (imm) + c16
    u8* hwp = hflat + (q * 1088 + w * 32 + c16);

    __syncthreads();

    for (int t2 = 0; t2 < 128; t2 += 2) {
        LSTM_STEP(t2,     xqa, xqb, 0)
        LSTM_STEP(t2 + 1, xqb, xqa, 1)
    }
}

// ============================================================
// Emissions: emis[pos][17] = hs[pos][512] . proj_w[17][512] + proj_b
// ============================================================
__global__ __launch_bounds__(256) void k_emis(const u16* __restrict__ hs,
                                              const float* __restrict__ proj_w,
                                              const float* __restrict__ proj_b,
                                              float* __restrict__ emis) {
    __shared__ float pw[17 * 512];
    int tid = threadIdx.x;
    for (int i = tid; i < 17 * 512; i += 256) pw[i] = proj_w[i];
    __syncthreads();
    int lane = tid & 63, wv = tid >> 6;
    int pos = blockIdx.x * 4 + wv;
    float hv[8];
    const u16* hp = hs + (size_t)pos * 512 + lane * 8;
#pragma unroll
    for (int j = 0; j < 8; ++j) hv[j] = bf2f(hp[j]);
    for (int tg = 0; tg < 17; ++tg) {
        const float* wp = pw + tg * 512 + lane * 8;
        float s = 0.f;
#pragma unroll
        for (int j = 0; j < 8; ++j) s = fmaf(hv[j], wp[j], s);
#pragma unroll
        for (int off = 32; off; off >>= 1) s += __shfl_down(s, off);
        if (lane == 0) emis[(size_t)pos * 17 + tg] = s + proj_b[tg];
    }
}

// ============================================================
// CRF per-sample NLL. One 64-thread block per batch element.
// ============================================================
__global__ __launch_bounds__(64) void k_crf(const float* __restrict__ emis,
                                            const int* __restrict__ tags,
                                            const int* __restrict__ lengths,
                                            const float* __restrict__ trans,
                                            const float* __restrict__ start_trans,
                                            const float* __restrict__ end_trans,
                                            float* __restrict__ nll) {
    int b = blockIdx.x, lane = threadIdx.x;
    __shared__ float tr[289];
    __shared__ float al[17];
    __shared__ float scs;
    for (int i = lane; i < 289; i += 64) tr[i] = trans[i];
    int len = lengths[b];
    const int* tg = tags + (size_t)b * 128;
    const float* em = emis + (size_t)b * 128 * 17;
    __syncthreads();

    float sc = 0.f;
    for (int t = lane; t < len; t += 64) {
        sc += em[t * 17 + tg[t]];
        if (t >= 1) sc += tr[tg[t - 1] * 17 + tg[t]];
    }
#pragma unroll
    for (int off = 32; off; off >>= 1) sc += __shfl_down(sc, off);
    if (lane == 0) scs = sc + start_trans[tg[0]] + end_trans[tg[len - 1]];

    if (lane < 17) al[lane] = start_trans[lane] + em[lane];
    __syncthreads();
    for (int t = 1; t < len; ++t) {
        float anew = 0.f;
        if (lane < 17) {
            float m = -1e30f;
            for (int i = 0; i < 17; ++i) m = fmaxf(m, al[i] + tr[i * 17 + lane]);
            float s = 0.f;
            for (int i = 0; i < 17; ++i) s += __expf(al[i] + tr[i * 17 + lane] - m);
            anew = m + __logf(s) + em[t * 17 + lane];
        }
        __syncthreads();
        if (lane < 17) al[lane] = anew;
        __syncthreads();
    }
    float v = (lane < 17) ? al[lane] + end_trans[lane] : -1e30f;
    float m = v;
#pragma unroll
    for (int off = 32; off; off >>= 1) m = fmaxf(m, __shfl_xor(m, off));
    float s = (lane < 17) ? __expf(v - m) : 0.f;
#pragma unroll
    for (int off = 32; off; off >>= 1) s += __shfl_xor(s, off);
    if (lane == 0) nll[b] = (m + __logf(s)) - scs;
}

__global__ __launch_bounds__(128) void k_reduce(const float* __restrict__ nll, float* __restrict__ out) {
    int tid = threadIdx.x;
    float v = nll[tid];
#pragma unroll
    for (int off = 32; off; off >>= 1) v += __shfl_down(v, off);
    __shared__ float partial[2];
    if ((tid & 63) == 0) partial[tid >> 6] = v;
    __syncthreads();
    if (tid == 0) out[0] = partial[0] + partial[1];
}

// ============================================================
extern "C" void kernel_launch(void* const* d_in, const int* in_sizes, int n_in,
                              void* d_out, int out_size, void* d_ws, size_t ws_size,
                              hipStream_t stream) {
    (void)in_sizes; (void)n_in; (void)out_size; (void)ws_size;
    const int*   words       = (const int*)d_in[0];
    const int*   chars       = (const int*)d_in[1];
    const int*   tags        = (const int*)d_in[2];
    const int*   lengths     = (const int*)d_in[3];
    const float* word_emb    = (const float*)d_in[4];
    const float* char_emb    = (const float*)d_in[5];
    const float* conv_w      = (const float*)d_in[6];
    const float* conv_b      = (const float*)d_in[7];
    const float* w_ih_f      = (const float*)d_in[8];
    const float* w_hh_f      = (const float*)d_in[9];
    const float* b_f         = (const float*)d_in[10];
    const float* w_ih_b      = (const float*)d_in[11];
    const float* w_hh_b      = (const float*)d_in[12];
    const float* b_b         = (const float*)d_in[13];
    const float* proj_w      = (const float*)d_in[14];
    const float* proj_b      = (const float*)d_in[15];
    const float* trans       = (const float*)d_in[16];
    const float* start_trans = (const float*)d_in[17];
    const float* end_trans   = (const float*)d_in[18];

    char* ws = (char*)d_ws;
    u16* inp   = (u16*)(ws + OFF_INP);
    u16* wih   = (u16*)(ws + OFF_WIH);
    u8*  whh8  = (u8*)(ws + OFF_WHH);
    u16* xgb   = (u16*)(ws + OFF_XG);
    u16* hsb   = (u16*)(ws + OFF_HS);
    float* em  = (float*)(ws + OFF_EMIS);
    float* nll = (float*)(ws + OFF_NLL);

    k_prep_wih<<<2048, 128, 0, stream>>>(w_ih_f, w_ih_b, wih);
    k_prep_whh8<<<2048, 128, 0, stream>>>(w_hh_f, w_hh_b, whh8);
    k_embed_conv<<<NPOS, 128, 0, stream>>>(words, chars, word_emb, char_emb, conv_w, conv_b, inp);
    k_gemm<<<dim3(16, 128), 256, 0, stream>>>(inp, wih, xgb, lengths, b_f, b_b);
    k_lstm<<<16, 512, 0, stream>>>(xgb, whh8, lengths, hsb);
    k_emis<<<4096, 256, 0, stream>>>(hsb, proj_w, proj_b, em);
    k_crf<<<128, 64, 0, stream>>>(em, tags, lengths, trans, start_trans, end_trans, nll);
    k_reduce<<<1, 128, 0, stream>>>(nll, (float*)d_out);
}

// Round 9
// 479.772 us; speedup vs baseline: 1.5201x; 1.2640x over previous
//
#include <hip/hip_runtime.h>
#include <stdint.h>

typedef unsigned char u8;
typedef unsigned short u16;
typedef unsigned int u32;
typedef unsigned long long u64;

// ---- problem constants ----
// B=128 S=128 WL=16 V=50000 C=100 T=17 WE=300 CE=50 CF=50 K=3 H=256 D=350
#define NPOS 16384          // B*S
#define KPAD 384            // D padded to multiple of 64

typedef __attribute__((ext_vector_type(8))) short bf16x8;
typedef __attribute__((ext_vector_type(4))) float f32x4;
typedef __attribute__((ext_vector_type(8))) int i32x8;

__device__ __forceinline__ float bf2f(u16 u) { return __uint_as_float(((u32)u) << 16); }
__device__ __forceinline__ u16 f2bf(float f) {
    u32 u = __float_as_uint(f);
    u += 0x7fffu + ((u >> 16) & 1u);   // RNE
    return (u16)(u >> 16);
}
__device__ __forceinline__ float frcp(float x) {
#if __has_builtin(__builtin_amdgcn_rcpf)
    return __builtin_amdgcn_rcpf(x);       // v_rcp_f32, 1ulp — fine vs fp8 weights
#else
    return 1.0f / x;
#endif
}
__device__ __forceinline__ float sigm(float x) { return frcp(1.0f + __expf(-x)); }
__device__ __forceinline__ float tanh_(float x) { return fmaf(2.0f, frcp(1.0f + __expf(-2.0f * x)), -1.0f); }

// f32 -> fp8 e4m3fn (OCP), RNE, clamp to +-448. Prep-path (manual, no builtin risk).
__device__ u8 f2fp8_manual(float f) {
    u32 u = __float_as_uint(f);
    u32 s = (u >> 31) << 7;
    u32 ae = (u >> 23) & 255u;
    u32 m = u & 0x7fffffu;
    int e = (int)ae - 127;
    if (ae == 0) return (u8)s;                 // f32 subnormal -> 0
    if (e >= 9) return (u8)(s | 0x7e);         // >= 512 -> clamp 448
    if (e >= -6) {                             // e4m3 normal
        u32 mant = m >> 20;
        u32 rem = m & 0xfffffu;
        if (rem > 0x80000u || (rem == 0x80000u && (mant & 1u))) mant++;
        u32 ef = (u32)(e + 7);
        if (mant == 8u) { mant = 0u; ef++; }
        if (ef >= 16u || (ef == 15u && mant == 7u)) return (u8)(s | 0x7e);
        return (u8)(s | (ef << 3) | mant);
    }
    if (e < -10) return (u8)s;                 // underflow to 0
    int sb = 14 - e;                           // shift for units of 2^-9
    u32 X = 0x800000u | m;
    u32 mant = X >> sb;
    u32 rem = X & ((1u << sb) - 1u);
    u32 half = 1u << (sb - 1);
    if (rem > half || (rem == half && (mant & 1u))) mant++;
    if (mant >= 8u) return (u8)(s | (1u << 3)); // rounds to first normal 2^-6
    return (u8)(s | mant);
}

__device__ __forceinline__ u32 f2fp8(float f) {
#if __has_builtin(__builtin_amdgcn_cvt_pk_fp8_f32)
    return (u32)(__builtin_amdgcn_cvt_pk_fp8_f32(f, f, 0, false) & 0xff);
#else
    return (u32)f2fp8_manual(f);
#endif
}

// ---- workspace layout (bytes) ----
static constexpr size_t OFF_INP  = 0;                       // u16 [16384][384]   = 12582912
static constexpr size_t OFF_WIH  = 12582912;                // u16 [2048][384]    = 1572864
static constexpr size_t OFF_WHH  = 14155776;                // fp8 packed 512KB
static constexpr size_t OFF_XG   = 15204352;                // u16 xg2 repacked   = 67108864
static constexpr size_t OFF_HS   = 82313216;                // u16 [16384][512]   = 16777216
static constexpr size_t OFF_EMIS = 99090432;                // f32 [16384][17]    = 1114112
static constexpr size_t OFF_NLL  = 100204544;               // f32 [128]

// ============================================================
// Prep: pack [w_ih_f; w_ih_b] into bf16 [2048][384] (K padded w/ zeros)
// ============================================================
__global__ __launch_bounds__(128) void k_prep_wih(const float* __restrict__ wf,
                                                  const float* __restrict__ wb,
                                                  u16* __restrict__ wih) {
    int n = blockIdx.x, tid = threadIdx.x;
    const float* src = (n < 1024) ? (wf + (size_t)n * 350) : (wb + (size_t)(n - 1024) * 350);
    u16* dst = wih + (size_t)n * KPAD;
    for (int k = tid; k < KPAD; k += 128) dst[k] = (k < 350) ? f2bf(src[k]) : (u16)0;
}

// ============================================================
// Prep: w_hh (both dirs) -> fp8, packed for the MX-scaled 16x16x128 B-frag:
// whh8[((d*8+w)*4+g)*8192 + ((nb*2+kk)*64 + lane)*32 + j]
// where hid = w*32+nb*16+c16, lane = q*16+c16, k = kk*128 + q*32 + j
// ============================================================
__global__ __launch_bounds__(128) void k_prep_whh8(const float* __restrict__ wf,
                                                   const float* __restrict__ wb,
                                                   u8* __restrict__ whh8) {
    int bx = blockIdx.x, tid = threadIdx.x;
    int d = bx >> 10, row = bx & 1023;                 // row = gate*256 + hid
    const float* src = (d ? wb : wf) + (size_t)row * 256;
    int g = row >> 8, hid = row & 255;
    int w = hid >> 5, nb = (hid >> 4) & 1, c16 = hid & 15;
    u8* base = whh8 + ((size_t)((d * 8 + w) * 4 + g)) * 8192;
    for (int k = tid; k < 256; k += 128) {
        int kk = k >> 7, q = (k >> 5) & 3, j = k & 31;
        base[((nb * 2 + kk) * 64 + (q * 16 + c16)) * 32 + j] = f2fp8_manual(src[k]);
    }
}

// ============================================================
// Embedding + char conv + concat -> inp bf16 [16384][384]
// ============================================================
__global__ __launch_bounds__(128) void k_embed_conv(const int* __restrict__ words,
                                                    const int* __restrict__ chars,
                                                    const float* __restrict__ word_emb,
                                                    const float* __restrict__ char_emb,
                                                    const float* __restrict__ conv_w,
                                                    const float* __restrict__ conv_b,
                                                    u16* __restrict__ inp) {
    int pos = blockIdx.x, tid = threadIdx.x;
    __shared__ float ce[18 * 50];                      // rows 0 and 17 are zero pad
    const int* ch = chars + (size_t)pos * 16;
    for (int i = tid; i < 18 * 50; i += 128) {
        int row = i / 50, c = i - row * 50;
        float v = 0.f;
        if (row >= 1 && row <= 16) v = char_emb[(size_t)ch[row - 1] * 50 + c];
        ce[i] = v;
    }
    __syncthreads();
    {   // word embedding copy (float4 -> packed u64 of 4 bf16) + zero pad
        const float4* we4 = (const float4*)(word_emb + (size_t)words[pos] * 300);
        u16* op = inp + (size_t)pos * KPAD;
        if (tid < 75) {
            float4 v = we4[tid];
            u64 pk = (u64)f2bf(v.x) | ((u64)f2bf(v.y) << 16) |
                     ((u64)f2bf(v.z) << 32) | ((u64)f2bf(v.w) << 48);
            *(u64*)(op + tid * 4) = pk;
        }
        for (int c = 350 + tid; c < KPAD; c += 128) op[c] = 0;
    }
    if (tid < 100) {
        int oc = tid >> 1, half = tid & 1, t0 = half * 8;
        float acc[8];
#pragma unroll
        for (int tt = 0; tt < 8; ++tt) acc[tt] = 0.f;
        const float* wrow = conv_w + (size_t)oc * 150;
        for (int ic = 0; ic < 50; ++ic) {
#pragma unroll
            for (int k = 0; k < 3; ++k) {
                float wv = wrow[ic * 3 + k];
#pragma unroll
                for (int tt = 0; tt < 8; ++tt)
                    acc[tt] = fmaf(ce[(t0 + tt + k) * 50 + ic], wv, acc[tt]);
            }
        }
        float cb = conv_b[oc];
        float m = 0.f;                                  // relu floor
#pragma unroll
        for (int tt = 0; tt < 8; ++tt) m = fmaxf(m, acc[tt] + cb);
        m = fmaxf(m, __shfl_xor(m, 1));
        if (half == 0) inp[(size_t)pos * KPAD + 300 + oc] = f2bf(m);
    }
}

// ============================================================
// GEMM: inp[16384][384] @ wih[2048][384]^T (bf16 MFMA). N retiled so each
// wave owns (16 hid x 4 gates): blockIdx.x -> (dd, hblk of 32 hid); wave wc
// owns hid16 = hblk*32 + wc*16. The 4 gates of one (t,hid) land in one
// thread -> single u64 store (4 bf16, bias folded) into the k_lstm slab:
// slot = ((dd*8+grp)*128 + tt)*16384 + (hblk*64 + qq*16 + c16)*32 + (wc*4+rg)*4 + gate
// ============================================================
__global__ __launch_bounds__(256, 2) void k_gemm(const u16* __restrict__ A,
                                                 const u16* __restrict__ Bm,
                                                 u16* __restrict__ C,
                                                 const int* __restrict__ lengths,
                                                 const float* __restrict__ bias_f,
                                                 const float* __restrict__ bias_b) {
    __shared__ u16 sa[128 * 64];
    __shared__ u16 sb[128 * 64];
    int tid = threadIdx.x;
    int dd = blockIdx.x >> 3, hblk = blockIdx.x & 7;
    int m0 = blockIdx.y * 128;
    int lane = tid & 63, wid = tid >> 6;
    int wr = wid >> 1, wc = wid & 1;
    f32x4 acc[4][4];
#pragma unroll
    for (int mt = 0; mt < 4; ++mt)
#pragma unroll
        for (int g = 0; g < 4; ++g) acc[mt][g] = (f32x4){0.f, 0.f, 0.f, 0.f};

    for (int kt = 0; kt < 6; ++kt) {
#pragma unroll
        for (int c = 0; c < 4; ++c) {
            int idx = (c * 256 + tid) * 16;            // byte within 16KB tile
            int row = idx >> 7, colb = idx & 127;
            int dst = idx ^ ((row & 7) << 4);
            uint4 va = *(const uint4*)((const char*)A + (size_t)(m0 + row) * 768 + kt * 128 + colb);
            *(uint4*)((char*)sa + dst) = va;
            int bmrow = dd * 1024 + (row >> 5) * 256 + hblk * 32 + (row & 31);
            uint4 vb = *(const uint4*)((const char*)Bm + (size_t)bmrow * 768 + kt * 128 + colb);
            *(uint4*)((char*)sb + dst) = vb;
        }
        __syncthreads();
#pragma unroll
        for (int kc = 0; kc < 2; ++kc) {
            bf16x8 af[4], bf[4];
#pragma unroll
            for (int mt = 0; mt < 4; ++mt) {
                int row = wr * 64 + mt * 16 + (lane & 15);
                int off = (row * 128 + kc * 64 + (lane >> 4) * 16) ^ ((row & 7) << 4);
                af[mt] = *(const bf16x8*)((const char*)sa + off);
            }
#pragma unroll
            for (int g = 0; g < 4; ++g) {
                int row = g * 32 + wc * 16 + (lane & 15);
                int off = (row * 128 + kc * 64 + (lane >> 4) * 16) ^ ((row & 7) << 4);
                bf[g] = *(const bf16x8*)((const char*)sb + off);
            }
#pragma unroll
            for (int mt = 0; mt < 4; ++mt)
#pragma unroll
                for (int g = 0; g < 4; ++g)
                    acc[mt][g] = __builtin_amdgcn_mfma_f32_16x16x32_bf16(af[mt], bf[g], acc[mt][g], 0, 0, 0);
        }
        __syncthreads();
    }
    // epilogue: tile spans exactly batch element b = blockIdx.y (t = 0..127)
    int b = blockIdx.y;
    int len = lengths[b];
    int grp = b >> 4, row16 = b & 15;
    int qq = row16 >> 2, rg = row16 & 3;
    int c16 = lane & 15;
    int hid = hblk * 32 + wc * 16 + c16;
    const float* bias = dd ? bias_b : bias_f;
    float bv[4];
#pragma unroll
    for (int g = 0; g < 4; ++g) bv[g] = bias[g * 256 + hid];
    u32 base16 = (u32)((hblk * 64 + qq * 16 + c16) * 32 + (wc * 4 + rg) * 4);
    size_t slab0 = ((size_t)(dd * 8 + grp) * 128) * 16384;
#pragma unroll
    for (int mt = 0; mt < 4; ++mt)
#pragma unroll
        for (int r = 0; r < 4; ++r) {
            int t = wr * 64 + mt * 16 + (lane >> 4) * 4 + r;
            int tt = dd ? ((t < len) ? (len - 1 - t) : t) : t;
            u64 pk = (u64)f2bf(acc[mt][0][r] + bv[0]) |
                     ((u64)f2bf(acc[mt][1][r] + bv[1]) << 16) |
                     ((u64)f2bf(acc[mt][2][r] + bv[2]) << 32) |
                     ((u64)f2bf(acc[mt][3][r] + bv[3]) << 48);
            *(u64*)(C + slab0 + (size_t)tt * 16384 + base16) = pk;
        }
}

// ============================================================
// BiLSTM recurrence. 16 WGs = dir(2) x group(8, 16 rows). 512 thr = 8 waves.
// All 4 gates register-resident fp8 (i32x8 br[16] = 128 regs). h fp8
// double-buffered LDS, stride 272. MX-scaled MFMA 16x16x128 (unit scales).
// R9: acc initialized from xg (C-operand carries the preactivation);
// fully branchless epilogue (cndmask state/store-offset freeze, no exec
// masks); i32x8 A-frags loaded in place. Barrier drains lgkmcnt only.
// ============================================================
#define LSTM_STEP(T, XC, XN, HA, HW)                                              \
    {                                                                             \
        *(uint4*)(&XN[0])  = *(const uint4*)(xp);                                 \
        *(uint4*)(&XN[4])  = *(const uint4*)(xp + 8);                             \
        *(uint4*)(&XN[8])  = *(const uint4*)(xp + 16);                            \
        *(uint4*)(&XN[12]) = *(const uint4*)(xp + 24);                            \
        xp += 16384;                                                              \
        f32x4 acc[8];                                                             \
        _Pragma("unroll") for (int nb = 0; nb < 2; ++nb)                          \
            _Pragma("unroll") for (int rg = 0; rg < 4; ++rg) {                    \
                int u = nb * 4 + rg;                                              \
                u32 w0 = XC[u * 2], w1 = XC[u * 2 + 1];                           \
                acc[nb * 4 + 0][rg] = __uint_as_float(w0 << 16);                  \
                acc[nb * 4 + 1][rg] = __uint_as_float(w0 & 0xffff0000u);          \
                acc[nb * 4 + 2][rg] = __uint_as_float(w1 << 16);                  \
                acc[nb * 4 + 3][rg] = __uint_as_float(w1 & 0xffff0000u);          \
            }                                                                     \
        i32x8 a0, a1;                                                             \
        *(uint4*)&a0       = *(const uint4*)(HA);                                 \
        *((uint4*)&a0 + 1) = *(const uint4*)(HA + 16);                            \
        *(uint4*)&a1       = *(const uint4*)(HA + 128);                           \
        *((uint4*)&a1 + 1) = *(const uint4*)(HA + 144);                           \
        __builtin_amdgcn_s_setprio(1);                                            \
        _Pragma("unroll") for (int g = 0; g < 4; ++g)                             \
            acc[g] = __builtin_amdgcn_mfma_scale_f32_16x16x128_f8f6f4(            \
                a0, br[g * 4 + 0], acc[g], 0, 0, 0, 127, 0, 127);                 \
        _Pragma("unroll") for (int g = 0; g < 4; ++g)                             \
            acc[g] = __builtin_amdgcn_mfma_scale_f32_16x16x128_f8f6f4(            \
                a1, br[g * 4 + 1], acc[g], 0, 0, 0, 127, 0, 127);                 \
        _Pragma("unroll") for (int g = 0; g < 4; ++g)                             \
            acc[4 + g] = __builtin_amdgcn_mfma_scale_f32_16x16x128_f8f6f4(        \
                a0, br[g * 4 + 2], acc[4 + g], 0, 0, 0, 127, 0, 127);             \
        _Pragma("unroll") for (int g = 0; g < 4; ++g)                             \
            acc[4 + g] = __builtin_amdgcn_mfma_scale_f32_16x16x128_f8f6f4(        \
                a1, br[g * 4 + 3], acc[4 + g], 0, 0, 0, 127, 0, 127);             \
        __builtin_amdgcn_s_setprio(0);                                            \
        _Pragma("unroll") for (int rg = 0; rg < 4; ++rg) {                        \
            bool mv = (T) < lenr[rg];                                             \
            _Pragma("unroll") for (int nb = 0; nb < 2; ++nb) {                    \
                int u = nb * 4 + rg;                                              \
                float gi = sigm(acc[nb * 4 + 0][rg]);                             \
                float gf = sigm(acc[nb * 4 + 1][rg]);                             \
                float gg = tanh_(acc[nb * 4 + 2][rg]);                            \
                float go = sigm(acc[nb * 4 + 3][rg]);                             \
                float cn = gf * cst[u] + gi * gg;                                 \
                float hn = go * tanh_(cn);                                        \
                cst[u] = mv ? cn : cst[u];                                        \
                hbf[u] = mv ? (__float_as_uint(hn) >> 16) : hbf[u];               \
                hq[u]  = mv ? f2fp8(hn) : hq[u];                                  \
                voff[u] += mv ? dstepB : 0;                                       \
                *(u16*)(hsp + voff[u]) = (u16)hbf[u];                             \
                (HW)[rg * 272 + nb * 16] = (u8)hq[u];                             \
            }                                                                     \
        }                                                                         \
        asm volatile("s_waitcnt lgkmcnt(0)\n\ts_barrier" ::: "memory");           \
    }

__global__ __launch_bounds__(512, 2) void k_lstm(const u16* __restrict__ xg2,
                                                 const u8* __restrict__ whh8,
                                                 const int* __restrict__ lengths,
                                                 u16* __restrict__ hs) {
    __shared__ u8 h8[2][4352];                         // [buf][16 rows][stride 272]
    int tid = threadIdx.x, lane = tid & 63, w = tid >> 6;
    int bx = blockIdx.x;
    int d = bx >> 3, grp = bx & 7;
    int c16 = lane & 15, q = lane >> 4;

    u8* hflat = &h8[0][0];
    for (int i = tid * 8; i < 8704; i += 4096) *(u64*)(hflat + i) = 0;

    int lenr[4];
#pragma unroll
    for (int rg = 0; rg < 4; ++rg) lenr[rg] = lengths[grp * 16 + q * 4 + rg];

    // register-resident fp8 weights: [g][nb][kk] i32x8 = 128 regs
    const u8* wbse = whh8 + ((size_t)((d * 8 + w) * 4)) * 8192;
    i32x8 br[16];
#pragma unroll
    for (int g = 0; g < 4; ++g)
#pragma unroll
        for (int nb = 0; nb < 2; ++nb)
#pragma unroll
            for (int kk = 0; kk < 2; ++kk) {
                const u8* p = wbse + (size_t)g * 8192 + ((nb * 2 + kk) * 64 + lane) * 32;
                i32x8 v;
                *(uint4*)&v       = *(const uint4*)p;
                *((uint4*)&v + 1) = *(const uint4*)(p + 16);
                br[g * 4 + nb * 2 + kk] = v;
            }

    float cst[8];
    u32 hq[8], hbf[8];                                 // frozen-carry h (fp8 / bf16 bits)
#pragma unroll
    for (int u = 0; u < 8; ++u) { cst[u] = 0.f; hq[u] = 0; hbf[u] = 0; }

    // hs byte offsets, advance-then-store (frozen when masked)
    u32 voff[8];
    int dstepB = d ? -1024 : 1024;
    u8* hsp = (u8*)hs;
#pragma unroll
    for (int nb = 0; nb < 2; ++nb)
#pragma unroll
        for (int rg = 0; rg < 4; ++rg) {
            int u = nb * 4 + rg;
            int row = q * 4 + rg;
            int hid = w * 32 + nb * 16 + c16;
            int p0 = d ? (lenr[rg] - 1) : 0;
            voff[u] = (u32)((((grp * 16 + row) * 128 + p0) * 512 + d * 256 + hid) * 2 - dstepB);
        }

    // xg: bias pre-folded; 64B/lane/step; xp points at the NEXT slab
    const u16* xslab = xg2 + ((size_t)(d * 8 + grp) * 128) * 16384 + (w * 64 + lane) * 32;
    u32 xqa[16], xqb[16];
    *(uint4*)(&xqa[0])  = *(const uint4*)(xslab);
    *(uint4*)(&xqa[4])  = *(const uint4*)(xslab + 8);
    *(uint4*)(&xqa[8])  = *(const uint4*)(xslab + 16);
    *(uint4*)(&xqa[12]) = *(const uint4*)(xslab + 24);
    const u16* xp = xslab + 16384;

    // A-frag LDS bases (row c16, k = q*32 + j, +kk*128 via imm), stride 272
    const u8* ha0 = hflat + (c16 * 272 + q * 32);
    const u8* ha1 = ha0 + 4352;
    // h write bases: row = q*4+rg (imm), hid = w*32 + nb*16 (imm) + c16
    u8* hw1 = hflat + (q * 1088 + w * 32 + c16);       // write target while reading buf0
    u8* hw0 = hw1 + 4352;

    __syncthreads();

    for (int t2 = 0; t2 < 128; t2 += 2) {
        LSTM_STEP(t2,     xqa, xqb, ha0, hw0)
        LSTM_STEP(t2 + 1, xqb, xqa, ha1, hw1)
    }
}

// ============================================================
// Emissions: emis[pos][17] = hs[pos][512] . proj_w[17][512] + proj_b
// ============================================================
__global__ __launch_bounds__(256) void k_emis(const u16* __restrict__ hs,
                                              const float* __restrict__ proj_w,
                                              const float* __restrict__ proj_b,
                                              float* __restrict__ emis) {
    __shared__ float pw[17 * 512];
    int tid = threadIdx.x;
    for (int i = tid; i < 17 * 512; i += 256) pw[i] = proj_w[i];
    __syncthreads();
    int lane = tid & 63, wv = tid >> 6;
    int pos = blockIdx.x * 4 + wv;
    float hv[8];
    const u16* hp = hs + (size_t)pos * 512 + lane * 8;
#pragma unroll
    for (int j = 0; j < 8; ++j) hv[j] = bf2f(hp[j]);
    for (int tg = 0; tg < 17; ++tg) {
        const float* wp = pw + tg * 512 + lane * 8;
        float s = 0.f;
#pragma unroll
        for (int j = 0; j < 8; ++j) s = fmaf(hv[j], wp[j], s);
#pragma unroll
        for (int off = 32; off; off >>= 1) s += __shfl_down(s, off);
        if (lane == 0) emis[(size_t)pos * 17 + tg] = s + proj_b[tg];
    }
}

// ============================================================
// CRF per-sample NLL. One 64-thread block per batch element.
// ============================================================
__global__ __launch_bounds__(64) void k_crf(const float* __restrict__ emis,
                                            const int* __restrict__ tags,
                                            const int* __restrict__ lengths,
                                            const float* __restrict__ trans,
                                            const float* __restrict__ start_trans,
                                            const float* __restrict__ end_trans,
                                            float* __restrict__ nll) {
    int b = blockIdx.x, lane = threadIdx.x;
    __shared__ float tr[289];
    __shared__ float al[17];
    __shared__ float scs;
    for (int i = lane; i < 289; i += 64) tr[i] = trans[i];
    int len = lengths[b];
    const int* tg = tags + (size_t)b * 128;
    const float* em = emis + (size_t)b * 128 * 17;
    __syncthreads();

    float sc = 0.f;
    for (int t = lane; t < len; t += 64) {
        sc += em[t * 17 + tg[t]];
        if (t >= 1) sc += tr[tg[t - 1] * 17 + tg[t]];
    }
#pragma unroll
    for (int off = 32; off; off >>= 1) sc += __shfl_down(sc, off);
    if (lane == 0) scs = sc + start_trans[tg[0]] + end_trans[tg[len - 1]];

    if (lane < 17) al[lane] = start_trans[lane] + em[lane];
    __syncthreads();
    for (int t = 1; t < len; ++t) {
        float anew = 0.f;
        if (lane < 17) {
            float m = -1e30f;
            for (int i = 0; i < 17; ++i) m = fmaxf(m, al[i] + tr[i * 17 + lane]);
            float s = 0.f;
            for (int i = 0; i < 17; ++i) s += __expf(al[i] + tr[i * 17 + lane] - m);
            anew = m + __logf(s) + em[t * 17 + lane];
        }
        __syncthreads();
        if (lane < 17) al[lane] = anew;
        __syncthreads();
    }
    float v = (lane < 17) ? al[lane] + end_trans[lane] : -1e30f;
    float m = v;
#pragma unroll
    for (int off = 32; off; off >>= 1) m = fmaxf(m, __shfl_xor(m, off));
    float s = (lane < 17) ? __expf(v - m) : 0.f;
#pragma unroll
    for (int off = 32; off; off >>= 1) s += __shfl_xor(s, off);
    if (lane == 0) nll[b] = (m + __logf(s)) - scs;
}

__global__ __launch_bounds__(128) void k_reduce(const float* __restrict__ nll, float* __restrict__ out) {
    int tid = threadIdx.x;
    float v = nll[tid];
#pragma unroll
    for (int off = 32; off; off >>= 1) v += __shfl_down(v, off);
    __shared__ float partial[2];
    if ((tid & 63) == 0) partial[tid >> 6] = v;
    __syncthreads();
    if (tid == 0) out[0] = partial[0] + partial[1];
}

// ============================================================
extern "C" void kernel_launch(void* const* d_in, const int* in_sizes, int n_in,
                              void* d_out, int out_size, void* d_ws, size_t ws_size,
                              hipStream_t stream) {
    (void)in_sizes; (void)n_in; (void)out_size; (void)ws_size;
    const int*   words       = (const int*)d_in[0];
    const int*   chars       = (const int*)d_in[1];
    const int*   tags        = (const int*)d_in[2];
    const int*   lengths     = (const int*)d_in[3];
    const float* word_emb    = (const float*)d_in[4];
    const float* char_emb    = (const float*)d_in[5];
    const float* conv_w      = (const float*)d_in[6];
    const float* conv_b      = (const float*)d_in[7];
    const float* w_ih_f      = (const float*)d_in[8];
    const float* w_hh_f      = (const float*)d_in[9];
    const float* b_f         = (const float*)d_in[10];
    const float* w_ih_b      = (const float*)d_in[11];
    const float* w_hh_b      = (const float*)d_in[12];
    const float* b_b         = (const float*)d_in[13];
    const float* proj_w      = (const float*)d_in[14];
    const float* proj_b      = (const float*)d_in[15];
    const float* trans       = (const float*)d_in[16];
    const float* start_trans = (const float*)d_in[17];
    const float* end_trans   = (const float*)d_in[18];

    char* ws = (char*)d_ws;
    u16* inp   = (u16*)(ws + OFF_INP);
    u16* wih   = (u16*)(ws + OFF_WIH);
    u8*  whh8  = (u8*)(ws + OFF_WHH);
    u16* xgb   = (u16*)(ws + OFF_XG);
    u16* hsb   = (u16*)(ws + OFF_HS);
    float* em  = (float*)(ws + OFF_EMIS);
    float* nll = (float*)(ws + OFF_NLL);

    k_prep_wih<<<2048, 128, 0, stream>>>(w_ih_f, w_ih_b, wih);
    k_prep_whh8<<<2048, 128, 0, stream>>>(w_hh_f, w_hh_b, whh8);
    k_embed_conv<<<NPOS, 128, 0, stream>>>(words, chars, word_emb, char_emb, conv_w, conv_b, inp);
    k_gemm<<<dim3(16, 128), 256, 0, stream>>>(inp, wih, xgb, lengths, b_f, b_b);
    k_lstm<<<16, 512, 0, stream>>>(xgb, whh8, lengths, hsb);
    k_emis<<<4096, 256, 0, stream>>>(hsb, proj_w, proj_b, em);
    k_crf<<<128, 64, 0, stream>>>(em, tags, lengths, trans, start_trans, end_trans, nll);
    k_reduce<<<1, 128, 0, stream>>>(nll, (float*)d_out);
}

// Round 10
// 478.899 us; speedup vs baseline: 1.5229x; 1.0018x over previous
//
#include <hip/hip_runtime.h>
#include <stdint.h>

typedef unsigned char u8;
typedef unsigned short u16;
typedef unsigned int u32;
typedef unsigned long long u64;

// ---- problem constants ----
// B=128 S=128 WL=16 V=50000 C=100 T=17 WE=300 CE=50 CF=50 K=3 H=256 D=350
#define NPOS 16384          // B*S
#define KPAD 384            // D padded to multiple of 64

typedef __attribute__((ext_vector_type(8))) short bf16x8;
typedef __attribute__((ext_vector_type(4))) float f32x4;
typedef __attribute__((ext_vector_type(8))) int i32x8;

__device__ __forceinline__ float bf2f(u16 u) { return __uint_as_float(((u32)u) << 16); }
__device__ __forceinline__ u16 f2bf(float f) {
    u32 u = __float_as_uint(f);
    u += 0x7fffu + ((u >> 16) & 1u);   // RNE
    return (u16)(u >> 16);
}
__device__ __forceinline__ float frcp(float x) {
#if __has_builtin(__builtin_amdgcn_rcpf)
    return __builtin_amdgcn_rcpf(x);       // v_rcp_f32, 1ulp — fine vs fp8 weights
#else
    return 1.0f / x;
#endif
}
__device__ __forceinline__ float sigm(float x) { return frcp(1.0f + __expf(-x)); }
__device__ __forceinline__ float tanh_(float x) { return fmaf(2.0f, frcp(1.0f + __expf(-2.0f * x)), -1.0f); }

// f32 -> fp8 e4m3fn (OCP), RNE, clamp to +-448. Prep-path (manual, no builtin risk).
__device__ u8 f2fp8_manual(float f) {
    u32 u = __float_as_uint(f);
    u32 s = (u >> 31) << 7;
    u32 ae = (u >> 23) & 255u;
    u32 m = u & 0x7fffffu;
    int e = (int)ae - 127;
    if (ae == 0) return (u8)s;                 // f32 subnormal -> 0
    if (e >= 9) return (u8)(s | 0x7e);         // >= 512 -> clamp 448
    if (e >= -6) {                             // e4m3 normal
        u32 mant = m >> 20;
        u32 rem = m & 0xfffffu;
        if (rem > 0x80000u || (rem == 0x80000u && (mant & 1u))) mant++;
        u32 ef = (u32)(e + 7);
        if (mant == 8u) { mant = 0u; ef++; }
        if (ef >= 16u || (ef == 15u && mant == 7u)) return (u8)(s | 0x7e);
        return (u8)(s | (ef << 3) | mant);
    }
    if (e < -10) return (u8)s;                 // underflow to 0
    int sb = 14 - e;                           // shift for units of 2^-9
    u32 X = 0x800000u | m;
    u32 mant = X >> sb;
    u32 rem = X & ((1u << sb) - 1u);
    u32 half = 1u << (sb - 1);
    if (rem > half || (rem == half && (mant & 1u))) mant++;
    if (mant >= 8u) return (u8)(s | (1u << 3)); // rounds to first normal 2^-6
    return (u8)(s | mant);
}

__device__ __forceinline__ u32 f2fp8(float f) {
#if __has_builtin(__builtin_amdgcn_cvt_pk_fp8_f32)
    return (u32)(__builtin_amdgcn_cvt_pk_fp8_f32(f, f, 0, false) & 0xff);
#else
    return (u32)f2fp8_manual(f);
#endif
}

// ---- workspace layout (bytes) ----
static constexpr size_t OFF_INP  = 0;                       // u16 [16384][384]   = 12582912
static constexpr size_t OFF_WIH  = 12582912;                // u16 [2048][384]    = 1572864
static constexpr size_t OFF_WHH  = 14155776;                // fp8 packed 512KB
static constexpr size_t OFF_XG   = 15204352;                // u16 xg2 repacked   = 67108864
static constexpr size_t OFF_HS   = 82313216;                // u16 [16384][512]   = 16777216
static constexpr size_t OFF_EMIS = 99090432;                // f32 [16384][17]    = 1114112
static constexpr size_t OFF_NLL  = 100204544;               // f32 [128]

// ============================================================
// Prep: pack [w_ih_f; w_ih_b] into bf16 [2048][384] (K padded w/ zeros)
// ============================================================
__global__ __launch_bounds__(128) void k_prep_wih(const float* __restrict__ wf,
                                                  const float* __restrict__ wb,
                                                  u16* __restrict__ wih) {
    int n = blockIdx.x, tid = threadIdx.x;
    const float* src = (n < 1024) ? (wf + (size_t)n * 350) : (wb + (size_t)(n - 1024) * 350);
    u16* dst = wih + (size_t)n * KPAD;
    for (int k = tid; k < KPAD; k += 128) dst[k] = (k < 350) ? f2bf(src[k]) : (u16)0;
}

// ============================================================
// Prep: w_hh (both dirs) -> fp8, packed for the MX-scaled 16x16x128 B-frag:
// whh8[((d*8+w)*4+g)*8192 + ((nb*2+kk)*64 + lane)*32 + j]
// where hid = w*32+nb*16+c16, lane = q*16+c16, k = kk*128 + q*32 + j
// ============================================================
__global__ __launch_bounds__(128) void k_prep_whh8(const float* __restrict__ wf,
                                                   const float* __restrict__ wb,
                                                   u8* __restrict__ whh8) {
    int bx = blockIdx.x, tid = threadIdx.x;
    int d = bx >> 10, row = bx & 1023;                 // row = gate*256 + hid
    const float* src = (d ? wb : wf) + (size_t)row * 256;
    int g = row >> 8, hid = row & 255;
    int w = hid >> 5, nb = (hid >> 4) & 1, c16 = hid & 15;
    u8* base = whh8 + ((size_t)((d * 8 + w) * 4 + g)) * 8192;
    for (int k = tid; k < 256; k += 128) {
        int kk = k >> 7, q = (k >> 5) & 3, j = k & 31;
        base[((nb * 2 + kk) * 64 + (q * 16 + c16)) * 32 + j] = f2fp8_manual(src[k]);
    }
}

// ============================================================
// Embedding + char conv + concat -> inp bf16 [16384][384]
// ============================================================
__global__ __launch_bounds__(128) void k_embed_conv(const int* __restrict__ words,
                                                    const int* __restrict__ chars,
                                                    const float* __restrict__ word_emb,
                                                    const float* __restrict__ char_emb,
                                                    const float* __restrict__ conv_w,
                                                    const float* __restrict__ conv_b,
                                                    u16* __restrict__ inp) {
    int pos = blockIdx.x, tid = threadIdx.x;
    __shared__ float ce[18 * 50];                      // rows 0 and 17 are zero pad
    const int* ch = chars + (size_t)pos * 16;
    for (int i = tid; i < 18 * 50; i += 128) {
        int row = i / 50, c = i - row * 50;
        float v = 0.f;
        if (row >= 1 && row <= 16) v = char_emb[(size_t)ch[row - 1] * 50 + c];
        ce[i] = v;
    }
    __syncthreads();
    {   // word embedding copy (float4 -> packed u64 of 4 bf16) + zero pad
        const float4* we4 = (const float4*)(word_emb + (size_t)words[pos] * 300);
        u16* op = inp + (size_t)pos * KPAD;
        if (tid < 75) {
            float4 v = we4[tid];
            u64 pk = (u64)f2bf(v.x) | ((u64)f2bf(v.y) << 16) |
                     ((u64)f2bf(v.z) << 32) | ((u64)f2bf(v.w) << 48);
            *(u64*)(op + tid * 4) = pk;
        }
        for (int c = 350 + tid; c < KPAD; c += 128) op[c] = 0;
    }
    if (tid < 100) {
        int oc = tid >> 1, half = tid & 1, t0 = half * 8;
        float acc[8];
#pragma unroll
        for (int tt = 0; tt < 8; ++tt) acc[tt] = 0.f;
        const float* wrow = conv_w + (size_t)oc * 150;
        for (int ic = 0; ic < 50; ++ic) {
#pragma unroll
            for (int k = 0; k < 3; ++k) {
                float wv = wrow[ic * 3 + k];
#pragma unroll
                for (int tt = 0; tt < 8; ++tt)
                    acc[tt] = fmaf(ce[(t0 + tt + k) * 50 + ic], wv, acc[tt]);
            }
        }
        float cb = conv_b[oc];
        float m = 0.f;                                  // relu floor
#pragma unroll
        for (int tt = 0; tt < 8; ++tt) m = fmaxf(m, acc[tt] + cb);
        m = fmaxf(m, __shfl_xor(m, 1));
        if (half == 0) inp[(size_t)pos * KPAD + 300 + oc] = f2bf(m);
    }
}

// ============================================================
// GEMM: inp[16384][384] @ wih[2048][384]^T (bf16 MFMA). N retiled so each
// wave owns (16 hid x 4 gates); single u64 store (4 bf16 gates, bias folded):
// slot = ((dd*8+grp)*128 + tt)*16384 + (hblk*64 + qq*16 + c16)*32 + (wc*4+rg)*4 + gate
// ============================================================
__global__ __launch_bounds__(256, 2) void k_gemm(const u16* __restrict__ A,
                                                 const u16* __restrict__ Bm,
                                                 u16* __restrict__ C,
                                                 const int* __restrict__ lengths,
                                                 const float* __restrict__ bias_f,
                                                 const float* __restrict__ bias_b) {
    __shared__ u16 sa[128 * 64];
    __shared__ u16 sb[128 * 64];
    int tid = threadIdx.x;
    int dd = blockIdx.x >> 3, hblk = blockIdx.x & 7;
    int m0 = blockIdx.y * 128;
    int lane = tid & 63, wid = tid >> 6;
    int wr = wid >> 1, wc = wid & 1;
    f32x4 acc[4][4];
#pragma unroll
    for (int mt = 0; mt < 4; ++mt)
#pragma unroll
        for (int g = 0; g < 4; ++g) acc[mt][g] = (f32x4){0.f, 0.f, 0.f, 0.f};

    for (int kt = 0; kt < 6; ++kt) {
#pragma unroll
        for (int c = 0; c < 4; ++c) {
            int idx = (c * 256 + tid) * 16;            // byte within 16KB tile
            int row = idx >> 7, colb = idx & 127;
            int dst = idx ^ ((row & 7) << 4);
            uint4 va = *(const uint4*)((const char*)A + (size_t)(m0 + row) * 768 + kt * 128 + colb);
            *(uint4*)((char*)sa + dst) = va;
            int bmrow = dd * 1024 + (row >> 5) * 256 + hblk * 32 + (row & 31);
            uint4 vb = *(const uint4*)((const char*)Bm + (size_t)bmrow * 768 + kt * 128 + colb);
            *(uint4*)((char*)sb + dst) = vb;
        }
        __syncthreads();
#pragma unroll
        for (int kc = 0; kc < 2; ++kc) {
            bf16x8 af[4], bf[4];
#pragma unroll
            for (int mt = 0; mt < 4; ++mt) {
                int row = wr * 64 + mt * 16 + (lane & 15);
                int off = (row * 128 + kc * 64 + (lane >> 4) * 16) ^ ((row & 7) << 4);
                af[mt] = *(const bf16x8*)((const char*)sa + off);
            }
#pragma unroll
            for (int g = 0; g < 4; ++g) {
                int row = g * 32 + wc * 16 + (lane & 15);
                int off = (row * 128 + kc * 64 + (lane >> 4) * 16) ^ ((row & 7) << 4);
                bf[g] = *(const bf16x8*)((const char*)sb + off);
            }
#pragma unroll
            for (int mt = 0; mt < 4; ++mt)
#pragma unroll
                for (int g = 0; g < 4; ++g)
                    acc[mt][g] = __builtin_amdgcn_mfma_f32_16x16x32_bf16(af[mt], bf[g], acc[mt][g], 0, 0, 0);
        }
        __syncthreads();
    }
    // epilogue: tile spans exactly batch element b = blockIdx.y (t = 0..127)
    int b = blockIdx.y;
    int len = lengths[b];
    int grp = b >> 4, row16 = b & 15;
    int qq = row16 >> 2, rg = row16 & 3;
    int c16 = lane & 15;
    int hid = hblk * 32 + wc * 16 + c16;
    const float* bias = dd ? bias_b : bias_f;
    float bv[4];
#pragma unroll
    for (int g = 0; g < 4; ++g) bv[g] = bias[g * 256 + hid];
    u32 base16 = (u32)((hblk * 64 + qq * 16 + c16) * 32 + (wc * 4 + rg) * 4);
    size_t slab0 = ((size_t)(dd * 8 + grp) * 128) * 16384;
#pragma unroll
    for (int mt = 0; mt < 4; ++mt)
#pragma unroll
        for (int r = 0; r < 4; ++r) {
            int t = wr * 64 + mt * 16 + (lane >> 4) * 4 + r;
            int tt = dd ? ((t < len) ? (len - 1 - t) : t) : t;
            u64 pk = (u64)f2bf(acc[mt][0][r] + bv[0]) |
                     ((u64)f2bf(acc[mt][1][r] + bv[1]) << 16) |
                     ((u64)f2bf(acc[mt][2][r] + bv[2]) << 32) |
                     ((u64)f2bf(acc[mt][3][r] + bv[3]) << 48);
            *(u64*)(C + slab0 + (size_t)tt * 16384 + base16) = pk;
        }
}

// ============================================================
// BiLSTM recurrence. 16 WGs = dir(2) x group(8, 16 rows). 512 thr = 8 waves.
// All 4 gates register-resident fp8 (i32x8 br[16] = 128 regs). h fp8
// double-buffered LDS, stride 272. MX-scaled MFMA 16x16x128 (unit scales).
// R10: per-step phase interleave MFMA-nb0 / EPI-nb0 / MFMA-nb1 / EPI-nb1
// pinned with sched_barrier(0) — in-order issue alternates matrix/VALU pipes
// so the 2 waves/SIMD anti-phase. Gate math uses combined reciprocals:
// gi*gg and go*tanh(cn) each share one rcp (8 trans/unit vs 10).
// ============================================================
#define LSTM_EPI(T, NB, HW)                                                       \
    _Pragma("unroll") for (int rg = 0; rg < 4; ++rg) {                            \
        int u = (NB) * 4 + rg;                                                    \
        bool mv = (T) < lenr[rg];                                                 \
        float ea = __expf(-acc[(NB) * 4 + 0][rg]);                                \
        float ec = __expf(-acc[(NB) * 4 + 1][rg]);                                \
        float eb = __expf(fminf(-2.0f * acc[(NB) * 4 + 2][rg], 60.0f));           \
        float ed = __expf(-acc[(NB) * 4 + 3][rg]);                                \
        float gfv = frcp(1.0f + ec);                                              \
        float gig = (1.0f - eb) * frcp((1.0f + ea) * (1.0f + eb));                \
        float cn = gfv * cst[u] + gig;                                            \
        float ee = __expf(fminf(-2.0f * cn, 60.0f));                              \
        float hn = (1.0f - ee) * frcp((1.0f + ed) * (1.0f + ee));                 \
        cst[u] = mv ? cn : cst[u];                                                \
        hbf[u] = mv ? (__float_as_uint(hn) >> 16) : hbf[u];                       \
        hq[u]  = mv ? f2fp8(hn) : hq[u];                                          \
        voff[u] += mv ? dstepB : 0;                                               \
        *(u16*)(hsp + voff[u]) = (u16)hbf[u];                                     \
        (HW)[rg * 272 + (NB) * 16] = (u8)hq[u];                                   \
    }

#define LSTM_STEP(T, XC, XN, HA, HW)                                              \
    {                                                                             \
        *(uint4*)(&XN[0])  = *(const uint4*)(xp);                                 \
        *(uint4*)(&XN[4])  = *(const uint4*)(xp + 8);                             \
        *(uint4*)(&XN[8])  = *(const uint4*)(xp + 16);                            \
        *(uint4*)(&XN[12]) = *(const uint4*)(xp + 24);                            \
        xp += 16384;                                                              \
        f32x4 acc[8];                                                             \
        _Pragma("unroll") for (int nb = 0; nb < 2; ++nb)                          \
            _Pragma("unroll") for (int rg = 0; rg < 4; ++rg) {                    \
                int u = nb * 4 + rg;                                              \
                u32 w0 = XC[u * 2], w1 = XC[u * 2 + 1];                           \
                acc[nb * 4 + 0][rg] = __uint_as_float(w0 << 16);                  \
                acc[nb * 4 + 1][rg] = __uint_as_float(w0 & 0xffff0000u);          \
                acc[nb * 4 + 2][rg] = __uint_as_float(w1 << 16);                  \
                acc[nb * 4 + 3][rg] = __uint_as_float(w1 & 0xffff0000u);          \
            }                                                                     \
        i32x8 a0, a1;                                                             \
        *(uint4*)&a0       = *(const uint4*)(HA);                                 \
        *((uint4*)&a0 + 1) = *(const uint4*)(HA + 16);                            \
        *(uint4*)&a1       = *(const uint4*)(HA + 128);                           \
        *((uint4*)&a1 + 1) = *(const uint4*)(HA + 144);                           \
        __builtin_amdgcn_s_setprio(1);                                            \
        _Pragma("unroll") for (int g = 0; g < 4; ++g)                             \
            acc[g] = __builtin_amdgcn_mfma_scale_f32_16x16x128_f8f6f4(            \
                a0, br[g * 4 + 0], acc[g], 0, 0, 0, 127, 0, 127);                 \
        _Pragma("unroll") for (int g = 0; g < 4; ++g)                             \
            acc[g] = __builtin_amdgcn_mfma_scale_f32_16x16x128_f8f6f4(            \
                a1, br[g * 4 + 1], acc[g], 0, 0, 0, 127, 0, 127);                 \
        __builtin_amdgcn_s_setprio(0);                                            \
        __builtin_amdgcn_sched_barrier(0);                                        \
        LSTM_EPI(T, 0, HW)                                                        \
        __builtin_amdgcn_sched_barrier(0);                                        \
        __builtin_amdgcn_s_setprio(1);                                            \
        _Pragma("unroll") for (int g = 0; g < 4; ++g)                             \
            acc[4 + g] = __builtin_amdgcn_mfma_scale_f32_16x16x128_f8f6f4(        \
                a0, br[g * 4 + 2], acc[4 + g], 0, 0, 0, 127, 0, 127);             \
        _Pragma("unroll") for (int g = 0; g < 4; ++g)                             \
            acc[4 + g] = __builtin_amdgcn_mfma_scale_f32_16x16x128_f8f6f4(        \
                a1, br[g * 4 + 3], acc[4 + g], 0, 0, 0, 127, 0, 127);             \
        __builtin_amdgcn_s_setprio(0);                                            \
        __builtin_amdgcn_sched_barrier(0);                                        \
        LSTM_EPI(T, 1, HW)                                                        \
        asm volatile("s_waitcnt lgkmcnt(0)\n\ts_barrier" ::: "memory");           \
    }

__global__ __launch_bounds__(512, 2) void k_lstm(const u16* __restrict__ xg2,
                                                 const u8* __restrict__ whh8,
                                                 const int* __restrict__ lengths,
                                                 u16* __restrict__ hs) {
    __shared__ u8 h8[2][4352];                         // [buf][16 rows][stride 272]
    int tid = threadIdx.x, lane = tid & 63, w = tid >> 6;
    int bx = blockIdx.x;
    int d = bx >> 3, grp = bx & 7;
    int c16 = lane & 15, q = lane >> 4;

    u8* hflat = &h8[0][0];
    for (int i = tid * 8; i < 8704; i += 4096) *(u64*)(hflat + i) = 0;

    int lenr[4];
#pragma unroll
    for (int rg = 0; rg < 4; ++rg) lenr[rg] = lengths[grp * 16 + q * 4 + rg];

    // register-resident fp8 weights: [g][nb][kk] i32x8 = 128 regs
    const u8* wbse = whh8 + ((size_t)((d * 8 + w) * 4)) * 8192;
    i32x8 br[16];
#pragma unroll
    for (int g = 0; g < 4; ++g)
#pragma unroll
        for (int nb = 0; nb < 2; ++nb)
#pragma unroll
            for (int kk = 0; kk < 2; ++kk) {
                const u8* p = wbse + (size_t)g * 8192 + ((nb * 2 + kk) * 64 + lane) * 32;
                i32x8 v;
                *(uint4*)&v       = *(const uint4*)p;
                *((uint4*)&v + 1) = *(const uint4*)(p + 16);
                br[g * 4 + nb * 2 + kk] = v;
            }

    float cst[8];
    u32 hq[8], hbf[8];                                 // frozen-carry h (fp8 / bf16 bits)
#pragma unroll
    for (int u = 0; u < 8; ++u) { cst[u] = 0.f; hq[u] = 0; hbf[u] = 0; }

    // hs byte offsets, advance-then-store (frozen when masked)
    u32 voff[8];
    int dstepB = d ? -1024 : 1024;
    u8* hsp = (u8*)hs;
#pragma unroll
    for (int nb = 0; nb < 2; ++nb)
#pragma unroll
        for (int rg = 0; rg < 4; ++rg) {
            int u = nb * 4 + rg;
            int row = q * 4 + rg;
            int hid = w * 32 + nb * 16 + c16;
            int p0 = d ? (lenr[rg] - 1) : 0;
            voff[u] = (u32)((((grp * 16 + row) * 128 + p0) * 512 + d * 256 + hid) * 2 - dstepB);
        }

    // xg: bias pre-folded; 64B/lane/step; xp points at the NEXT slab
    const u16* xslab = xg2 + ((size_t)(d * 8 + grp) * 128) * 16384 + (w * 64 + lane) * 32;
    u32 xqa[16], xqb[16];
    *(uint4*)(&xqa[0])  = *(const uint4*)(xslab);
    *(uint4*)(&xqa[4])  = *(const uint4*)(xslab + 8);
    *(uint4*)(&xqa[8])  = *(const uint4*)(xslab + 16);
    *(uint4*)(&xqa[12]) = *(const uint4*)(xslab + 24);
    const u16* xp = xslab + 16384;

    // A-frag LDS bases (row c16, k = q*32 + j, +kk*128 via imm), stride 272
    const u8* ha0 = hflat + (c16 * 272 + q * 32);
    const u8* ha1 = ha0 + 4352;
    // h write bases: row = q*4+rg (imm), hid = w*32 + nb*16 (imm) + c16
    u8* hw1 = hflat + (q * 1088 + w * 32 + c16);       // write target while reading buf0
    u8* hw0 = hw1 + 4352;

    __syncthreads();

    for (int t2 = 0; t2 < 128; t2 += 2) {
        LSTM_STEP(t2,     xqa, xqb, ha0, hw0)
        LSTM_STEP(t2 + 1, xqb, xqa, ha1, hw1)
    }
}

// ============================================================
// Emissions: emis[pos][17] = hs[pos][512] . proj_w[17][512] + proj_b
// 16 positions per block (4 per wave) -> 8x fewer proj_w LDS fills.
// ============================================================
__global__ __launch_bounds__(256) void k_emis(const u16* __restrict__ hs,
                                              const float* __restrict__ proj_w,
                                              const float* __restrict__ proj_b,
                                              float* __restrict__ emis) {
    __shared__ float pw[17 * 512];
    int tid = threadIdx.x;
    for (int i = tid; i < 17 * 512; i += 256) pw[i] = proj_w[i];
    __syncthreads();
    int lane = tid & 63, wv = tid >> 6;
    int pos0 = blockIdx.x * 16 + wv * 4;
    float hv[4][8];
#pragma unroll
    for (int p = 0; p < 4; ++p) {
        bf16x8 v = *(const bf16x8*)(hs + (size_t)(pos0 + p) * 512 + lane * 8);
#pragma unroll
        for (int j = 0; j < 8; ++j) hv[p][j] = bf2f((u16)v[j]);
    }
    for (int tg = 0; tg < 17; ++tg) {
        const float* wp = pw + tg * 512 + lane * 8;
        float wr[8];
#pragma unroll
        for (int j = 0; j < 8; ++j) wr[j] = wp[j];
        float s[4];
#pragma unroll
        for (int p = 0; p < 4; ++p) {
            float acc = 0.f;
#pragma unroll
            for (int j = 0; j < 8; ++j) acc = fmaf(hv[p][j], wr[j], acc);
            s[p] = acc;
        }
#pragma unroll
        for (int off = 32; off; off >>= 1)
#pragma unroll
            for (int p = 0; p < 4; ++p) s[p] += __shfl_down(s[p], off);
        if (lane < 4) emis[(size_t)(pos0 + lane) * 17 + tg] = __shfl(s[lane], 0) * 0.f + // placeholder avoided
                      0.f; // (overwritten below)
        if (lane == 0) {
#pragma unroll
            for (int p = 0; p < 4; ++p) emis[(size_t)(pos0 + p) * 17 + tg] = s[p] + proj_b[tg];
        }
    }
}

// ============================================================
// CRF per-sample NLL. One 64-thread block per batch element.
// ============================================================
__global__ __launch_bounds__(64) void k_crf(const float* __restrict__ emis,
                                            const int* __restrict__ tags,
                                            const int* __restrict__ lengths,
                                            const float* __restrict__ trans,
                                            const float* __restrict__ start_trans,
                                            const float* __restrict__ end_trans,
                                            float* __restrict__ nll) {
    int b = blockIdx.x, lane = threadIdx.x;
    __shared__ float tr[289];
    __shared__ float al[17];
    __shared__ float scs;
    for (int i = lane; i < 289; i += 64) tr[i] = trans[i];
    int len = lengths[b];
    const int* tg = tags + (size_t)b * 128;
    const float* em = emis + (size_t)b * 128 * 17;
    __syncthreads();

    float sc = 0.f;
    for (int t = lane; t < len; t += 64) {
        sc += em[t * 17 + tg[t]];
        if (t >= 1) sc += tr[tg[t - 1] * 17 + tg[t]];
    }
#pragma unroll
    for (int off = 32; off; off >>= 1) sc += __shfl_down(sc, off);
    if (lane == 0) scs = sc + start_trans[tg[0]] + end_trans[tg[len - 1]];

    if (lane < 17) al[lane] = start_trans[lane] + em[lane];
    __syncthreads();
    for (int t = 1; t < len; ++t) {
        float anew = 0.f;
        if (lane < 17) {
            float m = -1e30f;
            for (int i = 0; i < 17; ++i) m = fmaxf(m, al[i] + tr[i * 17 + lane]);
            float s = 0.f;
            for (int i = 0; i < 17; ++i) s += __expf(al[i] + tr[i * 17 + lane] - m);
            anew = m + __logf(s) + em[t * 17 + lane];
        }
        __syncthreads();
        if (lane < 17) al[lane] = anew;
        __syncthreads();
    }
    float v = (lane < 17) ? al[lane] + end_trans[lane] : -1e30f;
    float m = v;
#pragma unroll
    for (int off = 32; off; off >>= 1) m = fmaxf(m, __shfl_xor(m, off));
    float s = (lane < 17) ? __expf(v - m) : 0.f;
#pragma unroll
    for (int off = 32; off; off >>= 1) s += __shfl_xor(s, off);
    if (lane == 0) nll[b] = (m + __logf(s)) - scs;
}

__global__ __launch_bounds__(128) void k_reduce(const float* __restrict__ nll, float* __restrict__ out) {
    int tid = threadIdx.x;
    float v = nll[tid];
#pragma unroll
    for (int off = 32; off; off >>= 1) v += __shfl_down(v, off);
    __shared__ float partial[2];
    if ((tid & 63) == 0) partial[tid >> 6] = v;
    __syncthreads();
    if (tid == 0) out[0] = partial[0] + partial[1];
}

// ============================================================
extern "C" void kernel_launch(void* const* d_in, const int* in_sizes, int n_in,
                              void* d_out, int out_size, void* d_ws, size_t ws_size,
                              hipStream_t stream) {
    (void)in_sizes; (void)n_in; (void)out_size; (void)ws_size;
    const int*   words       = (const int*)d_in[0];
    const int*   chars       = (const int*)d_in[1];
    const int*   tags        = (const int*)d_in[2];
    const int*   lengths     = (const int*)d_in[3];
    const float* word_emb    = (const float*)d_in[4];
    const float* char_emb    = (const float*)d_in[5];
    const float* conv_w      = (const float*)d_in[6];
    const float* conv_b      = (const float*)d_in[7];
    const float* w_ih_f      = (const float*)d_in[8];
    const float* w_hh_f      = (const float*)d_in[9];
    const float* b_f         = (const float*)d_in[10];
    const float* w_ih_b      = (const float*)d_in[11];
    const float* w_hh_b      = (const float*)d_in[12];
    const float* b_b         = (const float*)d_in[13];
    const float* proj_w      = (const float*)d_in[14];
    const float* proj_b      = (const float*)d_in[15];
    const float* trans       = (const float*)d_in[16];
    const float* start_trans = (const float*)d_in[17];
    const float* end_trans   = (const float*)d_in[18];

    char* ws = (char*)d_ws;
    u16* inp   = (u16*)(ws + OFF_INP);
    u16* wih   = (u16*)(ws + OFF_WIH);
    u8*  whh8  = (u8*)(ws + OFF_WHH);
    u16* xgb   = (u16*)(ws + OFF_XG);
    u16* hsb   = (u16*)(ws + OFF_HS);
    float* em  = (float*)(ws + OFF_EMIS);
    float* nll = (float*)(ws + OFF_NLL);

    k_prep_wih<<<2048, 128, 0, stream>>>(w_ih_f, w_ih_b, wih);
    k_prep_whh8<<<2048, 128, 0, stream>>>(w_hh_f, w_hh_b, whh8);
    k_embed_conv<<<NPOS, 128, 0, stream>>>(words, chars, word_emb, char_emb, conv_w, conv_b, inp);
    k_gemm<<<dim3(16, 128), 256, 0, stream>>>(inp, wih, xgb, lengths, b_f, b_b);
    k_lstm<<<16, 512, 0, stream>>>(xgb, whh8, lengths, hsb);
    k_emis<<<1024, 256, 0, stream>>>(hsb, proj_w, proj_b, em);
    k_crf<<<128, 64, 0, stream>>>(em, tags, lengths, trans, start_trans, end_trans, nll);
    k_reduce<<<1, 128, 0, stream>>>(nll, (float*)d_out);
}

// Round 11
// 445.896 us; speedup vs baseline: 1.6356x; 1.0740x over previous
//
#include <hip/hip_runtime.h>
#include <stdint.h>

typedef unsigned char u8;
typedef unsigned short u16;
typedef unsigned int u32;
typedef unsigned long long u64;

// ---- problem constants ----
// B=128 S=128 WL=16 V=50000 C=100 T=17 WE=300 CE=50 CF=50 K=3 H=256 D=350
#define NPOS 16384          // B*S
#define KPAD 384            // D padded to multiple of 64

typedef __attribute__((ext_vector_type(8))) short bf16x8;
typedef __attribute__((ext_vector_type(4))) float f32x4;
typedef __attribute__((ext_vector_type(8))) int i32x8;

__device__ __forceinline__ float bf2f(u16 u) { return __uint_as_float(((u32)u) << 16); }
__device__ __forceinline__ u16 f2bf(float f) {
    u32 u = __float_as_uint(f);
    u += 0x7fffu + ((u >> 16) & 1u);   // RNE
    return (u16)(u >> 16);
}
__device__ __forceinline__ float frcp(float x) {
#if __has_builtin(__builtin_amdgcn_rcpf)
    return __builtin_amdgcn_rcpf(x);       // v_rcp_f32, 1ulp — fine vs fp8 weights
#else
    return 1.0f / x;
#endif
}
__device__ __forceinline__ float sigm(float x) { return frcp(1.0f + __expf(-x)); }
__device__ __forceinline__ float tanh_(float x) { return fmaf(2.0f, frcp(1.0f + __expf(-2.0f * x)), -1.0f); }

// f32 -> fp8 e4m3fn (OCP), RNE, clamp to +-448. Prep-path (manual, no builtin risk).
__device__ u8 f2fp8_manual(float f) {
    u32 u = __float_as_uint(f);
    u32 s = (u >> 31) << 7;
    u32 ae = (u >> 23) & 255u;
    u32 m = u & 0x7fffffu;
    int e = (int)ae - 127;
    if (ae == 0) return (u8)s;                 // f32 subnormal -> 0
    if (e >= 9) return (u8)(s | 0x7e);         // >= 512 -> clamp 448
    if (e >= -6) {                             // e4m3 normal
        u32 mant = m >> 20;
        u32 rem = m & 0xfffffu;
        if (rem > 0x80000u || (rem == 0x80000u && (mant & 1u))) mant++;
        u32 ef = (u32)(e + 7);
        if (mant == 8u) { mant = 0u; ef++; }
        if (ef >= 16u || (ef == 15u && mant == 7u)) return (u8)(s | 0x7e);
        return (u8)(s | (ef << 3) | mant);
    }
    if (e < -10) return (u8)s;                 // underflow to 0
    int sb = 14 - e;                           // shift for units of 2^-9
    u32 X = 0x800000u | m;
    u32 mant = X >> sb;
    u32 rem = X & ((1u << sb) - 1u);
    u32 half = 1u << (sb - 1);
    if (rem > half || (rem == half && (mant & 1u))) mant++;
    if (mant >= 8u) return (u8)(s | (1u << 3)); // rounds to first normal 2^-6
    return (u8)(s | mant);
}

__device__ __forceinline__ u32 f2fp8(float f) {
#if __has_builtin(__builtin_amdgcn_cvt_pk_fp8_f32)
    return (u32)(__builtin_amdgcn_cvt_pk_fp8_f32(f, f, 0, false) & 0xff);
#else
    return (u32)f2fp8_manual(f);
#endif
}

// ---- workspace layout (bytes) ----
static constexpr size_t OFF_INP  = 0;                       // u16 [16384][384]   = 12582912
static constexpr size_t OFF_WIH  = 12582912;                // u16 [2048][384]    = 1572864
static constexpr size_t OFF_WHH  = 14155776;                // fp8 packed 512KB
static constexpr size_t OFF_XG   = 15204352;                // u16 xg2 repacked   = 67108864
static constexpr size_t OFF_HS   = 82313216;                // u16 [16384][512]   = 16777216
static constexpr size_t OFF_EMIS = 99090432;                // f32 [16384][17]    = 1114112
static constexpr size_t OFF_NLL  = 100204544;               // f32 [128]
static constexpr size_t OFF_WT   = OFF_XG;                  // f32 wt[150][52] (transient; overwritten by xg later)

// ============================================================
// Prep0: transpose conv_w [50 oc][50 ic][3 k] -> wt[(ic*3+k)][52 pad][oc]
// (lives in the XG region; consumed by k_front's conv, then overwritten)
// ============================================================
__global__ __launch_bounds__(256) void k_prep0(const float* __restrict__ conv_w,
                                               float* __restrict__ wt) {
    int idx = blockIdx.x * 256 + threadIdx.x;
    if (idx < 7500) {
        int oc = idx / 150, r = idx - oc * 150;        // r = ic*3+k
        wt[r * 52 + oc] = conv_w[oc * 150 + r];
    }
}

// ============================================================
// Fused front kernel: blockIdx dispatch
//   b in [0,2048):    embedding + char conv (8 positions per block)
//   b in [2048,3072): pack w_ih -> bf16 [2048][384]
//   b in [3072,4096): pack w_hh -> fp8 MX layout
// ============================================================
__global__ __launch_bounds__(256) void k_front(const int* __restrict__ words,
                                               const int* __restrict__ chars,
                                               const float* __restrict__ word_emb,
                                               const float* __restrict__ char_emb,
                                               const float* __restrict__ wt,
                                               const float* __restrict__ conv_b,
                                               u16* __restrict__ inp,
                                               const float* __restrict__ wihf,
                                               const float* __restrict__ wihb,
                                               u16* __restrict__ wih,
                                               const float* __restrict__ whf,
                                               const float* __restrict__ whb,
                                               u8* __restrict__ whh8) {
    __shared__ float ce_t[8][50][20];                  // [pos][ic][t], t=0 & 17..19 zero pad
    int b = blockIdx.x, tid = threadIdx.x;

    if (b >= 2048) {
        if (b < 3072) {                                // ---- w_ih pack ----
            int n = (b - 2048) * 2 + (tid >> 7);
            int t128 = tid & 127;
            const float* src = (n < 1024) ? (wihf + (size_t)n * 350) : (wihb + (size_t)(n - 1024) * 350);
            u16* dst = wih + (size_t)n * KPAD;
            for (int k = t128; k < KPAD; k += 128) dst[k] = (k < 350) ? f2bf(src[k]) : (u16)0;
        } else {                                       // ---- w_hh pack (MX 16x16x128 B-frag) ----
            int gr = (b - 3072) * 2 + (tid >> 7);
            int t128 = tid & 127;
            int d = gr >> 10, row = gr & 1023;         // row = gate*256 + hid
            const float* src = (d ? whb : whf) + (size_t)row * 256;
            int g = row >> 8, hid = row & 255;
            int w = hid >> 5, nb = (hid >> 4) & 1, c16 = hid & 15;
            u8* base = whh8 + ((size_t)((d * 8 + w) * 4 + g)) * 8192;
            for (int k = t128; k < 256; k += 128) {
                int kk = k >> 7, q = (k >> 5) & 3, j = k & 31;
                base[((nb * 2 + kk) * 64 + (q * 16 + c16)) * 32 + j] = f2fp8_manual(src[k]);
            }
        }
        return;
    }

    // ---- embedding + char conv, 8 positions ----
    int pos0 = b * 8;

    // ce_t fill: threads 0..127 -> (pos, char c); threads 128..255 zero pad cols
    if (tid < 128) {
        int p = tid >> 4, c = tid & 15;
        int ch = chars[(size_t)(pos0 + p) * 16 + c];
        const float* src = char_emb + (size_t)ch * 50;
#pragma unroll
        for (int i = 0; i < 25; ++i) {
            float2 v = *(const float2*)(src + i * 2);
            ce_t[p][i * 2][c + 1] = v.x;
            ce_t[p][i * 2 + 1][c + 1] = v.y;
        }
    } else {
        int base = tid - 128;
        for (int i = base; i < 1600; i += 128) {
            int p = i / 200, rem = i - p * 200;
            int ic = rem >> 2, cid = rem & 3;
            ce_t[p][ic][cid == 0 ? 0 : 16 + cid] = 0.f;
        }
    }

    // word embedding: 8 pos x 75 float4 = 600 tasks
    for (int r = 0; r < 3; ++r) {
        int idx = r * 256 + tid;
        if (idx < 600) {
            int p = idx / 75, v = idx - p * 75;
            const float4* we4 = (const float4*)(word_emb + (size_t)words[pos0 + p] * 300);
            float4 val = we4[v];
            u64 pk = (u64)f2bf(val.x) | ((u64)f2bf(val.y) << 16) |
                     ((u64)f2bf(val.z) << 32) | ((u64)f2bf(val.w) << 48);
            *(u64*)(inp + (size_t)(pos0 + p) * KPAD + v * 4) = pk;
        }
    }
    // zero pad inp[350..383]: 8 pos x 17 u32
    {
        int idx = tid;
        if (idx < 136) {
            int p = idx / 17, j = idx - p * 17;
            *(u32*)(inp + (size_t)(pos0 + p) * KPAD + 350 + 2 * j) = 0;
        }
    }
    __syncthreads();

    // conv: 200 tasks = 8 pos x 25 oc-pairs; each task: 2 oc x 16 t
    if (tid < 200) {
        int p = tid / 25, ocp = tid - p * 25;
        int oc = ocp * 2;
        float acc0[16], acc1[16];
#pragma unroll
        for (int t = 0; t < 16; ++t) { acc0[t] = 0.f; acc1[t] = 0.f; }
        const float* cebase = &ce_t[p][0][0];
        for (int ic = 0; ic < 50; ++ic) {
            float c[20];
            const float* cp = cebase + ic * 20;
#pragma unroll
            for (int i = 0; i < 5; ++i) *(float4*)(&c[i * 4]) = *(const float4*)(cp + i * 4);
#pragma unroll
            for (int k = 0; k < 3; ++k) {
                float2 wv = *(const float2*)(wt + (ic * 3 + k) * 52 + oc);
#pragma unroll
                for (int t = 0; t < 16; ++t) {
                    acc0[t] = fmaf(c[t + k], wv.x, acc0[t]);
                    acc1[t] = fmaf(c[t + k], wv.y, acc1[t]);
                }
            }
        }
        float cb0 = conv_b[oc], cb1 = conv_b[oc + 1];
        float m0 = 0.f, m1 = 0.f;
#pragma unroll
        for (int t = 0; t < 16; ++t) {
            m0 = fmaxf(m0, acc0[t] + cb0);
            m1 = fmaxf(m1, acc1[t] + cb1);
        }
        u16* op = inp + (size_t)(pos0 + p) * KPAD + 300 + oc;
        op[0] = f2bf(m0);
        op[1] = f2bf(m1);
    }
}

// ============================================================
// GEMM: inp[16384][384] @ wih[2048][384]^T (bf16 MFMA). N retiled so each
// wave owns (16 hid x 4 gates); single u64 store (4 bf16 gates, bias folded):
// slot = ((dd*8+grp)*128 + tt)*16384 + (hblk*64 + qq*16 + c16)*32 + (wc*4+rg)*4 + gate
// ============================================================
__global__ __launch_bounds__(256, 2) void k_gemm(const u16* __restrict__ A,
                                                 const u16* __restrict__ Bm,
                                                 u16* __restrict__ C,
                                                 const int* __restrict__ lengths,
                                                 const float* __restrict__ bias_f,
                                                 const float* __restrict__ bias_b) {
    __shared__ u16 sa[128 * 64];
    __shared__ u16 sb[128 * 64];
    int tid = threadIdx.x;
    int dd = blockIdx.x >> 3, hblk = blockIdx.x & 7;
    int m0 = blockIdx.y * 128;
    int lane = tid & 63, wid = tid >> 6;
    int wr = wid >> 1, wc = wid & 1;
    f32x4 acc[4][4];
#pragma unroll
    for (int mt = 0; mt < 4; ++mt)
#pragma unroll
        for (int g = 0; g < 4; ++g) acc[mt][g] = (f32x4){0.f, 0.f, 0.f, 0.f};

    for (int kt = 0; kt < 6; ++kt) {
#pragma unroll
        for (int c = 0; c < 4; ++c) {
            int idx = (c * 256 + tid) * 16;            // byte within 16KB tile
            int row = idx >> 7, colb = idx & 127;
            int dst = idx ^ ((row & 7) << 4);
            uint4 va = *(const uint4*)((const char*)A + (size_t)(m0 + row) * 768 + kt * 128 + colb);
            *(uint4*)((char*)sa + dst) = va;
            int bmrow = dd * 1024 + (row >> 5) * 256 + hblk * 32 + (row & 31);
            uint4 vb = *(const uint4*)((const char*)Bm + (size_t)bmrow * 768 + kt * 128 + colb);
            *(uint4*)((char*)sb + dst) = vb;
        }
        __syncthreads();
#pragma unroll
        for (int kc = 0; kc < 2; ++kc) {
            bf16x8 af[4], bf[4];
#pragma unroll
            for (int mt = 0; mt < 4; ++mt) {
                int row = wr * 64 + mt * 16 + (lane & 15);
                int off = (row * 128 + kc * 64 + (lane >> 4) * 16) ^ ((row & 7) << 4);
                af[mt] = *(const bf16x8*)((const char*)sa + off);
            }
#pragma unroll
            for (int g = 0; g < 4; ++g) {
                int row = g * 32 + wc * 16 + (lane & 15);
                int off = (row * 128 + kc * 64 + (lane >> 4) * 16) ^ ((row & 7) << 4);
                bf[g] = *(const bf16x8*)((const char*)sb + off);
            }
#pragma unroll
            for (int mt = 0; mt < 4; ++mt)
#pragma unroll
                for (int g = 0; g < 4; ++g)
                    acc[mt][g] = __builtin_amdgcn_mfma_f32_16x16x32_bf16(af[mt], bf[g], acc[mt][g], 0, 0, 0);
        }
        __syncthreads();
    }
    // epilogue: tile spans exactly batch element b = blockIdx.y (t = 0..127)
    int b = blockIdx.y;
    int len = lengths[b];
    int grp = b >> 4, row16 = b & 15;
    int qq = row16 >> 2, rg = row16 & 3;
    int c16 = lane & 15;
    int hid = hblk * 32 + wc * 16 + c16;
    const float* bias = dd ? bias_b : bias_f;
    float bv[4];
#pragma unroll
    for (int g = 0; g < 4; ++g) bv[g] = bias[g * 256 + hid];
    u32 base16 = (u32)((hblk * 64 + qq * 16 + c16) * 32 + (wc * 4 + rg) * 4);
    size_t slab0 = ((size_t)(dd * 8 + grp) * 128) * 16384;
#pragma unroll
    for (int mt = 0; mt < 4; ++mt)
#pragma unroll
        for (int r = 0; r < 4; ++r) {
            int t = wr * 64 + mt * 16 + (lane >> 4) * 4 + r;
            int tt = dd ? ((t < len) ? (len - 1 - t) : t) : t;
            u64 pk = (u64)f2bf(acc[mt][0][r] + bv[0]) |
                     ((u64)f2bf(acc[mt][1][r] + bv[1]) << 16) |
                     ((u64)f2bf(acc[mt][2][r] + bv[2]) << 32) |
                     ((u64)f2bf(acc[mt][3][r] + bv[3]) << 48);
            *(u64*)(C + slab0 + (size_t)tt * 16384 + base16) = pk;
        }
}

// ============================================================
// BiLSTM recurrence (R9 version — best measured). 16 WGs = dir(2) x group(8).
// All 4 gates register-resident fp8 (i32x8 br[16] = 128 regs). h fp8
// double-buffered LDS, stride 272. MX-scaled MFMA 16x16x128 (unit scales).
// acc initialized from xg (C-operand); branchless cndmask epilogue.
// ============================================================
#define LSTM_STEP(T, XC, XN, HA, HW)                                              \
    {                                                                             \
        *(uint4*)(&XN[0])  = *(const uint4*)(xp);                                 \
        *(uint4*)(&XN[4])  = *(const uint4*)(xp + 8);                             \
        *(uint4*)(&XN[8])  = *(const uint4*)(xp + 16);                            \
        *(uint4*)(&XN[12]) = *(const uint4*)(xp + 24);                            \
        xp += 16384;                                                              \
        f32x4 acc[8];                                                             \
        _Pragma("unroll") for (int nb = 0; nb < 2; ++nb)                          \
            _Pragma("unroll") for (int rg = 0; rg < 4; ++rg) {                    \
                int u = nb * 4 + rg;                                              \
                u32 w0 = XC[u * 2], w1 = XC[u * 2 + 1];                           \
                acc[nb * 4 + 0][rg] = __uint_as_float(w0 << 16);                  \
                acc[nb * 4 + 1][rg] = __uint_as_float(w0 & 0xffff0000u);          \
                acc[nb * 4 + 2][rg] = __uint_as_float(w1 << 16);                  \
                acc[nb * 4 + 3][rg] = __uint_as_float(w1 & 0xffff0000u);          \
            }                                                                     \
        i32x8 a0, a1;                                                             \
        *(uint4*)&a0       = *(const uint4*)(HA);                                 \
        *((uint4*)&a0 + 1) = *(const uint4*)(HA + 16);                            \
        *(uint4*)&a1       = *(const uint4*)(HA + 128);                           \
        *((uint4*)&a1 + 1) = *(const uint4*)(HA + 144);                           \
        __builtin_amdgcn_s_setprio(1);                                            \
        _Pragma("unroll") for (int g = 0; g < 4; ++g)                             \
            acc[g] = __builtin_amdgcn_mfma_scale_f32_16x16x128_f8f6f4(            \
                a0, br[g * 4 + 0], acc[g], 0, 0, 0, 127, 0, 127);                 \
        _Pragma("unroll") for (int g = 0; g < 4; ++g)                             \
            acc[g] = __builtin_amdgcn_mfma_scale_f32_16x16x128_f8f6f4(            \
                a1, br[g * 4 + 1], acc[g], 0, 0, 0, 127, 0, 127);                 \
        _Pragma("unroll") for (int g = 0; g < 4; ++g)                             \
            acc[4 + g] = __builtin_amdgcn_mfma_scale_f32_16x16x128_f8f6f4(        \
                a0, br[g * 4 + 2], acc[4 + g], 0, 0, 0, 127, 0, 127);             \
        _Pragma("unroll") for (int g = 0; g < 4; ++g)                             \
            acc[4 + g] = __builtin_amdgcn_mfma_scale_f32_16x16x128_f8f6f4(        \
                a1, br[g * 4 + 3], acc[4 + g], 0, 0, 0, 127, 0, 127);             \
        __builtin_amdgcn_s_setprio(0);                                            \
        _Pragma("unroll") for (int rg = 0; rg < 4; ++rg) {                        \
            bool mv = (T) < lenr[rg];                                             \
            _Pragma("unroll") for (int nb = 0; nb < 2; ++nb) {                    \
                int u = nb * 4 + rg;                                              \
                float gi = sigm(acc[nb * 4 + 0][rg]);                             \
                float gf = sigm(acc[nb * 4 + 1][rg]);                             \
                float gg = tanh_(acc[nb * 4 + 2][rg]);                            \
                float go = sigm(acc[nb * 4 + 3][rg]);                             \
                float cn = gf * cst[u] + gi * gg;                                 \
                float hn = go * tanh_(cn);                                        \
                cst[u] = mv ? cn : cst[u];                                        \
                hbf[u] = mv ? (__float_as_uint(hn) >> 16) : hbf[u];               \
                hq[u]  = mv ? f2fp8(hn) : hq[u];                                  \
                voff[u] += mv ? dstepB : 0;                                       \
                *(u16*)(hsp + voff[u]) = (u16)hbf[u];                             \
                (HW)[rg * 272 + nb * 16] = (u8)hq[u];                             \
            }                                                                     \
        }                                                                         \
        asm volatile("s_waitcnt lgkmcnt(0)\n\ts_barrier" ::: "memory");           \
    }

__global__ __launch_bounds__(512, 2) void k_lstm(const u16* __restrict__ xg2,
                                                 const u8* __restrict__ whh8,
                                                 const int* __restrict__ lengths,
                                                 u16* __restrict__ hs) {
    __shared__ u8 h8[2][4352];                         // [buf][16 rows][stride 272]
    int tid = threadIdx.x, lane = tid & 63, w = tid >> 6;
    int bx = blockIdx.x;
    int d = bx >> 3, grp = bx & 7;
    int c16 = lane & 15, q = lane >> 4;

    u8* hflat = &h8[0][0];
    for (int i = tid * 8; i < 8704; i += 4096) *(u64*)(hflat + i) = 0;

    int lenr[4];
#pragma unroll
    for (int rg = 0; rg < 4; ++rg) lenr[rg] = lengths[grp * 16 + q * 4 + rg];

    // register-resident fp8 weights: [g][nb][kk] i32x8 = 128 regs
    const u8* wbse = whh8 + ((size_t)((d * 8 + w) * 4)) * 8192;
    i32x8 br[16];
#pragma unroll
    for (int g = 0; g < 4; ++g)
#pragma unroll
        for (int nb = 0; nb < 2; ++nb)
#pragma unroll
            for (int kk = 0; kk < 2; ++kk) {
                const u8* p = wbse + (size_t)g * 8192 + ((nb * 2 + kk) * 64 + lane) * 32;
                i32x8 v;
                *(uint4*)&v       = *(const uint4*)p;
                *((uint4*)&v + 1) = *(const uint4*)(p + 16);
                br[g * 4 + nb * 2 + kk] = v;
            }

    float cst[8];
    u32 hq[8], hbf[8];                                 // frozen-carry h (fp8 / bf16 bits)
#pragma unroll
    for (int u = 0; u < 8; ++u) { cst[u] = 0.f; hq[u] = 0; hbf[u] = 0; }

    // hs byte offsets, advance-then-store (frozen when masked)
    u32 voff[8];
    int dstepB = d ? -1024 : 1024;
    u8* hsp = (u8*)hs;
#pragma unroll
    for (int nb = 0; nb < 2; ++nb)
#pragma unroll
        for (int rg = 0; rg < 4; ++rg) {
            int u = nb * 4 + rg;
            int row = q * 4 + rg;
            int hid = w * 32 + nb * 16 + c16;
            int p0 = d ? (lenr[rg] - 1) : 0;
            voff[u] = (u32)((((grp * 16 + row) * 128 + p0) * 512 + d * 256 + hid) * 2 - dstepB);
        }

    // xg: bias pre-folded; 64B/lane/step; xp points at the NEXT slab
    const u16* xslab = xg2 + ((size_t)(d * 8 + grp) * 128) * 16384 + (w * 64 + lane) * 32;
    u32 xqa[16], xqb[16];
    *(uint4*)(&xqa[0])  = *(const uint4*)(xslab);
    *(uint4*)(&xqa[4])  = *(const uint4*)(xslab + 8);
    *(uint4*)(&xqa[8])  = *(const uint4*)(xslab + 16);
    *(uint4*)(&xqa[12]) = *(const uint4*)(xslab + 24);
    const u16* xp = xslab + 16384;

    // A-frag LDS bases (row c16, k = q*32 + j, +kk*128 via imm), stride 272
    const u8* ha0 = hflat + (c16 * 272 + q * 32);
    const u8* ha1 = ha0 + 4352;
    // h write bases: row = q*4+rg (imm), hid = w*32 + nb*16 (imm) + c16
    u8* hw1 = hflat + (q * 1088 + w * 32 + c16);       // write target while reading buf0
    u8* hw0 = hw1 + 4352;

    __syncthreads();

    for (int t2 = 0; t2 < 128; t2 += 2) {
        LSTM_STEP(t2,     xqa, xqb, ha0, hw0)
        LSTM_STEP(t2 + 1, xqb, xqa, ha1, hw1)
    }
}

// ============================================================
// Emissions: emis[pos][17] = hs[pos][512] . proj_w[17][512] + proj_b
// 16 positions per block (4 per wave).
// ============================================================
__global__ __launch_bounds__(256) void k_emis(const u16* __restrict__ hs,
                                              const float* __restrict__ proj_w,
                                              const float* __restrict__ proj_b,
                                              float* __restrict__ emis) {
    __shared__ float pw[17 * 512];
    int tid = threadIdx.x;
    for (int i = tid; i < 17 * 512; i += 256) pw[i] = proj_w[i];
    __syncthreads();
    int lane = tid & 63, wv = tid >> 6;
    int pos0 = blockIdx.x * 16 + wv * 4;
    float hv[4][8];
#pragma unroll
    for (int p = 0; p < 4; ++p) {
        bf16x8 v = *(const bf16x8*)(hs + (size_t)(pos0 + p) * 512 + lane * 8);
#pragma unroll
        for (int j = 0; j < 8; ++j) hv[p][j] = bf2f((u16)v[j]);
    }
    for (int tg = 0; tg < 17; ++tg) {
        const float* wp = pw + tg * 512 + lane * 8;
        float wr[8];
#pragma unroll
        for (int j = 0; j < 8; ++j) wr[j] = wp[j];
        float s[4];
#pragma unroll
        for (int p = 0; p < 4; ++p) {
            float acc = 0.f;
#pragma unroll
            for (int j = 0; j < 8; ++j) acc = fmaf(hv[p][j], wr[j], acc);
            s[p] = acc;
        }
#pragma unroll
        for (int off = 32; off; off >>= 1)
#pragma unroll
            for (int p = 0; p < 4; ++p) s[p] += __shfl_down(s[p], off);
        if (lane == 0) {
#pragma unroll
            for (int p = 0; p < 4; ++p) emis[(size_t)(pos0 + p) * 17 + tg] = s[p] + proj_b[tg];
        }
    }
}

// ============================================================
// CRF per-sample NLL. One 64-thread block per batch element.
// ============================================================
__global__ __launch_bounds__(64) void k_crf(const float* __restrict__ emis,
                                            const int* __restrict__ tags,
                                            const int* __restrict__ lengths,
                                            const float* __restrict__ trans,
                                            const float* __restrict__ start_trans,
                                            const float* __restrict__ end_trans,
                                            float* __restrict__ nll) {
    int b = blockIdx.x, lane = threadIdx.x;
    __shared__ float tr[289];
    __shared__ float al[17];
    __shared__ float scs;
    for (int i = lane; i < 289; i += 64) tr[i] = trans[i];
    int len = lengths[b];
    const int* tg = tags + (size_t)b * 128;
    const float* em = emis + (size_t)b * 128 * 17;
    __syncthreads();

    float sc = 0.f;
    for (int t = lane; t < len; t += 64) {
        sc += em[t * 17 + tg[t]];
        if (t >= 1) sc += tr[tg[t - 1] * 17 + tg[t]];
    }
#pragma unroll
    for (int off = 32; off; off >>= 1) sc += __shfl_down(sc, off);
    if (lane == 0) scs = sc + start_trans[tg[0]] + end_trans[tg[len - 1]];

    if (lane < 17) al[lane] = start_trans[lane] + em[lane];
    __syncthreads();
    for (int t = 1; t < len; ++t) {
        float anew = 0.f;
        if (lane < 17) {
            float m = -1e30f;
            for (int i = 0; i < 17; ++i) m = fmaxf(m, al[i] + tr[i * 17 + lane]);
            float s = 0.f;
            for (int i = 0; i < 17; ++i) s += __expf(al[i] + tr[i * 17 + lane] - m);
            anew = m + __logf(s) + em[t * 17 + lane];
        }
        __syncthreads();
        if (lane < 17) al[lane] = anew;
        __syncthreads();
    }
    float v = (lane < 17) ? al[lane] + end_trans[lane] : -1e30f;
    float m = v;
#pragma unroll
    for (int off = 32; off; off >>= 1) m = fmaxf(m, __shfl_xor(m, off));
    float s = (lane < 17) ? __expf(v - m) : 0.f;
#pragma unroll
    for (int off = 32; off; off >>= 1) s += __shfl_xor(s, off);
    if (lane == 0) nll[b] = (m + __logf(s)) - scs;
}

__global__ __launch_bounds__(128) void k_reduce(const float* __restrict__ nll, float* __restrict__ out) {
    int tid = threadIdx.x;
    float v = nll[tid];
#pragma unroll
    for (int off = 32; off; off >>= 1) v += __shfl_down(v, off);
    __shared__ float partial[2];
    if ((tid & 63) == 0) partial[tid >> 6] = v;
    __syncthreads();
    if (tid == 0) out[0] = partial[0] + partial[1];
}

// ============================================================
extern "C" void kernel_launch(void* const* d_in, const int* in_sizes, int n_in,
                              void* d_out, int out_size, void* d_ws, size_t ws_size,
                              hipStream_t stream) {
    (void)in_sizes; (void)n_in; (void)out_size; (void)ws_size;
    const int*   words       = (const int*)d_in[0];
    const int*   chars       = (const int*)d_in[1];
    const int*   tags        = (const int*)d_in[2];
    const int*   lengths     = (const int*)d_in[3];
    const float* word_emb    = (const float*)d_in[4];
    const float* char_emb    = (const float*)d_in[5];
    const float* conv_w      = (const float*)d_in[6];
    const float* conv_b      = (const float*)d_in[7];
    const float* w_ih_f      = (const float*)d_in[8];
    const float* w_hh_f      = (const float*)d_in[9];
    const float* b_f         = (const float*)d_in[10];
    const float* w_ih_b      = (const float*)d_in[11];
    const float* w_hh_b      = (const float*)d_in[12];
    const float* b_b         = (const float*)d_in[13];
    const float* proj_w      = (const float*)d_in[14];
    const float* proj_b      = (const float*)d_in[15];
    const float* trans       = (const float*)d_in[16];
    const float* start_trans = (const float*)d_in[17];
    const float* end_trans   = (const float*)d_in[18];

    char* ws = (char*)d_ws;
    u16* inp   = (u16*)(ws + OFF_INP);
    u16* wih   = (u16*)(ws + OFF_WIH);
    u8*  whh8  = (u8*)(ws + OFF_WHH);
    u16* xgb   = (u16*)(ws + OFF_XG);
    u16* hsb   = (u16*)(ws + OFF_HS);
    float* em  = (float*)(ws + OFF_EMIS);
    float* nll = (float*)(ws + OFF_NLL);
    float* wt  = (float*)(ws + OFF_WT);

    k_prep0<<<30, 256, 0, stream>>>(conv_w, wt);
    k_front<<<4096, 256, 0, stream>>>(words, chars, word_emb, char_emb, wt, conv_b, inp,
                                      w_ih_f, w_ih_b, wih, w_hh_f, w_hh_b, whh8);
    k_gemm<<<dim3(16, 128), 256, 0, stream>>>(inp, wih, xgb, lengths, b_f, b_b);
    k_lstm<<<16, 512, 0, stream>>>(xgb, whh8, lengths, hsb);
    k_emis<<<1024, 256, 0, stream>>>(hsb, proj_w, proj_b, em);
    k_crf<<<128, 64, 0, stream>>>(em, tags, lengths, trans, start_trans, end_trans, nll);
    k_reduce<<<1, 128, 0, stream>>>(nll, (float*)d_out);
}

// Round 12
// 435.436 us; speedup vs baseline: 1.6749x; 1.0240x over previous
//
#include <hip/hip_runtime.h>
#include <stdint.h>

typedef unsigned char u8;
typedef unsigned short u16;
typedef unsigned int u32;
typedef unsigned long long u64;

// ---- problem constants ----
// B=128 S=128 WL=16 V=50000 C=100 T=17 WE=300 CE=50 CF=50 K=3 H=256 D=350
#define NPOS 16384          // B*S
#define KPAD 384            // D padded to multiple of 64

typedef __attribute__((ext_vector_type(8))) short bf16x8;
typedef __attribute__((ext_vector_type(4))) float f32x4;
typedef __attribute__((ext_vector_type(8))) int i32x8;

__device__ __forceinline__ float bf2f(u16 u) { return __uint_as_float(((u32)u) << 16); }
__device__ __forceinline__ u16 f2bf(float f) {
    u32 u = __float_as_uint(f);
    u += 0x7fffu + ((u >> 16) & 1u);   // RNE
    return (u16)(u >> 16);
}
__device__ __forceinline__ float frcp(float x) {
#if __has_builtin(__builtin_amdgcn_rcpf)
    return __builtin_amdgcn_rcpf(x);       // v_rcp_f32, 1ulp — fine vs fp8 weights
#else
    return 1.0f / x;
#endif
}
__device__ __forceinline__ float sigm(float x) { return frcp(1.0f + __expf(-x)); }
__device__ __forceinline__ float tanh_(float x) { return fmaf(2.0f, frcp(1.0f + __expf(-2.0f * x)), -1.0f); }

// f32 -> fp8 e4m3fn (OCP), RNE, clamp to +-448. Prep-path (manual, no builtin risk).
__device__ u8 f2fp8_manual(float f) {
    u32 u = __float_as_uint(f);
    u32 s = (u >> 31) << 7;
    u32 ae = (u >> 23) & 255u;
    u32 m = u & 0x7fffffu;
    int e = (int)ae - 127;
    if (ae == 0) return (u8)s;                 // f32 subnormal -> 0
    if (e >= 9) return (u8)(s | 0x7e);         // >= 512 -> clamp 448
    if (e >= -6) {                             // e4m3 normal
        u32 mant = m >> 20;
        u32 rem = m & 0xfffffu;
        if (rem > 0x80000u || (rem == 0x80000u && (mant & 1u))) mant++;
        u32 ef = (u32)(e + 7);
        if (mant == 8u) { mant = 0u; ef++; }
        if (ef >= 16u || (ef == 15u && mant == 7u)) return (u8)(s | 0x7e);
        return (u8)(s | (ef << 3) | mant);
    }
    if (e < -10) return (u8)s;                 // underflow to 0
    int sb = 14 - e;                           // shift for units of 2^-9
    u32 X = 0x800000u | m;
    u32 mant = X >> sb;
    u32 rem = X & ((1u << sb) - 1u);
    u32 half = 1u << (sb - 1);
    if (rem > half || (rem == half && (mant & 1u))) mant++;
    if (mant >= 8u) return (u8)(s | (1u << 3)); // rounds to first normal 2^-6
    return (u8)(s | mant);
}

__device__ __forceinline__ u32 f2fp8(float f) {
#if __has_builtin(__builtin_amdgcn_cvt_pk_fp8_f32)
    return (u32)(__builtin_amdgcn_cvt_pk_fp8_f32(f, f, 0, false) & 0xff);
#else
    return (u32)f2fp8_manual(f);
#endif
}

// ---- workspace layout (bytes) ----
static constexpr size_t OFF_INP  = 0;                       // u16 [16384][384]   = 12582912
static constexpr size_t OFF_WIH  = 12582912;                // u16 [2048][384]    = 1572864
static constexpr size_t OFF_WHH  = 14155776;                // fp8 packed 512KB
static constexpr size_t OFF_XG   = 15204352;                // u16 xg2 repacked   = 67108864
static constexpr size_t OFF_HS   = 82313216;                // u16 [16384][512]   = 16777216
static constexpr size_t OFF_EMIS = 99090432;                // f32 [16384][17]    = 1114112
static constexpr size_t OFF_NLL  = 100204544;               // f32 [128]
static constexpr size_t OFF_WT   = OFF_XG;                  // f32 wt[150][52] (transient; overwritten by xg later)

// ============================================================
// Prep0: transpose conv_w [50 oc][50 ic][3 k] -> wt[(ic*3+k)][52 pad][oc]
// ============================================================
__global__ __launch_bounds__(256) void k_prep0(const float* __restrict__ conv_w,
                                               float* __restrict__ wt) {
    int idx = blockIdx.x * 256 + threadIdx.x;
    if (idx < 7500) {
        int oc = idx / 150, r = idx - oc * 150;        // r = ic*3+k
        wt[r * 52 + oc] = conv_w[oc * 150 + r];
    }
}

// ============================================================
// Fused front kernel: blockIdx dispatch
//   b in [0,2048):    embedding + char conv (8 positions per block) —
//                     blocks fully past the row's length exit immediately.
//   b in [2048,3072): pack w_ih -> bf16 [2048][384]
//   b in [3072,4096): pack w_hh -> fp8 MX layout
// ============================================================
__global__ __launch_bounds__(256) void k_front(const int* __restrict__ words,
                                               const int* __restrict__ chars,
                                               const float* __restrict__ word_emb,
                                               const float* __restrict__ char_emb,
                                               const float* __restrict__ wt,
                                               const float* __restrict__ conv_b,
                                               u16* __restrict__ inp,
                                               const float* __restrict__ wihf,
                                               const float* __restrict__ wihb,
                                               u16* __restrict__ wih,
                                               const float* __restrict__ whf,
                                               const float* __restrict__ whb,
                                               u8* __restrict__ whh8,
                                               const int* __restrict__ lengths) {
    __shared__ float ce_t[8][50][20];                  // [pos][ic][t], t=0 & 17..19 zero pad
    int b = blockIdx.x, tid = threadIdx.x;

    if (b >= 2048) {
        if (b < 3072) {                                // ---- w_ih pack ----
            int n = (b - 2048) * 2 + (tid >> 7);
            int t128 = tid & 127;
            const float* src = (n < 1024) ? (wihf + (size_t)n * 350) : (wihb + (size_t)(n - 1024) * 350);
            u16* dst = wih + (size_t)n * KPAD;
            for (int k = t128; k < KPAD; k += 128) dst[k] = (k < 350) ? f2bf(src[k]) : (u16)0;
        } else {                                       // ---- w_hh pack (MX 16x16x128 B-frag) ----
            int gr = (b - 3072) * 2 + (tid >> 7);
            int t128 = tid & 127;
            int d = gr >> 10, row = gr & 1023;         // row = gate*256 + hid
            const float* src = (d ? whb : whf) + (size_t)row * 256;
            int g = row >> 8, hid = row & 255;
            int w = hid >> 5, nb = (hid >> 4) & 1, c16 = hid & 15;
            u8* base = whh8 + ((size_t)((d * 8 + w) * 4 + g)) * 8192;
            for (int k = t128; k < 256; k += 128) {
                int kk = k >> 7, q = (k >> 5) & 3, j = k & 31;
                base[((nb * 2 + kk) * 64 + (q * 16 + c16)) * 32 + j] = f2fp8_manual(src[k]);
            }
        }
        return;
    }

    // length skip: this block's 8 positions are t in [t0, t0+8) of batch row b>>4
    if (((b & 15) * 8) >= lengths[b >> 4]) return;

    // ---- embedding + char conv, 8 positions ----
    int pos0 = b * 8;

    // ce_t fill: threads 0..127 -> (pos, char c); threads 128..255 zero pad cols
    if (tid < 128) {
        int p = tid >> 4, c = tid & 15;
        int ch = chars[(size_t)(pos0 + p) * 16 + c];
        const float* src = char_emb + (size_t)ch * 50;
#pragma unroll
        for (int i = 0; i < 25; ++i) {
            float2 v = *(const float2*)(src + i * 2);
            ce_t[p][i * 2][c + 1] = v.x;
            ce_t[p][i * 2 + 1][c + 1] = v.y;
        }
    } else {
        int base = tid - 128;
        for (int i = base; i < 1600; i += 128) {
            int p = i / 200, rem = i - p * 200;
            int ic = rem >> 2, cid = rem & 3;
            ce_t[p][ic][cid == 0 ? 0 : 16 + cid] = 0.f;
        }
    }

    // word embedding: 8 pos x 75 float4 = 600 tasks
    for (int r = 0; r < 3; ++r) {
        int idx = r * 256 + tid;
        if (idx < 600) {
            int p = idx / 75, v = idx - p * 75;
            const float4* we4 = (const float4*)(word_emb + (size_t)words[pos0 + p] * 300);
            float4 val = we4[v];
            u64 pk = (u64)f2bf(val.x) | ((u64)f2bf(val.y) << 16) |
                     ((u64)f2bf(val.z) << 32) | ((u64)f2bf(val.w) << 48);
            *(u64*)(inp + (size_t)(pos0 + p) * KPAD + v * 4) = pk;
        }
    }
    // zero pad inp[350..383]: 8 pos x 17 u32
    {
        int idx = tid;
        if (idx < 136) {
            int p = idx / 17, j = idx - p * 17;
            *(u32*)(inp + (size_t)(pos0 + p) * KPAD + 350 + 2 * j) = 0;
        }
    }
    __syncthreads();

    // conv: 200 tasks = 8 pos x 25 oc-pairs; each task: 2 oc x 16 t
    if (tid < 200) {
        int p = tid / 25, ocp = tid - p * 25;
        int oc = ocp * 2;
        float acc0[16], acc1[16];
#pragma unroll
        for (int t = 0; t < 16; ++t) { acc0[t] = 0.f; acc1[t] = 0.f; }
        const float* cebase = &ce_t[p][0][0];
        for (int ic = 0; ic < 50; ++ic) {
            float c[20];
            const float* cp = cebase + ic * 20;
#pragma unroll
            for (int i = 0; i < 5; ++i) *(float4*)(&c[i * 4]) = *(const float4*)(cp + i * 4);
#pragma unroll
            for (int k = 0; k < 3; ++k) {
                float2 wv = *(const float2*)(wt + (ic * 3 + k) * 52 + oc);
#pragma unroll
                for (int t = 0; t < 16; ++t) {
                    acc0[t] = fmaf(c[t + k], wv.x, acc0[t]);
                    acc1[t] = fmaf(c[t + k], wv.y, acc1[t]);
                }
            }
        }
        float cb0 = conv_b[oc], cb1 = conv_b[oc + 1];
        float m0 = 0.f, m1 = 0.f;
#pragma unroll
        for (int t = 0; t < 16; ++t) {
            m0 = fmaxf(m0, acc0[t] + cb0);
            m1 = fmaxf(m1, acc1[t] + cb1);
        }
        u16* op = inp + (size_t)(pos0 + p) * KPAD + 300 + oc;
        op[0] = f2bf(m0);
        op[1] = f2bf(m1);
    }
}

// ============================================================
// GEMM: inp[16384][384] @ wih[2048][384]^T (bf16 MFMA). N retiled so each
// wave owns (16 hid x 4 gates); single u64 store (4 bf16 gates, bias folded).
// mt-subtiles whose 16 t-rows start past the row length are skipped entirely
// (scalar branch via readfirstlane — no exec-masked MFMA).
// ============================================================
__global__ __launch_bounds__(256, 2) void k_gemm(const u16* __restrict__ A,
                                                 const u16* __restrict__ Bm,
                                                 u16* __restrict__ C,
                                                 const int* __restrict__ lengths,
                                                 const float* __restrict__ bias_f,
                                                 const float* __restrict__ bias_b) {
    __shared__ u16 sa[128 * 64];
    __shared__ u16 sb[128 * 64];
    int tid = threadIdx.x;
    int dd = blockIdx.x >> 3, hblk = blockIdx.x & 7;
    int m0 = blockIdx.y * 128;
    int lane = tid & 63, wid = tid >> 6;
    int wr = wid >> 1, wc = wid & 1;
    int b = blockIdx.y;
    int len = lengths[b];
    int lenS = __builtin_amdgcn_readfirstlane(len);
    int wrS = __builtin_amdgcn_readfirstlane(wr);

    f32x4 acc[4][4];
#pragma unroll
    for (int mt = 0; mt < 4; ++mt)
#pragma unroll
        for (int g = 0; g < 4; ++g) acc[mt][g] = (f32x4){0.f, 0.f, 0.f, 0.f};

    for (int kt = 0; kt < 6; ++kt) {
#pragma unroll
        for (int c = 0; c < 4; ++c) {
            int idx = (c * 256 + tid) * 16;            // byte within 16KB tile
            int row = idx >> 7, colb = idx & 127;
            int dst = idx ^ ((row & 7) << 4);
            uint4 va = *(const uint4*)((const char*)A + (size_t)(m0 + row) * 768 + kt * 128 + colb);
            *(uint4*)((char*)sa + dst) = va;
            int bmrow = dd * 1024 + (row >> 5) * 256 + hblk * 32 + (row & 31);
            uint4 vb = *(const uint4*)((const char*)Bm + (size_t)bmrow * 768 + kt * 128 + colb);
            *(uint4*)((char*)sb + dst) = vb;
        }
        __syncthreads();
#pragma unroll
        for (int kc = 0; kc < 2; ++kc) {
            bf16x8 bf[4];
#pragma unroll
            for (int g = 0; g < 4; ++g) {
                int row = g * 32 + wc * 16 + (lane & 15);
                int off = (row * 128 + kc * 64 + (lane >> 4) * 16) ^ ((row & 7) << 4);
                bf[g] = *(const bf16x8*)((const char*)sb + off);
            }
#pragma unroll
            for (int mt = 0; mt < 4; ++mt) {
                if (wrS * 64 + mt * 16 < lenS) {       // scalar skip of dead t-subtiles
                    int row = wr * 64 + mt * 16 + (lane & 15);
                    int off = (row * 128 + kc * 64 + (lane >> 4) * 16) ^ ((row & 7) << 4);
                    bf16x8 af = *(const bf16x8*)((const char*)sa + off);
#pragma unroll
                    for (int g = 0; g < 4; ++g)
                        acc[mt][g] = __builtin_amdgcn_mfma_f32_16x16x32_bf16(af, bf[g], acc[mt][g], 0, 0, 0);
                }
            }
        }
        __syncthreads();
    }
    // epilogue
    int grp = b >> 4, row16 = b & 15;
    int qq = row16 >> 2, rg = row16 & 3;
    int c16 = lane & 15;
    int hid = hblk * 32 + wc * 16 + c16;
    const float* bias = dd ? bias_b : bias_f;
    float bv[4];
#pragma unroll
    for (int g = 0; g < 4; ++g) bv[g] = bias[g * 256 + hid];
    u32 base16 = (u32)((hblk * 64 + qq * 16 + c16) * 32 + (wc * 4 + rg) * 4);
    size_t slab0 = ((size_t)(dd * 8 + grp) * 128) * 16384;
#pragma unroll
    for (int mt = 0; mt < 4; ++mt) {
        if (wrS * 64 + mt * 16 < lenS) {
#pragma unroll
            for (int r = 0; r < 4; ++r) {
                int t = wr * 64 + mt * 16 + (lane >> 4) * 4 + r;
                int tt = dd ? ((t < len) ? (len - 1 - t) : t) : t;
                u64 pk = (u64)f2bf(acc[mt][0][r] + bv[0]) |
                         ((u64)f2bf(acc[mt][1][r] + bv[1]) << 16) |
                         ((u64)f2bf(acc[mt][2][r] + bv[2]) << 32) |
                         ((u64)f2bf(acc[mt][3][r] + bv[3]) << 48);
                *(u64*)(C + slab0 + (size_t)tt * 16384 + base16) = pk;
            }
        }
    }
}

// ============================================================
// BiLSTM recurrence (R9 structure). 16 WGs = dir(2) x group(8).
// All 4 gates register-resident fp8 (i32x8 br[16] = 128 regs). h fp8
// double-buffered LDS, stride 272. MX-scaled MFMA 16x16x128 (unit scales).
// acc initialized from xg (C-operand); branchless cndmask epilogue.
// R12: loop terminates at the WG-wide max length (wave-uniform).
// ============================================================
#define LSTM_STEP(T, XC, XN, HA, HW)                                              \
    {                                                                             \
        *(uint4*)(&XN[0])  = *(const uint4*)(xp);                                 \
        *(uint4*)(&XN[4])  = *(const uint4*)(xp + 8);                             \
        *(uint4*)(&XN[8])  = *(const uint4*)(xp + 16);                            \
        *(uint4*)(&XN[12]) = *(const uint4*)(xp + 24);                            \
        xp += 16384;                                                              \
        f32x4 acc[8];                                                             \
        _Pragma("unroll") for (int nb = 0; nb < 2; ++nb)                          \
            _Pragma("unroll") for (int rg = 0; rg < 4; ++rg) {                    \
                int u = nb * 4 + rg;                                              \
                u32 w0 = XC[u * 2], w1 = XC[u * 2 + 1];                           \
                acc[nb * 4 + 0][rg] = __uint_as_float(w0 << 16);                  \
                acc[nb * 4 + 1][rg] = __uint_as_float(w0 & 0xffff0000u);          \
                acc[nb * 4 + 2][rg] = __uint_as_float(w1 << 16);                  \
                acc[nb * 4 + 3][rg] = __uint_as_float(w1 & 0xffff0000u);          \
            }                                                                     \
        i32x8 a0, a1;                                                             \
        *(uint4*)&a0       = *(const uint4*)(HA);                                 \
        *((uint4*)&a0 + 1) = *(const uint4*)(HA + 16);                            \
        *(uint4*)&a1       = *(const uint4*)(HA + 128);                           \
        *((uint4*)&a1 + 1) = *(const uint4*)(HA + 144);                           \
        __builtin_amdgcn_s_setprio(1);                                            \
        _Pragma("unroll") for (int g = 0; g < 4; ++g)                             \
            acc[g] = __builtin_amdgcn_mfma_scale_f32_16x16x128_f8f6f4(            \
                a0, br[g * 4 + 0], acc[g], 0, 0, 0, 127, 0, 127);                 \
        _Pragma("unroll") for (int g = 0; g < 4; ++g)                             \
            acc[g] = __builtin_amdgcn_mfma_scale_f32_16x16x128_f8f6f4(            \
                a1, br[g * 4 + 1], acc[g], 0, 0, 0, 127, 0, 127);                 \
        _Pragma("unroll") for (int g = 0; g < 4; ++g)                             \
            acc[4 + g] = __builtin_amdgcn_mfma_scale_f32_16x16x128_f8f6f4(        \
                a0, br[g * 4 + 2], acc[4 + g], 0, 0, 0, 127, 0, 127);             \
        _Pragma("unroll") for (int g = 0; g < 4; ++g)                             \
            acc[4 + g] = __builtin_amdgcn_mfma_scale_f32_16x16x128_f8f6f4(        \
                a1, br[g * 4 + 3], acc[4 + g], 0, 0, 0, 127, 0, 127);             \
        __builtin_amdgcn_s_setprio(0);                                            \
        _Pragma("unroll") for (int rg = 0; rg < 4; ++rg) {                        \
            bool mv = (T) < lenr[rg];                                             \
            _Pragma("unroll") for (int nb = 0; nb < 2; ++nb) {                    \
                int u = nb * 4 + rg;                                              \
                float gi = sigm(acc[nb * 4 + 0][rg]);                             \
                float gf = sigm(acc[nb * 4 + 1][rg]);                             \
                float gg = tanh_(acc[nb * 4 + 2][rg]);                            \
                float go = sigm(acc[nb * 4 + 3][rg]);                             \
                float cn = gf * cst[u] + gi * gg;                                 \
                float hn = go * tanh_(cn);                                        \
                cst[u] = mv ? cn : cst[u];                                        \
                hbf[u] = mv ? (__float_as_uint(hn) >> 16) : hbf[u];               \
                hq[u]  = mv ? f2fp8(hn) : hq[u];                                  \
                voff[u] += mv ? dstepB : 0;                                       \
                *(u16*)(hsp + voff[u]) = (u16)hbf[u];                             \
                (HW)[rg * 272 + nb * 16] = (u8)hq[u];                             \
            }                                                                     \
        }                                                                         \
        asm volatile("s_waitcnt lgkmcnt(0)\n\ts_barrier" ::: "memory");           \
    }

__global__ __launch_bounds__(512, 2) void k_lstm(const u16* __restrict__ xg2,
                                                 const u8* __restrict__ whh8,
                                                 const int* __restrict__ lengths,
                                                 u16* __restrict__ hs) {
    __shared__ u8 h8[2][4352];                         // [buf][16 rows][stride 272]
    int tid = threadIdx.x, lane = tid & 63, w = tid >> 6;
    int bx = blockIdx.x;
    int d = bx >> 3, grp = bx & 7;
    int c16 = lane & 15, q = lane >> 4;

    u8* hflat = &h8[0][0];
    for (int i = tid * 8; i < 8704; i += 4096) *(u64*)(hflat + i) = 0;

    int lenr[4];
#pragma unroll
    for (int rg = 0; rg < 4; ++rg) lenr[rg] = lengths[grp * 16 + q * 4 + rg];

    // WG-wide max length (identical across waves: every wave spans q=0..3)
    int ml = lenr[0];
#pragma unroll
    for (int rg = 1; rg < 4; ++rg) ml = ml > lenr[rg] ? ml : lenr[rg];
    {
        int o = __shfl_xor(ml, 16); ml = ml > o ? ml : o;
        o = __shfl_xor(ml, 32);     ml = ml > o ? ml : o;
    }
    int tmax = (ml + 1) & ~1;                          // even (double-buffer parity)

    // register-resident fp8 weights: [g][nb][kk] i32x8 = 128 regs
    const u8* wbse = whh8 + ((size_t)((d * 8 + w) * 4)) * 8192;
    i32x8 br[16];
#pragma unroll
    for (int g = 0; g < 4; ++g)
#pragma unroll
        for (int nb = 0; nb < 2; ++nb)
#pragma unroll
            for (int kk = 0; kk < 2; ++kk) {
                const u8* p = wbse + (size_t)g * 8192 + ((nb * 2 + kk) * 64 + lane) * 32;
                i32x8 v;
                *(uint4*)&v       = *(const uint4*)p;
                *((uint4*)&v + 1) = *(const uint4*)(p + 16);
                br[g * 4 + nb * 2 + kk] = v;
            }

    float cst[8];
    u32 hq[8], hbf[8];                                 // frozen-carry h (fp8 / bf16 bits)
#pragma unroll
    for (int u = 0; u < 8; ++u) { cst[u] = 0.f; hq[u] = 0; hbf[u] = 0; }

    // hs byte offsets, advance-then-store (frozen when masked)
    u32 voff[8];
    int dstepB = d ? -1024 : 1024;
    u8* hsp = (u8*)hs;
#pragma unroll
    for (int nb = 0; nb < 2; ++nb)
#pragma unroll
        for (int rg = 0; rg < 4; ++rg) {
            int u = nb * 4 + rg;
            int row = q * 4 + rg;
            int hid = w * 32 + nb * 16 + c16;
            int p0 = d ? (lenr[rg] - 1) : 0;
            voff[u] = (u32)((((grp * 16 + row) * 128 + p0) * 512 + d * 256 + hid) * 2 - dstepB);
        }

    // xg: bias pre-folded; 64B/lane/step; xp points at the NEXT slab
    const u16* xslab = xg2 + ((size_t)(d * 8 + grp) * 128) * 16384 + (w * 64 + lane) * 32;
    u32 xqa[16], xqb[16];
    *(uint4*)(&xqa[0])  = *(const uint4*)(xslab);
    *(uint4*)(&xqa[4])  = *(const uint4*)(xslab + 8);
    *(uint4*)(&xqa[8])  = *(const uint4*)(xslab + 16);
    *(uint4*)(&xqa[12]) = *(const uint4*)(xslab + 24);
    const u16* xp = xslab + 16384;

    // A-frag LDS bases (row c16, k = q*32 + j, +kk*128 via imm), stride 272
    const u8* ha0 = hflat + (c16 * 272 + q * 32);
    const u8* ha1 = ha0 + 4352;
    // h write bases: row = q*4+rg (imm), hid = w*32 + nb*16 (imm) + c16
    u8* hw1 = hflat + (q * 1088 + w * 32 + c16);       // write target while reading buf0
    u8* hw0 = hw1 + 4352;

    __syncthreads();

    for (int t2 = 0; t2 < tmax; t2 += 2) {
        LSTM_STEP(t2,     xqa, xqb, ha0, hw0)
        LSTM_STEP(t2 + 1, xqb, xqa, ha1, hw1)
    }
}

// ============================================================
// Emissions: emis[pos][17] = hs[pos][512] . proj_w[17][512] + proj_b
// 16 positions per block (4 per wave); blocks past length exit.
// ============================================================
__global__ __launch_bounds__(256) void k_emis(const u16* __restrict__ hs,
                                              const float* __restrict__ proj_w,
                                              const float* __restrict__ proj_b,
                                              float* __restrict__ emis,
                                              const int* __restrict__ lengths) {
    int p00 = blockIdx.x * 16;
    if ((p00 & 127) >= lengths[p00 >> 7]) return;      // length skip

    __shared__ float pw[17 * 512];
    int tid = threadIdx.x;
    for (int i = tid; i < 17 * 512; i += 256) pw[i] = proj_w[i];
    __syncthreads();
    int lane = tid & 63, wv = tid >> 6;
    int pos0 = p00 + wv * 4;
    float hv[4][8];
#pragma unroll
    for (int p = 0; p < 4; ++p) {
        bf16x8 v = *(const bf16x8*)(hs + (size_t)(pos0 + p) * 512 + lane * 8);
#pragma unroll
        for (int j = 0; j < 8; ++j) hv[p][j] = bf2f((u16)v[j]);
    }
    for (int tg = 0; tg < 17; ++tg) {
        const float* wp = pw + tg * 512 + lane * 8;
        float wr[8];
#pragma unroll
        for (int j = 0; j < 8; ++j) wr[j] = wp[j];
        float s[4];
#pragma unroll
        for (int p = 0; p < 4; ++p) {
            float acc = 0.f;
#pragma unroll
            for (int j = 0; j < 8; ++j) acc = fmaf(hv[p][j], wr[j], acc);
            s[p] = acc;
        }
#pragma unroll
        for (int off = 32; off; off >>= 1)
#pragma unroll
            for (int p = 0; p < 4; ++p) s[p] += __shfl_down(s[p], off);
        if (lane == 0) {
#pragma unroll
            for (int p = 0; p < 4; ++p) emis[(size_t)(pos0 + p) * 17 + tg] = s[p] + proj_b[tg];
        }
    }
}

// ============================================================
// CRF per-sample NLL. One 64-thread block per batch element.
// ============================================================
__global__ __launch_bounds__(64) void k_crf(const float* __restrict__ emis,
                                            const int* __restrict__ tags,
                                            const int* __restrict__ lengths,
                                            const float* __restrict__ trans,
                                            const float* __restrict__ start_trans,
                                            const float* __restrict__ end_trans,
                                            float* __restrict__ nll) {
    int b = blockIdx.x, lane = threadIdx.x;
    __shared__ float tr[289];
    __shared__ float al[17];
    __shared__ float scs;
    for (int i = lane; i < 289; i += 64) tr[i] = trans[i];
    int len = lengths[b];
    const int* tg = tags + (size_t)b * 128;
    const float* em = emis + (size_t)b * 128 * 17;
    __syncthreads();

    float sc = 0.f;
    for (int t = lane; t < len; t += 64) {
        sc += em[t * 17 + tg[t]];
        if (t >= 1) sc += tr[tg[t - 1] * 17 + tg[t]];
    }
#pragma unroll
    for (int off = 32; off; off >>= 1) sc += __shfl_down(sc, off);
    if (lane == 0) scs = sc + start_trans[tg[0]] + end_trans[tg[len - 1]];

    if (lane < 17) al[lane] = start_trans[lane] + em[lane];
    __syncthreads();
    for (int t = 1; t < len; ++t) {
        float anew = 0.f;
        if (lane < 17) {
            float m = -1e30f;
            for (int i = 0; i < 17; ++i) m = fmaxf(m, al[i] + tr[i * 17 + lane]);
            float s = 0.f;
            for (int i = 0; i < 17; ++i) s += __expf(al[i] + tr[i * 17 + lane] - m);
            anew = m + __logf(s) + em[t * 17 + lane];
        }
        __syncthreads();
        if (lane < 17) al[lane] = anew;
        __syncthreads();
    }
    float v = (lane < 17) ? al[lane] + end_trans[lane] : -1e30f;
    float m = v;
#pragma unroll
    for (int off = 32; off; off >>= 1) m = fmaxf(m, __shfl_xor(m, off));
    float s = (lane < 17) ? __expf(v - m) : 0.f;
#pragma unroll
    for (int off = 32; off; off >>= 1) s += __shfl_xor(s, off);
    if (lane == 0) nll[b] = (m + __logf(s)) - scs;
}

__global__ __launch_bounds__(128) void k_reduce(const float* __restrict__ nll, float* __restrict__ out) {
    int tid = threadIdx.x;
    float v = nll[tid];
#pragma unroll
    for (int off = 32; off; off >>= 1) v += __shfl_down(v, off);
    __shared__ float partial[2];
    if ((tid & 63) == 0) partial[tid >> 6] = v;
    __syncthreads();
    if (tid == 0) out[0] = partial[0] + partial[1];
}

// ============================================================
extern "C" void kernel_launch(void* const* d_in, const int* in_sizes, int n_in,
                              void* d_out, int out_size, void* d_ws, size_t ws_size,
                              hipStream_t stream) {
    (void)in_sizes; (void)n_in; (void)out_size; (void)ws_size;
    const int*   words       = (const int*)d_in[0];
    const int*   chars       = (const int*)d_in[1];
    const int*   tags        = (const int*)d_in[2];
    const int*   lengths     = (const int*)d_in[3];
    const float* word_emb    = (const float*)d_in[4];
    const float* char_emb    = (const float*)d_in[5];
    const float* conv_w      = (const float*)d_in[6];
    const float* conv_b      = (const float*)d_in[7];
    const float* w_ih_f      = (const float*)d_in[8];
    const float* w_hh_f      = (const float*)d_in[9];
    const float* b_f         = (const float*)d_in[10];
    const float* w_ih_b      = (const float*)d_in[11];
    const float* w_hh_b      = (const float*)d_in[12];
    const float* b_b         = (const float*)d_in[13];
    const float* proj_w      = (const float*)d_in[14];
    const float* proj_b      = (const float*)d_in[15];
    const float* trans       = (const float*)d_in[16];
    const float* start_trans = (const float*)d_in[17];
    const float* end_trans   = (const float*)d_in[18];

    char* ws = (char*)d_ws;
    u16* inp   = (u16*)(ws + OFF_INP);
    u16* wih   = (u16*)(ws + OFF_WIH);
    u8*  whh8  = (u8*)(ws + OFF_WHH);
    u16* xgb   = (u16*)(ws + OFF_XG);
    u16* hsb   = (u16*)(ws + OFF_HS);
    float* em  = (float*)(ws + OFF_EMIS);
    float* nll = (float*)(ws + OFF_NLL);
    float* wt  = (float*)(ws + OFF_WT);

    k_prep0<<<30, 256, 0, stream>>>(conv_w, wt);
    k_front<<<4096, 256, 0, stream>>>(words, chars, word_emb, char_emb, wt, conv_b, inp,
                                      w_ih_f, w_ih_b, wih, w_hh_f, w_hh_b, whh8, lengths);
    k_gemm<<<dim3(16, 128), 256, 0, stream>>>(inp, wih, xgb, lengths, b_f, b_b);
    k_lstm<<<16, 512, 0, stream>>>(xgb, whh8, lengths, hsb);
    k_emis<<<1024, 256, 0, stream>>>(hsb, proj_w, proj_b, em, lengths);
    k_crf<<<128, 64, 0, stream>>>(em, tags, lengths, trans, start_trans, end_trans, nll);
    k_reduce<<<1, 128, 0, stream>>>(nll, (float*)d_out);
}

// Round 13
// 426.140 us; speedup vs baseline: 1.7114x; 1.0218x over previous
//
#include <hip/hip_runtime.h>
#include <stdint.h>

typedef unsigned char u8;
typedef unsigned short u16;
typedef unsigned int u32;
typedef unsigned long long u64;

// ---- problem constants ----
// B=128 S=128 WL=16 V=50000 C=100 T=17 WE=300 CE=50 CF=50 K=3 H=256 D=350
#define NPOS 16384          // B*S
#define KPAD 384            // D padded to multiple of 64

typedef __attribute__((ext_vector_type(8))) short bf16x8;
typedef __attribute__((ext_vector_type(4))) float f32x4;
typedef __attribute__((ext_vector_type(8))) int i32x8;

__device__ __forceinline__ float bf2f(u16 u) { return __uint_as_float(((u32)u) << 16); }
__device__ __forceinline__ u16 f2bf(float f) {
    u32 u = __float_as_uint(f);
    u += 0x7fffu + ((u >> 16) & 1u);   // RNE
    return (u16)(u >> 16);
}
__device__ __forceinline__ float frcp(float x) {
#if __has_builtin(__builtin_amdgcn_rcpf)
    return __builtin_amdgcn_rcpf(x);       // v_rcp_f32, 1ulp — fine vs fp8 weights
#else
    return 1.0f / x;
#endif
}
__device__ __forceinline__ float sigm(float x) { return frcp(1.0f + __expf(-x)); }
__device__ __forceinline__ float tanh_(float x) { return fmaf(2.0f, frcp(1.0f + __expf(-2.0f * x)), -1.0f); }

// f32 -> fp8 e4m3fn (OCP), RNE, clamp to +-448. Prep-path (manual, no builtin risk).
__device__ u8 f2fp8_manual(float f) {
    u32 u = __float_as_uint(f);
    u32 s = (u >> 31) << 7;
    u32 ae = (u >> 23) & 255u;
    u32 m = u & 0x7fffffu;
    int e = (int)ae - 127;
    if (ae == 0) return (u8)s;                 // f32 subnormal -> 0
    if (e >= 9) return (u8)(s | 0x7e);         // >= 512 -> clamp 448
    if (e >= -6) {                             // e4m3 normal
        u32 mant = m >> 20;
        u32 rem = m & 0xfffffu;
        if (rem > 0x80000u || (rem == 0x80000u && (mant & 1u))) mant++;
        u32 ef = (u32)(e + 7);
        if (mant == 8u) { mant = 0u; ef++; }
        if (ef >= 16u || (ef == 15u && mant == 7u)) return (u8)(s | 0x7e);
        return (u8)(s | (ef << 3) | mant);
    }
    if (e < -10) return (u8)s;                 // underflow to 0
    int sb = 14 - e;                           // shift for units of 2^-9
    u32 X = 0x800000u | m;
    u32 mant = X >> sb;
    u32 rem = X & ((1u << sb) - 1u);
    u32 half = 1u << (sb - 1);
    if (rem > half || (rem == half && (mant & 1u))) mant++;
    if (mant >= 8u) return (u8)(s | (1u << 3)); // rounds to first normal 2^-6
    return (u8)(s | mant);
}

__device__ __forceinline__ u32 f2fp8(float f) {
#if __has_builtin(__builtin_amdgcn_cvt_pk_fp8_f32)
    return (u32)(__builtin_amdgcn_cvt_pk_fp8_f32(f, f, 0, false) & 0xff);
#else
    return (u32)f2fp8_manual(f);
#endif
}

// ---- workspace layout (bytes) ----
static constexpr size_t OFF_INP  = 0;                       // u16 [16384][384]   = 12582912
static constexpr size_t OFF_WIH  = 12582912;                // u16 [2048][384]    = 1572864
static constexpr size_t OFF_WHH  = 14155776;                // fp8 packed 512KB
static constexpr size_t OFF_XG   = 15204352;                // u16 xg2 repacked   = 67108864
static constexpr size_t OFF_HS   = 82313216;                // u16 [16384][512]   = 16777216
static constexpr size_t OFF_EMIS = 99090432;                // f32 [16384][17]    = 1114112
static constexpr size_t OFF_NLL  = 100204544;               // f32 [128]
static constexpr size_t OFF_WT   = OFF_XG;                  // f32 wt[150][52] (transient; overwritten by xg later)

// ============================================================
// Prep0: transpose conv_w [50 oc][50 ic][3 k] -> wt[(ic*3+k)][52 pad][oc]
// ============================================================
__global__ __launch_bounds__(256) void k_prep0(const float* __restrict__ conv_w,
                                               float* __restrict__ wt) {
    int idx = blockIdx.x * 256 + threadIdx.x;
    if (idx < 7500) {
        int oc = idx / 150, r = idx - oc * 150;        // r = ic*3+k
        wt[r * 52 + oc] = conv_w[oc * 150 + r];
    }
}

// ============================================================
// Fused front kernel: blockIdx dispatch
//   b in [0,2048):    embedding + char conv (8 positions per block) —
//                     blocks fully past the row's length exit immediately.
//   b in [2048,3072): pack w_ih -> bf16 [2048][384]
//   b in [3072,4096): pack w_hh -> fp8 MX layout
// ============================================================
__global__ __launch_bounds__(256) void k_front(const int* __restrict__ words,
                                               const int* __restrict__ chars,
                                               const float* __restrict__ word_emb,
                                               const float* __restrict__ char_emb,
                                               const float* __restrict__ wt,
                                               const float* __restrict__ conv_b,
                                               u16* __restrict__ inp,
                                               const float* __restrict__ wihf,
                                               const float* __restrict__ wihb,
                                               u16* __restrict__ wih,
                                               const float* __restrict__ whf,
                                               const float* __restrict__ whb,
                                               u8* __restrict__ whh8,
                                               const int* __restrict__ lengths) {
    __shared__ float ce_t[8][50][20];                  // [pos][ic][t], t=0 & 17..19 zero pad
    int b = blockIdx.x, tid = threadIdx.x;

    if (b >= 2048) {
        if (b < 3072) {                                // ---- w_ih pack ----
            int n = (b - 2048) * 2 + (tid >> 7);
            int t128 = tid & 127;
            const float* src = (n < 1024) ? (wihf + (size_t)n * 350) : (wihb + (size_t)(n - 1024) * 350);
            u16* dst = wih + (size_t)n * KPAD;
            for (int k = t128; k < KPAD; k += 128) dst[k] = (k < 350) ? f2bf(src[k]) : (u16)0;
        } else {                                       // ---- w_hh pack (MX 16x16x128 B-frag) ----
            int gr = (b - 3072) * 2 + (tid >> 7);
            int t128 = tid & 127;
            int d = gr >> 10, row = gr & 1023;         // row = gate*256 + hid
            const float* src = (d ? whb : whf) + (size_t)row * 256;
            int g = row >> 8, hid = row & 255;
            int w = hid >> 5, nb = (hid >> 4) & 1, c16 = hid & 15;
            u8* base = whh8 + ((size_t)((d * 8 + w) * 4 + g)) * 8192;
            for (int k = t128; k < 256; k += 128) {
                int kk = k >> 7, q = (k >> 5) & 3, j = k & 31;
                base[((nb * 2 + kk) * 64 + (q * 16 + c16)) * 32 + j] = f2fp8_manual(src[k]);
            }
        }
        return;
    }

    // length skip: this block's 8 positions are t in [t0, t0+8) of batch row b>>4
    if (((b & 15) * 8) >= lengths[b >> 4]) return;

    // ---- embedding + char conv, 8 positions ----
    int pos0 = b * 8;

    // ce_t fill: threads 0..127 -> (pos, char c); threads 128..255 zero pad cols
    if (tid < 128) {
        int p = tid >> 4, c = tid & 15;
        int ch = chars[(size_t)(pos0 + p) * 16 + c];
        const float* src = char_emb + (size_t)ch * 50;
#pragma unroll
        for (int i = 0; i < 25; ++i) {
            float2 v = *(const float2*)(src + i * 2);
            ce_t[p][i * 2][c + 1] = v.x;
            ce_t[p][i * 2 + 1][c + 1] = v.y;
        }
    } else {
        int base = tid - 128;
        for (int i = base; i < 1600; i += 128) {
            int p = i / 200, rem = i - p * 200;
            int ic = rem >> 2, cid = rem & 3;
            ce_t[p][ic][cid == 0 ? 0 : 16 + cid] = 0.f;
        }
    }

    // word embedding: 8 pos x 75 float4 = 600 tasks
    for (int r = 0; r < 3; ++r) {
        int idx = r * 256 + tid;
        if (idx < 600) {
            int p = idx / 75, v = idx - p * 75;
            const float4* we4 = (const float4*)(word_emb + (size_t)words[pos0 + p] * 300);
            float4 val = we4[v];
            u64 pk = (u64)f2bf(val.x) | ((u64)f2bf(val.y) << 16) |
                     ((u64)f2bf(val.z) << 32) | ((u64)f2bf(val.w) << 48);
            *(u64*)(inp + (size_t)(pos0 + p) * KPAD + v * 4) = pk;
        }
    }
    // zero pad inp[350..383]: 8 pos x 17 u32
    {
        int idx = tid;
        if (idx < 136) {
            int p = idx / 17, j = idx - p * 17;
            *(u32*)(inp + (size_t)(pos0 + p) * KPAD + 350 + 2 * j) = 0;
        }
    }
    __syncthreads();

    // conv: 200 tasks = 8 pos x 25 oc-pairs; each task: 2 oc x 16 t
    if (tid < 200) {
        int p = tid / 25, ocp = tid - p * 25;
        int oc = ocp * 2;
        float acc0[16], acc1[16];
#pragma unroll
        for (int t = 0; t < 16; ++t) { acc0[t] = 0.f; acc1[t] = 0.f; }
        const float* cebase = &ce_t[p][0][0];
        for (int ic = 0; ic < 50; ++ic) {
            float c[20];
            const float* cp = cebase + ic * 20;
#pragma unroll
            for (int i = 0; i < 5; ++i) *(float4*)(&c[i * 4]) = *(const float4*)(cp + i * 4);
#pragma unroll
            for (int k = 0; k < 3; ++k) {
                float2 wv = *(const float2*)(wt + (ic * 3 + k) * 52 + oc);
#pragma unroll
                for (int t = 0; t < 16; ++t) {
                    acc0[t] = fmaf(c[t + k], wv.x, acc0[t]);
                    acc1[t] = fmaf(c[t + k], wv.y, acc1[t]);
                }
            }
        }
        float cb0 = conv_b[oc], cb1 = conv_b[oc + 1];
        float m0 = 0.f, m1 = 0.f;
#pragma unroll
        for (int t = 0; t < 16; ++t) {
            m0 = fmaxf(m0, acc0[t] + cb0);
            m1 = fmaxf(m1, acc1[t] + cb1);
        }
        u16* op = inp + (size_t)(pos0 + p) * KPAD + 300 + oc;
        op[0] = f2bf(m0);
        op[1] = f2bf(m1);
    }
}

// ============================================================
// GEMM: inp[16384][384] @ wih[2048][384]^T (bf16 MFMA). R13: N=256 per block
// (block = dd x 64-hid slice): A-panel refetch 16x -> 8x, half the blocks.
// B-LDS 32KB + A-LDS 16KB = 48KB (2 blocks/CU). Each wave owns 32 hid x 4
// gates x 2 nb; u64 stores (4 bf16 gates, bias folded) into the k_lstm slab.
// mt-subtiles past the row length skipped via scalar branch.
// ============================================================
__global__ __launch_bounds__(256, 2) void k_gemm(const u16* __restrict__ A,
                                                 const u16* __restrict__ Bm,
                                                 u16* __restrict__ C,
                                                 const int* __restrict__ lengths,
                                                 const float* __restrict__ bias_f,
                                                 const float* __restrict__ bias_b) {
    __shared__ u16 sa[128 * 64];                       // 16KB
    __shared__ u16 sb[256 * 64];                       // 32KB
    int tid = threadIdx.x;
    int dd = blockIdx.x >> 2, hb2 = blockIdx.x & 3;    // 64-hid slice
    int m0 = blockIdx.y * 128;
    int lane = tid & 63, wid = tid >> 6;
    int wr = wid >> 1, wc = wid & 1;
    int b = blockIdx.y;
    int len = lengths[b];
    int lenS = __builtin_amdgcn_readfirstlane(len);
    int wrS = __builtin_amdgcn_readfirstlane(wr);

    f32x4 acc[4][8];                                   // [mt][nb*4+g]
#pragma unroll
    for (int mt = 0; mt < 4; ++mt)
#pragma unroll
        for (int j = 0; j < 8; ++j) acc[mt][j] = (f32x4){0.f, 0.f, 0.f, 0.f};

    for (int kt = 0; kt < 6; ++kt) {
#pragma unroll
        for (int c = 0; c < 4; ++c) {                  // stage A: 128 rows x 128B
            int idx = (c * 256 + tid) * 16;
            int row = idx >> 7, colb = idx & 127;
            int dst = idx ^ ((row & 7) << 4);
            uint4 va = *(const uint4*)((const char*)A + (size_t)(m0 + row) * 768 + kt * 128 + colb);
            *(uint4*)((char*)sa + dst) = va;
        }
#pragma unroll
        for (int c = 0; c < 8; ++c) {                  // stage B: 256 rows x 128B
            int idx = (c * 256 + tid) * 16;
            int row = idx >> 7, colb = idx & 127;
            int dst = idx ^ ((row & 7) << 4);
            int bmrow = dd * 1024 + (row >> 6) * 256 + hb2 * 64 + (row & 63);
            uint4 vb = *(const uint4*)((const char*)Bm + (size_t)bmrow * 768 + kt * 128 + colb);
            *(uint4*)((char*)sb + dst) = vb;
        }
        __syncthreads();
#pragma unroll
        for (int kc = 0; kc < 2; ++kc) {
            bf16x8 bf[8];
#pragma unroll
            for (int nb = 0; nb < 2; ++nb)
#pragma unroll
                for (int g = 0; g < 4; ++g) {
                    int row = g * 64 + wc * 32 + nb * 16 + (lane & 15);
                    int off = (row * 128 + kc * 64 + (lane >> 4) * 16) ^ ((row & 7) << 4);
                    bf[nb * 4 + g] = *(const bf16x8*)((const char*)sb + off);
                }
#pragma unroll
            for (int mt = 0; mt < 4; ++mt) {
                if (wrS * 64 + mt * 16 < lenS) {       // scalar skip of dead t-subtiles
                    int row = wr * 64 + mt * 16 + (lane & 15);
                    int off = (row * 128 + kc * 64 + (lane >> 4) * 16) ^ ((row & 7) << 4);
                    bf16x8 af = *(const bf16x8*)((const char*)sa + off);
#pragma unroll
                    for (int j = 0; j < 8; ++j)
                        acc[mt][j] = __builtin_amdgcn_mfma_f32_16x16x32_bf16(af, bf[j], acc[mt][j], 0, 0, 0);
                }
            }
        }
        __syncthreads();
    }
    // epilogue
    int grp = b >> 4, row16 = b & 15;
    int qq = row16 >> 2, rg = row16 & 3;
    int c16 = lane & 15;
    const float* bias = dd ? bias_b : bias_f;
    float bv[2][4];
    u32 base16[2];
#pragma unroll
    for (int nb = 0; nb < 2; ++nb) {
        int hid = hb2 * 64 + wc * 32 + nb * 16 + c16;
#pragma unroll
        for (int g = 0; g < 4; ++g) bv[nb][g] = bias[g * 256 + hid];
        base16[nb] = (u32)(((hb2 * 2 + wc) * 64 + qq * 16 + c16) * 32 + (nb * 4 + rg) * 4);
    }
    size_t slab0 = ((size_t)(dd * 8 + grp) * 128) * 16384;
#pragma unroll
    for (int mt = 0; mt < 4; ++mt) {
        if (wrS * 64 + mt * 16 < lenS) {
#pragma unroll
            for (int r = 0; r < 4; ++r) {
                int t = wr * 64 + mt * 16 + (lane >> 4) * 4 + r;
                int tt = dd ? ((t < len) ? (len - 1 - t) : t) : t;
#pragma unroll
                for (int nb = 0; nb < 2; ++nb) {
                    u64 pk = (u64)f2bf(acc[mt][nb * 4 + 0][r] + bv[nb][0]) |
                             ((u64)f2bf(acc[mt][nb * 4 + 1][r] + bv[nb][1]) << 16) |
                             ((u64)f2bf(acc[mt][nb * 4 + 2][r] + bv[nb][2]) << 32) |
                             ((u64)f2bf(acc[mt][nb * 4 + 3][r] + bv[nb][3]) << 48);
                    *(u64*)(C + slab0 + (size_t)tt * 16384 + base16[nb]) = pk;
                }
            }
        }
    }
}

// ============================================================
// BiLSTM recurrence (R9 structure — frozen control). 16 WGs = dir(2) x group(8).
// All 4 gates register-resident fp8 (i32x8 br[16] = 128 regs). h fp8
// double-buffered LDS, stride 272. MX-scaled MFMA 16x16x128 (unit scales).
// acc initialized from xg (C-operand); branchless cndmask epilogue.
// ============================================================
#define LSTM_STEP(T, XC, XN, HA, HW)                                              \
    {                                                                             \
        *(uint4*)(&XN[0])  = *(const uint4*)(xp);                                 \
        *(uint4*)(&XN[4])  = *(const uint4*)(xp + 8);                             \
        *(uint4*)(&XN[8])  = *(const uint4*)(xp + 16);                            \
        *(uint4*)(&XN[12]) = *(const uint4*)(xp + 24);                            \
        xp += 16384;                                                              \
        f32x4 acc[8];                                                             \
        _Pragma("unroll") for (int nb = 0; nb < 2; ++nb)                          \
            _Pragma("unroll") for (int rg = 0; rg < 4; ++rg) {                    \
                int u = nb * 4 + rg;                                              \
                u32 w0 = XC[u * 2], w1 = XC[u * 2 + 1];                           \
                acc[nb * 4 + 0][rg] = __uint_as_float(w0 << 16);                  \
                acc[nb * 4 + 1][rg] = __uint_as_float(w0 & 0xffff0000u);          \
                acc[nb * 4 + 2][rg] = __uint_as_float(w1 << 16);                  \
                acc[nb * 4 + 3][rg] = __uint_as_float(w1 & 0xffff0000u);          \
            }                                                                     \
        i32x8 a0, a1;                                                             \
        *(uint4*)&a0       = *(const uint4*)(HA);                                 \
        *((uint4*)&a0 + 1) = *(const uint4*)(HA + 16);                            \
        *(uint4*)&a1       = *(const uint4*)(HA + 128);                           \
        *((uint4*)&a1 + 1) = *(const uint4*)(HA + 144);                           \
        __builtin_amdgcn_s_setprio(1);                                            \
        _Pragma("unroll") for (int g = 0; g < 4; ++g)                             \
            acc[g] = __builtin_amdgcn_mfma_scale_f32_16x16x128_f8f6f4(            \
                a0, br[g * 4 + 0], acc[g], 0, 0, 0, 127, 0, 127);                 \
        _Pragma("unroll") for (int g = 0; g < 4; ++g)                             \
            acc[g] = __builtin_amdgcn_mfma_scale_f32_16x16x128_f8f6f4(            \
                a1, br[g * 4 + 1], acc[g], 0, 0, 0, 127, 0, 127);                 \
        _Pragma("unroll") for (int g = 0; g < 4; ++g)                             \
            acc[4 + g] = __builtin_amdgcn_mfma_scale_f32_16x16x128_f8f6f4(        \
                a0, br[g * 4 + 2], acc[4 + g], 0, 0, 0, 127, 0, 127);             \
        _Pragma("unroll") for (int g = 0; g < 4; ++g)                             \
            acc[4 + g] = __builtin_amdgcn_mfma_scale_f32_16x16x128_f8f6f4(        \
                a1, br[g * 4 + 3], acc[4 + g], 0, 0, 0, 127, 0, 127);             \
        __builtin_amdgcn_s_setprio(0);                                            \
        _Pragma("unroll") for (int rg = 0; rg < 4; ++rg) {                        \
            bool mv = (T) < lenr[rg];                                             \
            _Pragma("unroll") for (int nb = 0; nb < 2; ++nb) {                    \
                int u = nb * 4 + rg;                                              \
                float gi = sigm(acc[nb * 4 + 0][rg]);                             \
                float gf = sigm(acc[nb * 4 + 1][rg]);                             \
                float gg = tanh_(acc[nb * 4 + 2][rg]);                            \
                float go = sigm(acc[nb * 4 + 3][rg]);                             \
                float cn = gf * cst[u] + gi * gg;                                 \
                float hn = go * tanh_(cn);                                        \
                cst[u] = mv ? cn : cst[u];                                        \
                hbf[u] = mv ? (__float_as_uint(hn) >> 16) : hbf[u];               \
                hq[u]  = mv ? f2fp8(hn) : hq[u];                                  \
                voff[u] += mv ? dstepB : 0;                                       \
                *(u16*)(hsp + voff[u]) = (u16)hbf[u];                             \
                (HW)[rg * 272 + nb * 16] = (u8)hq[u];                             \
            }                                                                     \
        }                                                                         \
        asm volatile("s_waitcnt lgkmcnt(0)\n\ts_barrier" ::: "memory");           \
    }

__global__ __launch_bounds__(512, 2) void k_lstm(const u16* __restrict__ xg2,
                                                 const u8* __restrict__ whh8,
                                                 const int* __restrict__ lengths,
                                                 u16* __restrict__ hs) {
    __shared__ u8 h8[2][4352];                         // [buf][16 rows][stride 272]
    int tid = threadIdx.x, lane = tid & 63, w = tid >> 6;
    int bx = blockIdx.x;
    int d = bx >> 3, grp = bx & 7;
    int c16 = lane & 15, q = lane >> 4;

    u8* hflat = &h8[0][0];
    for (int i = tid * 8; i < 8704; i += 4096) *(u64*)(hflat + i) = 0;

    int lenr[4];
#pragma unroll
    for (int rg = 0; rg < 4; ++rg) lenr[rg] = lengths[grp * 16 + q * 4 + rg];

    // WG-wide max length (identical across waves)
    int ml = lenr[0];
#pragma unroll
    for (int rg = 1; rg < 4; ++rg) ml = ml > lenr[rg] ? ml : lenr[rg];
    {
        int o = __shfl_xor(ml, 16); ml = ml > o ? ml : o;
        o = __shfl_xor(ml, 32);     ml = ml > o ? ml : o;
    }
    int tmax = (ml + 1) & ~1;                          // even (double-buffer parity)

    // register-resident fp8 weights: [g][nb][kk] i32x8 = 128 regs
    const u8* wbse = whh8 + ((size_t)((d * 8 + w) * 4)) * 8192;
    i32x8 br[16];
#pragma unroll
    for (int g = 0; g < 4; ++g)
#pragma unroll
        for (int nb = 0; nb < 2; ++nb)
#pragma unroll
            for (int kk = 0; kk < 2; ++kk) {
                const u8* p = wbse + (size_t)g * 8192 + ((nb * 2 + kk) * 64 + lane) * 32;
                i32x8 v;
                *(uint4*)&v       = *(const uint4*)p;
                *((uint4*)&v + 1) = *(const uint4*)(p + 16);
                br[g * 4 + nb * 2 + kk] = v;
            }

    float cst[8];
    u32 hq[8], hbf[8];                                 // frozen-carry h (fp8 / bf16 bits)
#pragma unroll
    for (int u = 0; u < 8; ++u) { cst[u] = 0.f; hq[u] = 0; hbf[u] = 0; }

    // hs byte offsets, advance-then-store (frozen when masked)
    u32 voff[8];
    int dstepB = d ? -1024 : 1024;
    u8* hsp = (u8*)hs;
#pragma unroll
    for (int nb = 0; nb < 2; ++nb)
#pragma unroll
        for (int rg = 0; rg < 4; ++rg) {
            int u = nb * 4 + rg;
            int row = q * 4 + rg;
            int hid = w * 32 + nb * 16 + c16;
            int p0 = d ? (lenr[rg] - 1) : 0;
            voff[u] = (u32)((((grp * 16 + row) * 128 + p0) * 512 + d * 256 + hid) * 2 - dstepB);
        }

    // xg: bias pre-folded; 64B/lane/step; xp points at the NEXT slab
    const u16* xslab = xg2 + ((size_t)(d * 8 + grp) * 128) * 16384 + (w * 64 + lane) * 32;
    u32 xqa[16], xqb[16];
    *(uint4*)(&xqa[0])  = *(const uint4*)(xslab);
    *(uint4*)(&xqa[4])  = *(const uint4*)(xslab + 8);
    *(uint4*)(&xqa[8])  = *(const uint4*)(xslab + 16);
    *(uint4*)(&xqa[12]) = *(const uint4*)(xslab + 24);
    const u16* xp = xslab + 16384;

    // A-frag LDS bases (row c16, k = q*32 + j, +kk*128 via imm), stride 272
    const u8* ha0 = hflat + (c16 * 272 + q * 32);
    const u8* ha1 = ha0 + 4352;
    // h write bases: row = q*4+rg (imm), hid = w*32 + nb*16 (imm) + c16
    u8* hw1 = hflat + (q * 1088 + w * 32 + c16);       // write target while reading buf0
    u8* hw0 = hw1 + 4352;

    __syncthreads();

    for (int t2 = 0; t2 < tmax; t2 += 2) {
        LSTM_STEP(t2,     xqa, xqb, ha0, hw0)
        LSTM_STEP(t2 + 1, xqb, xqa, ha1, hw1)
    }
}

// ============================================================
// Emissions: emis[pos][17] = hs[pos][512] . proj_w[17][512] + proj_b
// 16 positions per block (4 per wave); blocks past length exit.
// ============================================================
__global__ __launch_bounds__(256) void k_emis(const u16* __restrict__ hs,
                                              const float* __restrict__ proj_w,
                                              const float* __restrict__ proj_b,
                                              float* __restrict__ emis,
                                              const int* __restrict__ lengths) {
    int p00 = blockIdx.x * 16;
    if ((p00 & 127) >= lengths[p00 >> 7]) return;      // length skip

    __shared__ float pw[17 * 512];
    int tid = threadIdx.x;
    for (int i = tid; i < 17 * 512; i += 256) pw[i] = proj_w[i];
    __syncthreads();
    int lane = tid & 63, wv = tid >> 6;
    int pos0 = p00 + wv * 4;
    float hv[4][8];
#pragma unroll
    for (int p = 0; p < 4; ++p) {
        bf16x8 v = *(const bf16x8*)(hs + (size_t)(pos0 + p) * 512 + lane * 8);
#pragma unroll
        for (int j = 0; j < 8; ++j) hv[p][j] = bf2f((u16)v[j]);
    }
    for (int tg = 0; tg < 17; ++tg) {
        const float* wp = pw + tg * 512 + lane * 8;
        float wr[8];
#pragma unroll
        for (int j = 0; j < 8; ++j) wr[j] = wp[j];
        float s[4];
#pragma unroll
        for (int p = 0; p < 4; ++p) {
            float acc = 0.f;
#pragma unroll
            for (int j = 0; j < 8; ++j) acc = fmaf(hv[p][j], wr[j], acc);
            s[p] = acc;
        }
#pragma unroll
        for (int off = 32; off; off >>= 1)
#pragma unroll
            for (int p = 0; p < 4; ++p) s[p] += __shfl_down(s[p], off);
        if (lane == 0) {
#pragma unroll
            for (int p = 0; p < 4; ++p) emis[(size_t)(pos0 + p) * 17 + tg] = s[p] + proj_b[tg];
        }
    }
}

// ============================================================
// CRF per-sample NLL. One 64-thread block per batch element.
// ============================================================
__global__ __launch_bounds__(64) void k_crf(const float* __restrict__ emis,
                                            const int* __restrict__ tags,
                                            const int* __restrict__ lengths,
                                            const float* __restrict__ trans,
                                            const float* __restrict__ start_trans,
                                            const float* __restrict__ end_trans,
                                            float* __restrict__ nll) {
    int b = blockIdx.x, lane = threadIdx.x;
    __shared__ float tr[289];
    __shared__ float al[17];
    __shared__ float scs;
    for (int i = lane; i < 289; i += 64) tr[i] = trans[i];
    int len = lengths[b];
    const int* tg = tags + (size_t)b * 128;
    const float* em = emis + (size_t)b * 128 * 17;
    __syncthreads();

    float sc = 0.f;
    for (int t = lane; t < len; t += 64) {
        sc += em[t * 17 + tg[t]];
        if (t >= 1) sc += tr[tg[t - 1] * 17 + tg[t]];
    }
#pragma unroll
    for (int off = 32; off; off >>= 1) sc += __shfl_down(sc, off);
    if (lane == 0) scs = sc + start_trans[tg[0]] + end_trans[tg[len - 1]];

    if (lane < 17) al[lane] = start_trans[lane] + em[lane];
    __syncthreads();
    for (int t = 1; t < len; ++t) {
        float anew = 0.f;
        if (lane < 17) {
            float m = -1e30f;
            for (int i = 0; i < 17; ++i) m = fmaxf(m, al[i] + tr[i * 17 + lane]);
            float s = 0.f;
            for (int i = 0; i < 17; ++i) s += __expf(al[i] + tr[i * 17 + lane] - m);
            anew = m + __logf(s) + em[t * 17 + lane];
        }
        __syncthreads();
        if (lane < 17) al[lane] = anew;
        __syncthreads();
    }
    float v = (lane < 17) ? al[lane] + end_trans[lane] : -1e30f;
    float m = v;
#pragma unroll
    for (int off = 32; off; off >>= 1) m = fmaxf(m, __shfl_xor(m, off));
    float s = (lane < 17) ? __expf(v - m) : 0.f;
#pragma unroll
    for (int off = 32; off; off >>= 1) s += __shfl_xor(s, off);
    if (lane == 0) nll[b] = (m + __logf(s)) - scs;
}

__global__ __launch_bounds__(128) void k_reduce(const float* __restrict__ nll, float* __restrict__ out) {
    int tid = threadIdx.x;
    float v = nll[tid];
#pragma unroll
    for (int off = 32; off; off >>= 1) v += __shfl_down(v, off);
    __shared__ float partial[2];
    if ((tid & 63) == 0) partial[tid >> 6] = v;
    __syncthreads();
    if (tid == 0) out[0] = partial[0] + partial[1];
}

// ============================================================
extern "C" void kernel_launch(void* const* d_in, const int* in_sizes, int n_in,
                              void* d_out, int out_size, void* d_ws, size_t ws_size,
                              hipStream_t stream) {
    (void)in_sizes; (void)n_in; (void)out_size; (void)ws_size;
    const int*   words       = (const int*)d_in[0];
    const int*   chars       = (const int*)d_in[1];
    const int*   tags        = (const int*)d_in[2];
    const int*   lengths     = (const int*)d_in[3];
    const float* word_emb    = (const float*)d_in[4];
    const float* char_emb    = (const float*)d_in[5];
    const float* conv_w      = (const float*)d_in[6];
    const float* conv_b      = (const float*)d_in[7];
    const float* w_ih_f      = (const float*)d_in[8];
    const float* w_hh_f      = (const float*)d_in[9];
    const float* b_f         = (const float*)d_in[10];
    const float* w_ih_b      = (const float*)d_in[11];
    const float* w_hh_b      = (const float*)d_in[12];
    const float* b_b         = (const float*)d_in[13];
    const float* proj_w      = (const float*)d_in[14];
    const float* proj_b      = (const float*)d_in[15];
    const float* trans       = (const float*)d_in[16];
    const float* start_trans = (const float*)d_in[17];
    const float* end_trans   = (const float*)d_in[18];

    char* ws = (char*)d_ws;
    u16* inp   = (u16*)(ws + OFF_INP);
    u16* wih   = (u16*)(ws + OFF_WIH);
    u8*  whh8  = (u8*)(ws + OFF_WHH);
    u16* xgb   = (u16*)(ws + OFF_XG);
    u16* hsb   = (u16*)(ws + OFF_HS);
    float* em  = (float*)(ws + OFF_EMIS);
    float* nll = (float*)(ws + OFF_NLL);
    float* wt  = (float*)(ws + OFF_WT);

    k_prep0<<<30, 256, 0, stream>>>(conv_w, wt);
    k_front<<<4096, 256, 0, stream>>>(words, chars, word_emb, char_emb, wt, conv_b, inp,
                                      w_ih_f, w_ih_b, wih, w_hh_f, w_hh_b, whh8, lengths);
    k_gemm<<<dim3(8, 128), 256, 0, stream>>>(inp, wih, xgb, lengths, b_f, b_b);
    k_lstm<<<16, 512, 0, stream>>>(xgb, whh8, lengths, hsb);
    k_emis<<<1024, 256, 0, stream>>>(hsb, proj_w, proj_b, em, lengths);
    k_crf<<<128, 64, 0, stream>>>(em, tags, lengths, trans, start_trans, end_trans, nll);
    k_reduce<<<1, 128, 0, stream>>>(nll, (float*)d_out);
}

// Round 14
// 406.053 us; speedup vs baseline: 1.7961x; 1.0495x over previous
//
#include <hip/hip_runtime.h>
#include <stdint.h>

typedef unsigned char u8;
typedef unsigned short u16;
typedef unsigned int u32;
typedef unsigned long long u64;

// ---- problem constants ----
// B=128 S=128 WL=16 V=50000 C=100 T=17 WE=300 CE=50 CF=50 K=3 H=256 D=350
#define NPOS 16384          // B*S
#define KPAD 384            // D padded to multiple of 64

#define L2E  1.4426950408889634f
#define L2E2 2.8853900817779268f

typedef __attribute__((ext_vector_type(8))) short bf16x8;
typedef __attribute__((ext_vector_type(4))) float f32x4;
typedef __attribute__((ext_vector_type(8))) int i32x8;

__device__ __forceinline__ float bf2f(u16 u) { return __uint_as_float(((u32)u) << 16); }
__device__ __forceinline__ u16 f2bf(float f) {
    u32 u = __float_as_uint(f);
    u += 0x7fffu + ((u >> 16) & 1u);   // RNE
    return (u16)(u >> 16);
}
__device__ __forceinline__ float frcp(float x) {
#if __has_builtin(__builtin_amdgcn_rcpf)
    return __builtin_amdgcn_rcpf(x);       // v_rcp_f32, 1ulp — fine vs fp8 weights
#else
    return 1.0f / x;
#endif
}
__device__ __forceinline__ float fexp2(float x) {
#if __has_builtin(__builtin_amdgcn_exp2f)
    return __builtin_amdgcn_exp2f(x);      // bare v_exp_f32 (negate folds as src modifier)
#else
    return exp2f(x);
#endif
}

// f32 -> fp8 e4m3fn (OCP), RNE, clamp to +-448. Prep-path (manual, no builtin risk).
__device__ u8 f2fp8_manual(float f) {
    u32 u = __float_as_uint(f);
    u32 s = (u >> 31) << 7;
    u32 ae = (u >> 23) & 255u;
    u32 m = u & 0x7fffffu;
    int e = (int)ae - 127;
    if (ae == 0) return (u8)s;                 // f32 subnormal -> 0
    if (e >= 9) return (u8)(s | 0x7e);         // >= 512 -> clamp 448
    if (e >= -6) {                             // e4m3 normal
        u32 mant = m >> 20;
        u32 rem = m & 0xfffffu;
        if (rem > 0x80000u || (rem == 0x80000u && (mant & 1u))) mant++;
        u32 ef = (u32)(e + 7);
        if (mant == 8u) { mant = 0u; ef++; }
        if (ef >= 16u || (ef == 15u && mant == 7u)) return (u8)(s | 0x7e);
        return (u8)(s | (ef << 3) | mant);
    }
    if (e < -10) return (u8)s;                 // underflow to 0
    int sb = 14 - e;                           // shift for units of 2^-9
    u32 X = 0x800000u | m;
    u32 mant = X >> sb;
    u32 rem = X & ((1u << sb) - 1u);
    u32 half = 1u << (sb - 1);
    if (rem > half || (rem == half && (mant & 1u))) mant++;
    if (mant >= 8u) return (u8)(s | (1u << 3)); // rounds to first normal 2^-6
    return (u8)(s | mant);
}

__device__ __forceinline__ u32 f2fp8(float f) {
#if __has_builtin(__builtin_amdgcn_cvt_pk_fp8_f32)
    return (u32)(__builtin_amdgcn_cvt_pk_fp8_f32(f, f, 0, false) & 0xff);
#else
    return (u32)f2fp8_manual(f);
#endif
}

// ---- workspace layout (bytes) ----
static constexpr size_t OFF_INP  = 0;                       // u16 [16384][384]   = 12582912
static constexpr size_t OFF_WIH  = 12582912;                // u16 [2048][384]    = 1572864
static constexpr size_t OFF_WHH  = 14155776;                // fp8 packed 512KB
static constexpr size_t OFF_XG   = 15204352;                // u16 xg2 repacked   = 67108864
static constexpr size_t OFF_HS   = 82313216;                // u16 [16384][512]   = 16777216
static constexpr size_t OFF_EMIS = 99090432;                // f32 [16384][17]    = 1114112
static constexpr size_t OFF_NLL  = 100204544;               // f32 [128]
static constexpr size_t OFF_WT   = OFF_XG;                  // f32 wt[150][52] (transient; overwritten by xg later)

// ============================================================
// Prep0: transpose conv_w [50 oc][50 ic][3 k] -> wt[(ic*3+k)][52 pad][oc]
// ============================================================
__global__ __launch_bounds__(256) void k_prep0(const float* __restrict__ conv_w,
                                               float* __restrict__ wt) {
    int idx = blockIdx.x * 256 + threadIdx.x;
    if (idx < 7500) {
        int oc = idx / 150, r = idx - oc * 150;        // r = ic*3+k
        wt[r * 52 + oc] = conv_w[oc * 150 + r];
    }
}

// ============================================================
// Fused front kernel: blockIdx dispatch
//   b in [0,2048):    embedding + char conv (8 positions per block) —
//                     blocks fully past the row's length exit immediately.
//   b in [2048,3072): pack w_ih -> bf16 [2048][384], pre-scaled by log2e
//                     (gate g: 2*log2e) so the LSTM uses bare v_exp_f32.
//   b in [3072,4096): pack w_hh -> fp8 MX layout, same pre-scale.
// ============================================================
__global__ __launch_bounds__(256) void k_front(const int* __restrict__ words,
                                               const int* __restrict__ chars,
                                               const float* __restrict__ word_emb,
                                               const float* __restrict__ char_emb,
                                               const float* __restrict__ wt,
                                               const float* __restrict__ conv_b,
                                               u16* __restrict__ inp,
                                               const float* __restrict__ wihf,
                                               const float* __restrict__ wihb,
                                               u16* __restrict__ wih,
                                               const float* __restrict__ whf,
                                               const float* __restrict__ whb,
                                               u8* __restrict__ whh8,
                                               const int* __restrict__ lengths) {
    __shared__ float ce_t[8][50][20];                  // [pos][ic][t], t=0 & 17..19 zero pad
    int b = blockIdx.x, tid = threadIdx.x;

    if (b >= 2048) {
        if (b < 3072) {                                // ---- w_ih pack (pre-scaled) ----
            int n = (b - 2048) * 2 + (tid >> 7);
            int t128 = tid & 127;
            const float* src = (n < 1024) ? (wihf + (size_t)n * 350) : (wihb + (size_t)(n - 1024) * 350);
            float sc = (((n & 1023) >> 8) == 2) ? L2E2 : L2E;
            u16* dst = wih + (size_t)n * KPAD;
            for (int k = t128; k < KPAD; k += 128) dst[k] = (k < 350) ? f2bf(src[k] * sc) : (u16)0;
        } else {                                       // ---- w_hh pack (MX B-frag, pre-scaled) ----
            int gr = (b - 3072) * 2 + (tid >> 7);
            int t128 = tid & 127;
            int d = gr >> 10, row = gr & 1023;         // row = gate*256 + hid
            const float* src = (d ? whb : whf) + (size_t)row * 256;
            int g = row >> 8, hid = row & 255;
            float sc = (g == 2) ? L2E2 : L2E;
            int w = hid >> 5, nb = (hid >> 4) & 1, c16 = hid & 15;
            u8* base = whh8 + ((size_t)((d * 8 + w) * 4 + g)) * 8192;
            for (int k = t128; k < 256; k += 128) {
                int kk = k >> 7, q = (k >> 5) & 3, j = k & 31;
                base[((nb * 2 + kk) * 64 + (q * 16 + c16)) * 32 + j] = f2fp8_manual(src[k] * sc);
            }
        }
        return;
    }

    // length skip: this block's 8 positions are t in [t0, t0+8) of batch row b>>4
    if (((b & 15) * 8) >= lengths[b >> 4]) return;

    // ---- embedding + char conv, 8 positions ----
    int pos0 = b * 8;

    // ce_t fill: threads 0..127 -> (pos, char c); threads 128..255 zero pad cols
    if (tid < 128) {
        int p = tid >> 4, c = tid & 15;
        int ch = chars[(size_t)(pos0 + p) * 16 + c];
        const float* src = char_emb + (size_t)ch * 50;
#pragma unroll
        for (int i = 0; i < 25; ++i) {
            float2 v = *(const float2*)(src + i * 2);
            ce_t[p][i * 2][c + 1] = v.x;
            ce_t[p][i * 2 + 1][c + 1] = v.y;
        }
    } else {
        int base = tid - 128;
        for (int i = base; i < 1600; i += 128) {
            int p = i / 200, rem = i - p * 200;
            int ic = rem >> 2, cid = rem & 3;
            ce_t[p][ic][cid == 0 ? 0 : 16 + cid] = 0.f;
        }
    }

    // word embedding: 8 pos x 75 float4 = 600 tasks
    for (int r = 0; r < 3; ++r) {
        int idx = r * 256 + tid;
        if (idx < 600) {
            int p = idx / 75, v = idx - p * 75;
            const float4* we4 = (const float4*)(word_emb + (size_t)words[pos0 + p] * 300);
            float4 val = we4[v];
            u64 pk = (u64)f2bf(val.x) | ((u64)f2bf(val.y) << 16) |
                     ((u64)f2bf(val.z) << 32) | ((u64)f2bf(val.w) << 48);
            *(u64*)(inp + (size_t)(pos0 + p) * KPAD + v * 4) = pk;
        }
    }
    // zero pad inp[350..383]: 8 pos x 17 u32
    {
        int idx = tid;
        if (idx < 136) {
            int p = idx / 17, j = idx - p * 17;
            *(u32*)(inp + (size_t)(pos0 + p) * KPAD + 350 + 2 * j) = 0;
        }
    }
    __syncthreads();

    // conv: 200 tasks = 8 pos x 25 oc-pairs; each task: 2 oc x 16 t
    if (tid < 200) {
        int p = tid / 25, ocp = tid - p * 25;
        int oc = ocp * 2;
        float acc0[16], acc1[16];
#pragma unroll
        for (int t = 0; t < 16; ++t) { acc0[t] = 0.f; acc1[t] = 0.f; }
        const float* cebase = &ce_t[p][0][0];
        for (int ic = 0; ic < 50; ++ic) {
            float c[20];
            const float* cp = cebase + ic * 20;
#pragma unroll
            for (int i = 0; i < 5; ++i) *(float4*)(&c[i * 4]) = *(const float4*)(cp + i * 4);
#pragma unroll
            for (int k = 0; k < 3; ++k) {
                float2 wv = *(const float2*)(wt + (ic * 3 + k) * 52 + oc);
#pragma unroll
                for (int t = 0; t < 16; ++t) {
                    acc0[t] = fmaf(c[t + k], wv.x, acc0[t]);
                    acc1[t] = fmaf(c[t + k], wv.y, acc1[t]);
                }
            }
        }
        float cb0 = conv_b[oc], cb1 = conv_b[oc + 1];
        float m0 = 0.f, m1 = 0.f;
#pragma unroll
        for (int t = 0; t < 16; ++t) {
            m0 = fmaxf(m0, acc0[t] + cb0);
            m1 = fmaxf(m1, acc1[t] + cb1);
        }
        u16* op = inp + (size_t)(pos0 + p) * KPAD + 300 + oc;
        op[0] = f2bf(m0);
        op[1] = f2bf(m1);
    }
}

// ============================================================
// GEMM: inp[16384][384] @ wih[2048][384]^T (bf16 MFMA). N=256 per block
// (block = dd x 64-hid slice). Bias folded with the same log2e pre-scale.
// mt-subtiles past the row length skipped via scalar branch.
// ============================================================
__global__ __launch_bounds__(256, 2) void k_gemm(const u16* __restrict__ A,
                                                 const u16* __restrict__ Bm,
                                                 u16* __restrict__ C,
                                                 const int* __restrict__ lengths,
                                                 const float* __restrict__ bias_f,
                                                 const float* __restrict__ bias_b) {
    __shared__ u16 sa[128 * 64];                       // 16KB
    __shared__ u16 sb[256 * 64];                       // 32KB
    int tid = threadIdx.x;
    int dd = blockIdx.x >> 2, hb2 = blockIdx.x & 3;    // 64-hid slice
    int m0 = blockIdx.y * 128;
    int lane = tid & 63, wid = tid >> 6;
    int wr = wid >> 1, wc = wid & 1;
    int b = blockIdx.y;
    int len = lengths[b];
    int lenS = __builtin_amdgcn_readfirstlane(len);
    int wrS = __builtin_amdgcn_readfirstlane(wr);

    f32x4 acc[4][8];                                   // [mt][nb*4+g]
#pragma unroll
    for (int mt = 0; mt < 4; ++mt)
#pragma unroll
        for (int j = 0; j < 8; ++j) acc[mt][j] = (f32x4){0.f, 0.f, 0.f, 0.f};

    for (int kt = 0; kt < 6; ++kt) {
#pragma unroll
        for (int c = 0; c < 4; ++c) {                  // stage A: 128 rows x 128B
            int idx = (c * 256 + tid) * 16;
            int row = idx >> 7, colb = idx & 127;
            int dst = idx ^ ((row & 7) << 4);
            uint4 va = *(const uint4*)((const char*)A + (size_t)(m0 + row) * 768 + kt * 128 + colb);
            *(uint4*)((char*)sa + dst) = va;
        }
#pragma unroll
        for (int c = 0; c < 8; ++c) {                  // stage B: 256 rows x 128B
            int idx = (c * 256 + tid) * 16;
            int row = idx >> 7, colb = idx & 127;
            int dst = idx ^ ((row & 7) << 4);
            int bmrow = dd * 1024 + (row >> 6) * 256 + hb2 * 64 + (row & 63);
            uint4 vb = *(const uint4*)((const char*)Bm + (size_t)bmrow * 768 + kt * 128 + colb);
            *(uint4*)((char*)sb + dst) = vb;
        }
        __syncthreads();
#pragma unroll
        for (int kc = 0; kc < 2; ++kc) {
            bf16x8 bf[8];
#pragma unroll
            for (int nb = 0; nb < 2; ++nb)
#pragma unroll
                for (int g = 0; g < 4; ++g) {
                    int row = g * 64 + wc * 32 + nb * 16 + (lane & 15);
                    int off = (row * 128 + kc * 64 + (lane >> 4) * 16) ^ ((row & 7) << 4);
                    bf[nb * 4 + g] = *(const bf16x8*)((const char*)sb + off);
                }
#pragma unroll
            for (int mt = 0; mt < 4; ++mt) {
                if (wrS * 64 + mt * 16 < lenS) {       // scalar skip of dead t-subtiles
                    int row = wr * 64 + mt * 16 + (lane & 15);
                    int off = (row * 128 + kc * 64 + (lane >> 4) * 16) ^ ((row & 7) << 4);
                    bf16x8 af = *(const bf16x8*)((const char*)sa + off);
#pragma unroll
                    for (int j = 0; j < 8; ++j)
                        acc[mt][j] = __builtin_amdgcn_mfma_f32_16x16x32_bf16(af, bf[j], acc[mt][j], 0, 0, 0);
                }
            }
        }
        __syncthreads();
    }
    // epilogue
    int grp = b >> 4, row16 = b & 15;
    int qq = row16 >> 2, rg = row16 & 3;
    int c16 = lane & 15;
    const float* bias = dd ? bias_b : bias_f;
    float bv[2][4];
    u32 base16[2];
#pragma unroll
    for (int nb = 0; nb < 2; ++nb) {
        int hid = hb2 * 64 + wc * 32 + nb * 16 + c16;
#pragma unroll
        for (int g = 0; g < 4; ++g) bv[nb][g] = bias[g * 256 + hid] * ((g == 2) ? L2E2 : L2E);
        base16[nb] = (u32)(((hb2 * 2 + wc) * 64 + qq * 16 + c16) * 32 + (nb * 4 + rg) * 4);
    }
    size_t slab0 = ((size_t)(dd * 8 + grp) * 128) * 16384;
#pragma unroll
    for (int mt = 0; mt < 4; ++mt) {
        if (wrS * 64 + mt * 16 < lenS) {
#pragma unroll
            for (int r = 0; r < 4; ++r) {
                int t = wr * 64 + mt * 16 + (lane >> 4) * 4 + r;
                int tt = dd ? ((t < len) ? (len - 1 - t) : t) : t;
#pragma unroll
                for (int nb = 0; nb < 2; ++nb) {
                    u64 pk = (u64)f2bf(acc[mt][nb * 4 + 0][r] + bv[nb][0]) |
                             ((u64)f2bf(acc[mt][nb * 4 + 1][r] + bv[nb][1]) << 16) |
                             ((u64)f2bf(acc[mt][nb * 4 + 2][r] + bv[nb][2]) << 32) |
                             ((u64)f2bf(acc[mt][nb * 4 + 3][r] + bv[nb][3]) << 48);
                    *(u64*)(C + slab0 + (size_t)tt * 16384 + base16[nb]) = pk;
                }
            }
        }
    }
}

// ============================================================
// BiLSTM recurrence. 16 WGs = dir(2) x group(8). All 4 gates register-
// resident fp8 (i32x8 br[16] = 128 regs). h fp8 double-buffered LDS,
// stride 272. MX-scaled MFMA 16x16x128 (unit scales).
// R14: weights pre-scaled by log2e (gate g: 2*log2e) -> bare v_exp_f32;
// shared-reciprocal gate algebra: gi*gg = (1-eb)*rcp((1+ea)(1+eb)),
// go*tanh(cn) = (1-ee)*rcp((1+ed)(1+ee)) — 8 trans/unit (was 10+5mul).
// Branchless cndmask epilogue; barrier drains lgkmcnt only.
// ============================================================
#define LSTM_STEP(T, XC, XN, HA, HW)                                              \
    {                                                                             \
        *(uint4*)(&XN[0])  = *(const uint4*)(xp);                                 \
        *(uint4*)(&XN[4])  = *(const uint4*)(xp + 8);                             \
        *(uint4*)(&XN[8])  = *(const uint4*)(xp + 16);                            \
        *(uint4*)(&XN[12]) = *(const uint4*)(xp + 24);                            \
        xp += 16384;                                                              \
        f32x4 acc[8];                                                             \
        _Pragma("unroll") for (int nb = 0; nb < 2; ++nb)                          \
            _Pragma("unroll") for (int rg = 0; rg < 4; ++rg) {                    \
                int u = nb * 4 + rg;                                              \
                u32 w0 = XC[u * 2], w1 = XC[u * 2 + 1];                           \
                acc[nb * 4 + 0][rg] = __uint_as_float(w0 << 16);                  \
                acc[nb * 4 + 1][rg] = __uint_as_float(w0 & 0xffff0000u);          \
                acc[nb * 4 + 2][rg] = __uint_as_float(w1 << 16);                  \
                acc[nb * 4 + 3][rg] = __uint_as_float(w1 & 0xffff0000u);          \
            }                                                                     \
        i32x8 a0, a1;                                                             \
        *(uint4*)&a0       = *(const uint4*)(HA);                                 \
        *((uint4*)&a0 + 1) = *(const uint4*)(HA + 16);                            \
        *(uint4*)&a1       = *(const uint4*)(HA + 128);                           \
        *((uint4*)&a1 + 1) = *(const uint4*)(HA + 144);                           \
        __builtin_amdgcn_s_setprio(1);                                            \
        _Pragma("unroll") for (int g = 0; g < 4; ++g)                             \
            acc[g] = __builtin_amdgcn_mfma_scale_f32_16x16x128_f8f6f4(            \
                a0, br[g * 4 + 0], acc[g], 0, 0, 0, 127, 0, 127);                 \
        _Pragma("unroll") for (int g = 0; g < 4; ++g)                             \
            acc[g] = __builtin_amdgcn_mfma_scale_f32_16x16x128_f8f6f4(            \
                a1, br[g * 4 + 1], acc[g], 0, 0, 0, 127, 0, 127);                 \
        _Pragma("unroll") for (int g = 0; g < 4; ++g)                             \
            acc[4 + g] = __builtin_amdgcn_mfma_scale_f32_16x16x128_f8f6f4(        \
                a0, br[g * 4 + 2], acc[4 + g], 0, 0, 0, 127, 0, 127);             \
        _Pragma("unroll") for (int g = 0; g < 4; ++g)                             \
            acc[4 + g] = __builtin_amdgcn_mfma_scale_f32_16x16x128_f8f6f4(        \
                a1, br[g * 4 + 3], acc[4 + g], 0, 0, 0, 127, 0, 127);             \
        __builtin_amdgcn_s_setprio(0);                                            \
        _Pragma("unroll") for (int rg = 0; rg < 4; ++rg) {                        \
            bool mv = (T) < lenr[rg];                                             \
            _Pragma("unroll") for (int nb = 0; nb < 2; ++nb) {                    \
                int u = nb * 4 + rg;                                              \
                float ea = fexp2(-acc[nb * 4 + 0][rg]);                           \
                float ec = fexp2(-acc[nb * 4 + 1][rg]);                           \
                float eb = fexp2(-acc[nb * 4 + 2][rg]);                           \
                float ed = fexp2(-acc[nb * 4 + 3][rg]);                           \
                float gf = frcp(1.0f + ec);                                       \
                float gig = (1.0f - eb) * frcp((1.0f + ea) * (1.0f + eb));        \
                float cn = gf * cst[u] + gig;                                     \
                float ee = fexp2(fminf(-L2E2 * cn, 126.0f));                      \
                float hn = (1.0f - ee) * frcp((1.0f + ed) * (1.0f + ee));         \
                cst[u] = mv ? cn : cst[u];                                        \
                hbf[u] = mv ? (__float_as_uint(hn) >> 16) : hbf[u];               \
                hq[u]  = mv ? f2fp8(hn) : hq[u];                                  \
                voff[u] += mv ? dstepB : 0;                                       \
                *(u16*)(hsp + voff[u]) = (u16)hbf[u];                             \
                (HW)[rg * 272 + nb * 16] = (u8)hq[u];                             \
            }                                                                     \
        }                                                                         \
        asm volatile("s_waitcnt lgkmcnt(0)\n\ts_barrier" ::: "memory");           \
    }

__global__ __launch_bounds__(512, 2) void k_lstm(const u16* __restrict__ xg2,
                                                 const u8* __restrict__ whh8,
                                                 const int* __restrict__ lengths,
                                                 u16* __restrict__ hs) {
    __shared__ u8 h8[2][4352];                         // [buf][16 rows][stride 272]
    int tid = threadIdx.x, lane = tid & 63, w = tid >> 6;
    int bx = blockIdx.x;
    int d = bx >> 3, grp = bx & 7;
    int c16 = lane & 15, q = lane >> 4;

    u8* hflat = &h8[0][0];
    for (int i = tid * 8; i < 8704; i += 4096) *(u64*)(hflat + i) = 0;

    int lenr[4];
#pragma unroll
    for (int rg = 0; rg < 4; ++rg) lenr[rg] = lengths[grp * 16 + q * 4 + rg];

    // WG-wide max length (identical across waves)
    int ml = lenr[0];
#pragma unroll
    for (int rg = 1; rg < 4; ++rg) ml = ml > lenr[rg] ? ml : lenr[rg];
    {
        int o = __shfl_xor(ml, 16); ml = ml > o ? ml : o;
        o = __shfl_xor(ml, 32);     ml = ml > o ? ml : o;
    }
    int tmax = (ml + 1) & ~1;                          // even (double-buffer parity)

    // register-resident fp8 weights: [g][nb][kk] i32x8 = 128 regs
    const u8* wbse = whh8 + ((size_t)((d * 8 + w) * 4)) * 8192;
    i32x8 br[16];
#pragma unroll
    for (int g = 0; g < 4; ++g)
#pragma unroll
        for (int nb = 0; nb < 2; ++nb)
#pragma unroll
            for (int kk = 0; kk < 2; ++kk) {
                const u8* p = wbse + (size_t)g * 8192 + ((nb * 2 + kk) * 64 + lane) * 32;
                i32x8 v;
                *(uint4*)&v       = *(const uint4*)p;
                *((uint4*)&v + 1) = *(const uint4*)(p + 16);
                br[g * 4 + nb * 2 + kk] = v;
            }

    float cst[8];
    u32 hq[8], hbf[8];                                 // frozen-carry h (fp8 / bf16 bits)
#pragma unroll
    for (int u = 0; u < 8; ++u) { cst[u] = 0.f; hq[u] = 0; hbf[u] = 0; }

    // hs byte offsets, advance-then-store (frozen when masked)
    u32 voff[8];
    int dstepB = d ? -1024 : 1024;
    u8* hsp = (u8*)hs;
#pragma unroll
    for (int nb = 0; nb < 2; ++nb)
#pragma unroll
        for (int rg = 0; rg < 4; ++rg) {
            int u = nb * 4 + rg;
            int row = q * 4 + rg;
            int hid = w * 32 + nb * 16 + c16;
            int p0 = d ? (lenr[rg] - 1) : 0;
            voff[u] = (u32)((((grp * 16 + row) * 128 + p0) * 512 + d * 256 + hid) * 2 - dstepB);
        }

    // xg: bias pre-folded; 64B/lane/step; xp points at the NEXT slab
    const u16* xslab = xg2 + ((size_t)(d * 8 + grp) * 128) * 16384 + (w * 64 + lane) * 32;
    u32 xqa[16], xqb[16];
    *(uint4*)(&xqa[0])  = *(const uint4*)(xslab);
    *(uint4*)(&xqa[4])  = *(const uint4*)(xslab + 8);
    *(uint4*)(&xqa[8])  = *(const uint4*)(xslab + 16);
    *(uint4*)(&xqa[12]) = *(const uint4*)(xslab + 24);
    const u16* xp = xslab + 16384;

    // A-frag LDS bases (row c16, k = q*32 + j, +kk*128 via imm), stride 272
    const u8* ha0 = hflat + (c16 * 272 + q * 32);
    const u8* ha1 = ha0 + 4352;
    // h write bases: row = q*4+rg (imm), hid = w*32 + nb*16 (imm) + c16
    u8* hw1 = hflat + (q * 1088 + w * 32 + c16);       // write target while reading buf0
    u8* hw0 = hw1 + 4352;

    __syncthreads();

    for (int t2 = 0; t2 < tmax; t2 += 2) {
        LSTM_STEP(t2,     xqa, xqb, ha0, hw0)
        LSTM_STEP(t2 + 1, xqb, xqa, ha1, hw1)
    }
}

// ============================================================
// Emissions: emis[pos][17] = hs[pos][512] . proj_w[17][512] + proj_b
// 16 positions per block (4 per wave); blocks past length exit.
// ============================================================
__global__ __launch_bounds__(256) void k_emis(const u16* __restrict__ hs,
                                              const float* __restrict__ proj_w,
                                              const float* __restrict__ proj_b,
                                              float* __restrict__ emis,
                                              const int* __restrict__ lengths) {
    int p00 = blockIdx.x * 16;
    if ((p00 & 127) >= lengths[p00 >> 7]) return;      // length skip

    __shared__ float pw[17 * 512];
    int tid = threadIdx.x;
    for (int i = tid; i < 17 * 512; i += 256) pw[i] = proj_w[i];
    __syncthreads();
    int lane = tid & 63, wv = tid >> 6;
    int pos0 = p00 + wv * 4;
    float hv[4][8];
#pragma unroll
    for (int p = 0; p < 4; ++p) {
        bf16x8 v = *(const bf16x8*)(hs + (size_t)(pos0 + p) * 512 + lane * 8);
#pragma unroll
        for (int j = 0; j < 8; ++j) hv[p][j] = bf2f((u16)v[j]);
    }
    for (int tg = 0; tg < 17; ++tg) {
        const float* wp = pw + tg * 512 + lane * 8;
        float wr[8];
#pragma unroll
        for (int j = 0; j < 8; ++j) wr[j] = wp[j];
        float s[4];
#pragma unroll
        for (int p = 0; p < 4; ++p) {
            float acc = 0.f;
#pragma unroll
            for (int j = 0; j < 8; ++j) acc = fmaf(hv[p][j], wr[j], acc);
            s[p] = acc;
        }
#pragma unroll
        for (int off = 32; off; off >>= 1)
#pragma unroll
            for (int p = 0; p < 4; ++p) s[p] += __shfl_down(s[p], off);
        if (lane == 0) {
#pragma unroll
            for (int p = 0; p < 4; ++p) emis[(size_t)(pos0 + p) * 17 + tg] = s[p] + proj_b[tg];
        }
    }
}

// ============================================================
// CRF per-sample NLL. One 64-thread block per batch element.
// ============================================================
__global__ __launch_bounds__(64) void k_crf(const float* __restrict__ emis,
                                            const int* __restrict__ tags,
                                            const int* __restrict__ lengths,
                                            const float* __restrict__ trans,
                                            const float* __restrict__ start_trans,
                                            const float* __restrict__ end_trans,
                                            float* __restrict__ nll) {
    int b = blockIdx.x, lane = threadIdx.x;
    __shared__ float tr[289];
    __shared__ float al[17];
    __shared__ float scs;
    for (int i = lane; i < 289; i += 64) tr[i] = trans[i];
    int len = lengths[b];
    const int* tg = tags + (size_t)b * 128;
    const float* em = emis + (size_t)b * 128 * 17;
    __syncthreads();

    float sc = 0.f;
    for (int t = lane; t < len; t += 64) {
        sc += em[t * 17 + tg[t]];
        if (t >= 1) sc += tr[tg[t - 1] * 17 + tg[t]];
    }
#pragma unroll
    for (int off = 32; off; off >>= 1) sc += __shfl_down(sc, off);
    if (lane == 0) scs = sc + start_trans[tg[0]] + end_trans[tg[len - 1]];

    if (lane < 17) al[lane] = start_trans[lane] + em[lane];
    __syncthreads();
    for (int t = 1; t < len; ++t) {
        float anew = 0.f;
        if (lane < 17) {
            float m = -1e30f;
            for (int i = 0; i < 17; ++i) m = fmaxf(m, al[i] + tr[i * 17 + lane]);
            float s = 0.f;
            for (int i = 0; i < 17; ++i) s += __expf(al[i] + tr[i * 17 + lane] - m);
            anew = m + __logf(s) + em[t * 17 + lane];
        }
        __syncthreads();
        if (lane < 17) al[lane] = anew;
        __syncthreads();
    }
    float v = (lane < 17) ? al[lane] + end_trans[lane] : -1e30f;
    float m = v;
#pragma unroll
    for (int off = 32; off; off >>= 1) m = fmaxf(m, __shfl_xor(m, off));
    float s = (lane < 17) ? __expf(v - m) : 0.f;
#pragma unroll
    for (int off = 32; off; off >>= 1) s += __shfl_xor(s, off);
    if (lane == 0) nll[b] = (m + __logf(s)) - scs;
}

__global__ __launch_bounds__(128) void k_reduce(const float* __restrict__ nll, float* __restrict__ out) {
    int tid = threadIdx.x;
    float v = nll[tid];
#pragma unroll
    for (int off = 32; off; off >>= 1) v += __shfl_down(v, off);
    __shared__ float partial[2];
    if ((tid & 63) == 0) partial[tid >> 6] = v;
    __syncthreads();
    if (tid == 0) out[0] = partial[0] + partial[1];
}

// ============================================================
extern "C" void kernel_launch(void* const* d_in, const int* in_sizes, int n_in,
                              void* d_out, int out_size, void* d_ws, size_t ws_size,
                              hipStream_t stream) {
    (void)in_sizes; (void)n_in; (void)out_size; (void)ws_size;
    const int*   words       = (const int*)d_in[0];
    const int*   chars       = (const int*)d_in[1];
    const int*   tags        = (const int*)d_in[2];
    const int*   lengths     = (const int*)d_in[3];
    const float* word_emb    = (const float*)d_in[4];
    const float* char_emb    = (const float*)d_in[5];
    const float* conv_w      = (const float*)d_in[6];
    const float* conv_b      = (const float*)d_in[7];
    const float* w_ih_f      = (const float*)d_in[8];
    const float* w_hh_f      = (const float*)d_in[9];
    const float* b_f         = (const float*)d_in[10];
    const float* w_ih_b      = (const float*)d_in[11];
    const float* w_hh_b      = (const float*)d_in[12];
    const float* b_b         = (const float*)d_in[13];
    const float* proj_w      = (const float*)d_in[14];
    const float* proj_b      = (const float*)d_in[15];
    const float* trans       = (const float*)d_in[16];
    const float* start_trans = (const float*)d_in[17];
    const float* end_trans   = (const float*)d_in[18];

    char* ws = (char*)d_ws;
    u16* inp   = (u16*)(ws + OFF_INP);
    u16* wih   = (u16*)(ws + OFF_WIH);
    u8*  whh8  = (u8*)(ws + OFF_WHH);
    u16* xgb   = (u16*)(ws + OFF_XG);
    u16* hsb   = (u16*)(ws + OFF_HS);
    float* em  = (float*)(ws + OFF_EMIS);
    float* nll = (float*)(ws + OFF_NLL);
    float* wt  = (float*)(ws + OFF_WT);

    k_prep0<<<30, 256, 0, stream>>>(conv_w, wt);
    k_front<<<4096, 256, 0, stream>>>(words, chars, word_emb, char_emb, wt, conv_b, inp,
                                      w_ih_f, w_ih_b, wih, w_hh_f, w_hh_b, whh8, lengths);
    k_gemm<<<dim3(8, 128), 256, 0, stream>>>(inp, wih, xgb, lengths, b_f, b_b);
    k_lstm<<<16, 512, 0, stream>>>(xgb, whh8, lengths, hsb);
    k_emis<<<1024, 256, 0, stream>>>(hsb, proj_w, proj_b, em, lengths);
    k_crf<<<128, 64, 0, stream>>>(em, tags, lengths, trans, start_trans, end_trans, nll);
    k_reduce<<<1, 128, 0, stream>>>(nll, (float*)d_out);
}